// Round 4
// baseline (1219.248 us; speedup 1.0000x reference)
//
#include <hip/hip_runtime.h>

typedef unsigned short u16;
typedef __attribute__((ext_vector_type(8))) short bf16x8;
typedef __attribute__((ext_vector_type(4))) float f32x4;

#define PITCH 40   // small-conv kernel LDS pitch (shorts)

__device__ __forceinline__ u16 f2bf(float f) {
  union { float f; unsigned u; } v; v.f = f;
  unsigned r = v.u + 0x7fffu + ((v.u >> 16) & 1u);
  return (u16)(r >> 16);
}
__device__ __forceinline__ float bf2f(u16 h) {
  union { unsigned u; float f; } v; v.u = ((unsigned)h) << 16;
  return v.f;
}
__device__ __forceinline__ float4 load4bf(const u16* p) {
  ushort4 h = *(const ushort4*)p;
  return make_float4(bf2f(h.x), bf2f(h.y), bf2f(h.z), bf2f(h.w));
}
// async global->LDS, 16B per lane; LDS dest = wave-uniform base + lane*16
__device__ __forceinline__ void gll16(const u16* g, u16* l) {
  __builtin_amdgcn_global_load_lds(
      (const __attribute__((address_space(1))) unsigned int*)g,
      (__attribute__((address_space(3))) unsigned int*)l, 16, 0, 0);
}

// ---------------- tiled transpose (l,c,s) -> token-major [(l,s), c] fp32 ----------------
__global__ __launch_bounds__(256) void k_tin(const float* __restrict__ x,
                                             float* __restrict__ xt) {
  __shared__ float t[32][33];
  int s0 = blockIdx.x * 32, c0 = blockIdx.y * 32, l = blockIdx.z;
  int r = threadIdx.x >> 3, q4 = (threadIdx.x & 7) * 4;
  float4 v = *(const float4*)(x + ((long)(l * 128 + c0 + r) << 12) + s0 + q4);
  t[r][q4] = v.x; t[r][q4 + 1] = v.y; t[r][q4 + 2] = v.z; t[r][q4 + 3] = v.w;
  __syncthreads();
  float4 o = {t[q4][r], t[q4 + 1][r], t[q4 + 2][r], t[q4 + 3][r]};
  *(float4*)(xt + ((long)(l * 4096 + s0 + r) << 7) + c0 + q4) = o;
}

__global__ __launch_bounds__(256) void k_tout(const float* __restrict__ xt,
                                              float* __restrict__ out) {
  __shared__ float t[32][33];
  int s0 = blockIdx.x * 32, c0 = blockIdx.y * 32, l = blockIdx.z;
  int r = threadIdx.x >> 3, q4 = (threadIdx.x & 7) * 4;
  float4 v = *(const float4*)(xt + ((long)(l * 4096 + s0 + r) << 7) + c0 + q4);
  t[r][q4] = v.x; t[r][q4 + 1] = v.y; t[r][q4 + 2] = v.z; t[r][q4 + 3] = v.w;
  __syncthreads();
  float4 o = {t[q4][r], t[q4 + 1][r], t[q4 + 2][r], t[q4 + 3][r]};
  *(float4*)(out + ((long)(l * 128 + c0 + r) << 12) + s0 + q4) = o;
}

__global__ __launch_bounds__(256) void k_zeropage(u16* __restrict__ zp) {
  zp[threadIdx.x] = 0; zp[threadIdx.x + 256] = 0;
  zp[threadIdx.x + 512] = 0; zp[threadIdx.x + 768] = 0;
}

// ---------------- layernorm fp32 in -> bf16 out, one wave per row ----------------
__global__ __launch_bounds__(256) void k_ln_f2b(const float* __restrict__ X,
                                                const float* __restrict__ g,
                                                const float* __restrict__ b,
                                                u16* __restrict__ Y, int M) {
  int n = blockIdx.x * 4 + (threadIdx.x >> 6);
  if (n >= M) return;
  int lane = threadIdx.x & 63;
  const float* row = X + (long)n * 128;
  float2 v = *(const float2*)(row + lane * 2);
  float s = v.x + v.y;
#pragma unroll
  for (int o = 32; o > 0; o >>= 1) s += __shfl_xor(s, o);
  float mu = s * (1.0f / 128.0f);
  float dx = v.x - mu, dy = v.y - mu;
  float q = dx * dx + dy * dy;
#pragma unroll
  for (int o = 32; o > 0; o >>= 1) q += __shfl_xor(q, o);
  float rs = rsqrtf(q * (1.0f / 128.0f) + 1e-5f);
  float2 gv = *(const float2*)(g + lane * 2);
  float2 bv = *(const float2*)(b + lane * 2);
  ushort2 o2;
  o2.x = f2bf(dx * rs * gv.x + bv.x);
  o2.y = f2bf(dy * rs * gv.y + bv.y);
  *(ushort2*)(Y + (long)n * 128 + lane * 2) = o2;
}

// ---------------- coalesced weight repack: W[oc][ic][t] fp32 -> Wb[t][oc][ic] bf16 ----------
__global__ __launch_bounds__(256) void k_repack2(const float* __restrict__ W,
                                                 u16* __restrict__ Wb,
                                                 int OC, int IC, int NT) {
  __shared__ float ws[128 * 81];
  int oc = blockIdx.x, ic0 = blockIdx.y * 128;
  const float* src = W + ((long)oc * IC + ic0) * NT;
  int n = 128 * NT;
  for (int i = threadIdx.x; i < n; i += 256) ws[i] = src[i];
  __syncthreads();
  u16* dst = Wb + (long)oc * IC + ic0;
  long tstep = (long)OC * IC;
  for (int idx = threadIdx.x; idx < n; idx += 256) {
    int t = idx >> 7, i = idx & 127;
    dst[(long)t * tstep + i] = f2bf(ws[i * NT + t]);
  }
}

// ---------------- small conv-as-gather-GEMM (64 x 64 tile) for small M ----------------
__global__ __launch_bounds__(256) void k_conv_mfma(
    const u16* __restrict__ X, const u16* __restrict__ W3,
    const float* __restrict__ bias, void* __restrict__ Yv,
    int M, int IC, int OC, int mode, int NT,
    int lgWo, int lgHo, int lgDo,
    int lgWi, int lgHi, int lgDi,
    int Li, int Di, int Hi, int Wi,
    int sL, int sD, int sH, int sW, int flags) {
  __shared__ u16 As[64 * PITCH];
  __shared__ u16 Bs[64 * PITCH];
  int tid = threadIdx.x;
  int wave = tid >> 6, lane = tid & 63;
  int quad = lane >> 4, l15 = lane & 15;
  int m0 = blockIdx.x * 64;
  int oc0 = blockIdx.y * 64;

  int srl = tid >> 2;
  int sao = (tid & 3) * 8;
  int sboc = tid >> 2, sbo = (tid & 3) * 8;

  int sm = m0 + srl;
  bool mv = sm < M;
  int w = sm & ((1 << lgWo) - 1);
  int h = (sm >> lgWo) & ((1 << lgHo) - 1);
  int d = (sm >> (lgWo + lgHo)) & ((1 << lgDo) - 1);
  int l = sm >> (lgWo + lgHo + lgDo);

  int c0 = 0, c1 = 0, c2 = 0, c3 = 0;
  auto comp_nb = [&]() -> long {
    if (!mv) return -1;
    int li, di, hi, wi; bool ok;
    if (mode == 0) {
      int dl = c0 - 1;
      int ll = (l & 1) + dl;
      ok = (ll >= 0 && ll < 2);
      li = l + dl; di = d; hi = h; wi = w;
    } else if (mode == 1) {
      li = l * sL; di = d * sD + c2 - 1; hi = h * sH + c1 - 1; wi = w * sW + c0 - 1;
      ok = ((unsigned)di < (unsigned)Di) && ((unsigned)hi < (unsigned)Hi) &&
           ((unsigned)wi < (unsigned)Wi);
    } else {
      li = l + c3 - 1; di = d + c2 - 1; hi = h + c1 - 1; wi = w + c0 - 1;
      ok = ((unsigned)li < (unsigned)Li) && ((unsigned)di < (unsigned)Di) &&
           ((unsigned)hi < (unsigned)Hi) && ((unsigned)wi < (unsigned)Wi);
    }
    if (!ok) return -1;
    return ((((long)((li << lgDi) + di) << lgHi) + hi) << lgWi) + wi;
  };

  long nb = comp_nb();
  const u16* wt = W3 + (long)(oc0 + sboc) * IC + sbo;
  long wstep = (long)OC * IC;
  int kmask = (IC >> 5) - 1;
  int total = NT * (IC >> 5);

  const bf16x8 Z = {0, 0, 0, 0, 0, 0, 0, 0};
  bf16x8 ra0 = Z, rb;
  if (nb >= 0) ra0 = *(const bf16x8*)(X + nb * IC + sao);
  rb = *(const bf16x8*)wt;

  f32x4 acc[4];
#pragma unroll
  for (int j = 0; j < 4; ++j) acc[j] = {0.f, 0.f, 0.f, 0.f};

  int wrow = wave * 16;

  for (int ks = 0; ks < total; ++ks) {
    __syncthreads();
    *(bf16x8*)&As[srl * PITCH + sao] = ra0;
    *(bf16x8*)&Bs[sboc * PITCH + sbo] = rb;
    __syncthreads();
    int ksn = ks + 1;
    if (ksn < total) {
      int k0n = (ksn & kmask) << 5;
      if ((ksn & kmask) == 0) {
        wt += wstep;
        if (++c0 == 3) { c0 = 0; if (++c1 == 3) { c1 = 0; if (++c2 == 3) { c2 = 0; ++c3; } } }
        nb = comp_nb();
      }
      ra0 = Z;
      if (nb >= 0) ra0 = *(const bf16x8*)(X + nb * IC + k0n + sao);
      rb = *(const bf16x8*)(wt + k0n);
    }
    bf16x8 a0 = *(const bf16x8*)&As[(wrow + l15) * PITCH + quad * 8];
#pragma unroll
    for (int j = 0; j < 4; ++j) {
      bf16x8 b = *(const bf16x8*)&Bs[(j * 16 + l15) * PITCH + quad * 8];
      acc[j] = __builtin_amdgcn_mfma_f32_16x16x32_bf16(a0, b, acc[j], 0, 0, 0);
    }
  }

  int col = oc0 + l15;
#pragma unroll
  for (int j = 0; j < 4; ++j) {
    float bj = bias[col + j * 16];
    int rbase = m0 + wrow + quad * 4;
#pragma unroll
    for (int r = 0; r < 4; ++r) {
      int row = rbase + r;
      if (row >= M) continue;
      float v = acc[j][r] + bj;
      if (flags & 2) v = fmaxf(v, 0.f);
      long off = (long)row * OC + col + j * 16;
      if (flags & 4) ((u16*)Yv)[off] = f2bf(v);
      else if (flags & 1) ((float*)Yv)[off] += v;
      else ((float*)Yv)[off] = v;
    }
  }
}

// ---------------- big conv-GEMM: 128x128 tile, BK=64, single-buffer global_load_lds ----------
__global__ __launch_bounds__(256, 4) void k_conv_gl(
    const u16* __restrict__ X, const u16* __restrict__ W3,
    const float* __restrict__ bias, void* __restrict__ Yv, float* __restrict__ SP,
    const u16* __restrict__ ZP,
    int M, int IC, int OC, int mode, int NT, int NSPLIT,
    int lgWo, int lgHo, int lgDo,
    int lgWi, int lgHi, int lgDi,
    int Li, int Di, int Hi, int Wi,
    int sL, int sD, int sH, int sW, int flags) {
  __shared__ __align__(16) u16 As[128 * 64];
  __shared__ __align__(16) u16 Bs[128 * 64];
  int tid = threadIdx.x;
  int wave = tid >> 6, lane = tid & 63;
  int quad = lane >> 4, l15 = lane & 15;
  int m0 = blockIdx.x * 128, oc0 = blockIdx.y * 128;
  int mi = wave & 1, ni = wave >> 1;

  int rp[4], cA[4], sm[4];
#pragma unroll
  for (int q = 0; q < 4; ++q) {
    rp[q] = wave * 32 + q * 8 + (lane >> 3);
    cA[q] = ((lane & 7) - (rp[q] >> 1)) & 7;
    sm[q] = m0 + rp[q];
  }

  int tap_per = (NT + NSPLIT - 1) / NSPLIT;
  int t0 = blockIdx.z * tap_per;
  int t1 = min(NT, t0 + tap_per);
  int kc = IC >> 6;
  int total = (t1 - t0) * kc;

  int c0 = t0 % 3, c1 = (t0 / 3) % 3, c2 = (t0 / 9) % 3, c3 = t0 / 27;
  auto comp_nb = [&](int smv) -> int {
    if (smv >= M) return -1;
    int w = smv & ((1 << lgWo) - 1);
    int h = (smv >> lgWo) & ((1 << lgHo) - 1);
    int d = (smv >> (lgWo + lgHo)) & ((1 << lgDo) - 1);
    int l = smv >> (lgWo + lgHo + lgDo);
    int li, di, hi, wi; bool ok;
    if (mode == 0) {
      int dl = c0 - 1;
      int ll = (l & 1) + dl;
      ok = (ll >= 0 && ll < 2);
      li = l + dl; di = d; hi = h; wi = w;
    } else if (mode == 1) {
      li = l * sL; di = d * sD + c2 - 1; hi = h * sH + c1 - 1; wi = w * sW + c0 - 1;
      ok = ((unsigned)di < (unsigned)Di) && ((unsigned)hi < (unsigned)Hi) &&
           ((unsigned)wi < (unsigned)Wi);
    } else {
      li = l + c3 - 1; di = d + c2 - 1; hi = h + c1 - 1; wi = w + c0 - 1;
      ok = ((unsigned)li < (unsigned)Li) && ((unsigned)di < (unsigned)Di) &&
           ((unsigned)hi < (unsigned)Hi) && ((unsigned)wi < (unsigned)Wi);
    }
    if (!ok) return -1;
    return (((li << lgDi) + di) << lgHi | hi) << lgWi | wi;
  };

  int nb[4];
#pragma unroll
  for (int q = 0; q < 4; ++q) nb[q] = comp_nb(sm[q]);
  long wstep = (long)OC * IC;
  const u16* wbase = W3 + (long)t0 * wstep + (long)oc0 * IC;

  f32x4 acc[4][4];
#pragma unroll
  for (int i = 0; i < 4; ++i)
#pragma unroll
    for (int j = 0; j < 4; ++j) acc[i][j] = {0.f, 0.f, 0.f, 0.f};

  int kk = 0;
  for (int ks = 0; ks < total; ++ks) {
    if (kk == kc) {
      kk = 0;
      if (++c0 == 3) { c0 = 0; if (++c1 == 3) { c1 = 0; if (++c2 == 3) { c2 = 0; ++c3; } } }
#pragma unroll
      for (int q = 0; q < 4; ++q) nb[q] = comp_nb(sm[q]);
      wbase += wstep;
    }
    int k0 = kk << 6;
    ++kk;
    __syncthreads();
#pragma unroll
    for (int q = 0; q < 4; ++q) {
      const u16* a = (nb[q] >= 0) ? X + (long)nb[q] * IC + k0 + cA[q] * 8 : ZP;
      gll16(a, &As[(wave * 4 + q) * 512]);
    }
#pragma unroll
    for (int q = 0; q < 4; ++q) {
      const u16* bsrc = wbase + (long)rp[q] * IC + k0 + cA[q] * 8;
      gll16(bsrc, &Bs[(wave * 4 + q) * 512]);
    }
    __syncthreads();
#pragma unroll
    for (int ksub = 0; ksub < 2; ++ksub) {
      bf16x8 af[4], bf[4];
#pragma unroll
      for (int i = 0; i < 4; ++i) {
        int row = mi * 64 + i * 16 + l15;
        int pa = ((ksub * 4 + quad) + (row >> 1)) & 7;
        af[i] = *(const bf16x8*)&As[row * 64 + pa * 8];
      }
#pragma unroll
      for (int j = 0; j < 4; ++j) {
        int row = ni * 64 + j * 16 + l15;
        int pb = ((ksub * 4 + quad) + (row >> 1)) & 7;
        bf[j] = *(const bf16x8*)&Bs[row * 64 + pb * 8];
      }
#pragma unroll
      for (int i = 0; i < 4; ++i)
#pragma unroll
        for (int j = 0; j < 4; ++j)
          acc[i][j] = __builtin_amdgcn_mfma_f32_16x16x32_bf16(af[i], bf[j], acc[i][j], 0, 0, 0);
    }
  }

  if (NSPLIT > 1) {
    float* out = SP + (long)blockIdx.z * M * OC;
#pragma unroll
    for (int j = 0; j < 4; ++j) {
      int c = oc0 + ni * 64 + j * 16 + l15;
#pragma unroll
      for (int i = 0; i < 4; ++i) {
        int rbase = m0 + mi * 64 + i * 16 + quad * 4;
#pragma unroll
        for (int r = 0; r < 4; ++r) {
          int row = rbase + r;
          if (row < M) out[(long)row * OC + c] = acc[i][j][r];
        }
      }
    }
  } else {
#pragma unroll
    for (int j = 0; j < 4; ++j) {
      int c = oc0 + ni * 64 + j * 16 + l15;
      float bj = bias[c];
#pragma unroll
      for (int i = 0; i < 4; ++i) {
        int rbase = m0 + mi * 64 + i * 16 + quad * 4;
#pragma unroll
        for (int r = 0; r < 4; ++r) {
          int row = rbase + r;
          if (row >= M) continue;
          float v = acc[i][j][r] + bj;
          if (flags & 2) v = fmaxf(v, 0.f);
          long off = (long)row * OC + c;
          if (flags & 4) ((u16*)Yv)[off] = f2bf(v);
          else if (flags & 1) ((float*)Yv)[off] += v;
          else ((float*)Yv)[off] = v;
        }
      }
    }
  }
}

// ---- fragment-read / MFMA macros for the pipelined 256x256 kernel (constant indices only)
#define RDA1(reg, D) do {                                              \
    const u16* _p = Abase + ((reg) << 13) + 2048 + rA0;                \
    D[0] = *(const bf16x8*)(_p);                                       \
    D[1] = *(const bf16x8*)(_p + 512);                                 \
    D[2] = *(const bf16x8*)(_p + 1024);                                \
    D[3] = *(const bf16x8*)(_p + 1536);                                \
  } while (0)
#define RDAB(reg, DA, DB) do {                                         \
    const u16* _pa = Abase + ((reg) << 13) + rA0;                      \
    const u16* _pb = Bbase + ((reg) << 13) + rB0;                      \
    DA[0] = *(const bf16x8*)(_pa);                                     \
    DB[0] = *(const bf16x8*)(_pb);                                     \
    DB[1] = *(const bf16x8*)(_pb + 512);                               \
    DB[2] = *(const bf16x8*)(_pb + 1024);                              \
    DB[3] = *(const bf16x8*)(_pb + 1536);                              \
    DA[1] = *(const bf16x8*)(_pa + 512);                               \
    DA[2] = *(const bf16x8*)(_pa + 1024);                              \
    DA[3] = *(const bf16x8*)(_pa + 1536);                              \
  } while (0)
#define MF16(AF, BF, IB) do {                                          \
    __builtin_amdgcn_s_setprio(1);                                     \
    _Pragma("unroll") for (int _i = 0; _i < 4; ++_i)                   \
    _Pragma("unroll") for (int _j = 0; _j < 4; ++_j)                   \
      acc[(IB) + _i][_j] = __builtin_amdgcn_mfma_f32_16x16x32_bf16(    \
          AF[_i], BF[_j], acc[(IB) + _i][_j], 0, 0, 0);                \
    __builtin_amdgcn_s_setprio(0);                                     \
  } while (0)
#define SBAR __builtin_amdgcn_sched_barrier(0)

// ---------------- 256x256 pipelined conv-GEMM (T2+T3+T4+T5), BK=64, 8 waves ----------------
// Round-4 restructure: fragment reads SOFTWARE-PIPELINED one phase ahead into
// double-buffered register sets (afA/afB alternate per phase, bfA/bfB per half-tile).
// Phase body = { stage(1 call); ds_reads for NEXT phase; 16 MFMA on CURRENT regs;
// [vmcnt(6) on even phases]; barrier } with NO sched_barrier inside the phase -> the
// compiler interleaves reads+stage under the MFMA cluster (R3 was serial: reads ->
// barrier -> MFMA -> barrier = 1346 cyc/phase vs 620 cyc MFMA work). One barrier per
// phase (was 2). vmcnt(6): waited-on stage issued 3 phases earlier (~2400 cyc > HBM lat).
// Region/stage order identical to R3 -> hazard proofs carry over.
__global__ __launch_bounds__(512, 2) void k_conv_g256(
    const u16* __restrict__ X, const u16* __restrict__ W3,
    const float* __restrict__ bias, void* __restrict__ Yv, float* __restrict__ SP,
    const u16* __restrict__ ZP,
    int M, int IC, int OC, int mode, int NT, int NSPLIT,
    int lgWo, int lgHo, int lgDo,
    int lgWi, int lgHi, int lgDi,
    int Li, int Di, int Hi, int Wi,
    int sL, int sD, int sH, int sW, int flags) {
  __shared__ __align__(16) u16 Ab[4][8192];   // 64 KiB, region = half-tile & 3
  __shared__ __align__(16) u16 Bb[4][8192];   // 64 KiB
  int tid = threadIdx.x;
  int wave = tid >> 6, lane = tid & 63;
  int quad = lane >> 4, l15 = lane & 15;
  int wr = wave >> 2, wc = wave & 3;
  int m0 = blockIdx.x * 256, oc0 = blockIdx.y * 256;

  // staging geometry: thread covers rows srow0 and srow0+128, 16B phys chunk spc
  int srow0 = tid >> 2;
  int spc = tid & 3;
  int lc0 = (spc - (srow0 >> 1)) & 3;          // logical k-chunk at this slot
  int lc1 = (spc - ((srow0 + 128) >> 1)) & 3;

  int kc = IC >> 6;
  int hsPerTap = kc << 1;
  int tap_per = (NT + NSPLIT - 1) / NSPLIT;
  int t0 = blockIdx.z * tap_per;
  int t1 = min(NT, t0 + tap_per);
  int TOT = (t1 - t0) * kc;
  int HT = TOT * 2;                            // half-tiles (K=32 each); even for IC%128==0

  int c0 = t0 % 3, c1 = (t0 / 3) % 3, c2 = (t0 / 9) % 3, c3 = t0 / 27;
  auto comp_nb = [&](int smv) -> int {
    if (smv >= M) return -1;
    int w = smv & ((1 << lgWo) - 1);
    int h = (smv >> lgWo) & ((1 << lgHo) - 1);
    int d = (smv >> (lgWo + lgHo)) & ((1 << lgDo) - 1);
    int l = smv >> (lgWo + lgHo + lgDo);
    int li, di, hi, wi; bool ok;
    if (mode == 0) {
      int dl = c0 - 1;
      int ll = (l & 1) + dl;
      ok = (ll >= 0 && ll < 2);
      li = l + dl; di = d; hi = h; wi = w;
    } else if (mode == 1) {
      li = l * sL; di = d * sD + c2 - 1; hi = h * sH + c1 - 1; wi = w * sW + c0 - 1;
      ok = ((unsigned)di < (unsigned)Di) && ((unsigned)hi < (unsigned)Hi) &&
           ((unsigned)wi < (unsigned)Wi);
    } else {
      li = l + c3 - 1; di = d + c2 - 1; hi = h + c1 - 1; wi = w + c0 - 1;
      ok = ((unsigned)li < (unsigned)Li) && ((unsigned)di < (unsigned)Di) &&
           ((unsigned)hi < (unsigned)Hi) && ((unsigned)wi < (unsigned)Wi);
    }
    if (!ok) return -1;
    return (((li << lgDi) + di) << lgHi | hi) << lgWi | wi;
  };

  // ---- A staging state (gather; recompute on tap change only) ----
  int nb0 = comp_nb(m0 + srow0);
  int nb1 = comp_nb(m0 + srow0 + 128);
  const u16* ap0;
  const u16* ap1;
  auto setAp = [&]() {
    ap0 = (nb0 >= 0) ? X + (long)nb0 * IC + lc0 * 8 : ZP;
    ap1 = (nb1 >= 0) ? X + (long)nb1 * IC + lc1 * 8 : ZP;
  };
  setAp();
  int ahs = 0, sA = 0;
  u16* adst = &Ab[0][wave << 9];
  auto stageA = [&]() {
    u16* d = adst + ((sA & 3) << 13);
    ++sA;
    if (sA > HT) { gll16(ZP, d); gll16(ZP, d + 4096); return; }
    gll16(ap0 + (ahs << 5), d);
    gll16(ap1 + (ahs << 5), d + 4096);
    if (++ahs == hsPerTap) {
      ahs = 0;
      if (++c0 == 3) { c0 = 0; if (++c1 == 3) { c1 = 0; if (++c2 == 3) { c2 = 0; ++c3; } } }
      nb0 = comp_nb(m0 + srow0);
      nb1 = comp_nb(m0 + srow0 + 128);
      setAp();
    }
  };

  // ---- B staging state (rolling pointer) ----
  long wstep = (long)OC * IC;
  const u16* bp = W3 + ((long)t0 * OC + oc0 + srow0) * IC + lc0 * 8;
  long bdlt = (long)128 * IC + (lc1 - lc0) * 8;
  long btap = wstep - (long)(hsPerTap - 1) * 32;
  int bhs = 0, sB = 0;
  u16* bdst = &Bb[0][wave << 9];
  auto stageB = [&]() {
    u16* d = bdst + ((sB & 3) << 13);
    ++sB;
    if (sB > HT) { gll16(ZP, d); gll16(ZP, d + 4096); return; }
    gll16(bp, d);
    gll16(bp + bdlt, d + 4096);
    if (++bhs == hsPerTap) { bhs = 0; bp += btap; }
    else bp += 32;
  };

  // ---- precomputed LDS read bases (swizzle chunk invariant under row+16/+64) ----
  int rowA0 = (wr << 7) + l15;
  int rA0 = rowA0 * 32 + (((quad + (rowA0 >> 1)) & 3) << 3);
  int rowB0 = (wc << 6) + l15;
  int rB0 = rowB0 * 32 + (((quad + (rowB0 >> 1)) & 3) << 3);
  const u16* Abase = &Ab[0][0];
  const u16* Bbase = &Bb[0][0];

  f32x4 acc[8][4];
#pragma unroll
  for (int i = 0; i < 8; ++i)
#pragma unroll
    for (int j = 0; j < 4; ++j) acc[i][j] = {0.f, 0.f, 0.f, 0.f};

  bf16x8 afA[4], afB[4], bfA[4], bfB[4];

  // prologue: stage half-tiles 0..2 (12 loads); vmcnt(8) -> A0,B0 complete
  stageA(); stageB();
  stageA(); stageB();
  stageA(); stageB();
  asm volatile("s_waitcnt vmcnt(8)" ::: "memory");
  __builtin_amdgcn_s_barrier();
  SBAR;
  RDAB(0, afA, bfA);                            // frags for phase (0,0)

  for (int h = 0; h < HT; h += 2) {
    int r0 = h & 3, r1 = (h + 1) & 3, r2 = (h + 2) & 3;
    // ---- phase (h,0): compute afA x bfA -> acc[0..3]; load afB (region h, ih=1) ----
    stageA();
    RDA1(r0, afB);
    MF16(afA, bfA, 0);
    asm volatile("s_waitcnt vmcnt(6)" ::: "memory");
    SBAR;
    __builtin_amdgcn_s_barrier();
    SBAR;
    // ---- phase (h,1): compute afB x bfA -> acc[4..7]; load afA+bfB (region h+1) ----
    stageB();
    RDAB(r1, afA, bfB);
    MF16(afB, bfA, 4);
    SBAR;
    __builtin_amdgcn_s_barrier();
    SBAR;
    // ---- phase (h+1,0): compute afA x bfB -> acc[0..3]; load afB (region h+1, ih=1) ----
    stageA();
    RDA1(r1, afB);
    MF16(afA, bfB, 0);
    asm volatile("s_waitcnt vmcnt(6)" ::: "memory");
    SBAR;
    __builtin_amdgcn_s_barrier();
    SBAR;
    // ---- phase (h+1,1): compute afB x bfB -> acc[4..7]; load afA+bfA (region h+2) ----
    stageB();
    RDAB(r2, afA, bfA);
    MF16(afB, bfB, 4);
    SBAR;
    __builtin_amdgcn_s_barrier();
    SBAR;
  }

  // epilogue: C/D layout col=l15, row=quad*4+r
  if (NSPLIT > 1) {
    float* outp = SP + (long)blockIdx.z * M * OC;
#pragma unroll
    for (int i = 0; i < 8; ++i)
#pragma unroll
      for (int j = 0; j < 4; ++j) {
        int c = oc0 + (wc << 6) + (j << 4) + l15;
        int rb = m0 + (wr << 7) + (i << 4) + (quad << 2);
#pragma unroll
        for (int r = 0; r < 4; ++r) {
          int row = rb + r;
          if (row < M) outp[(long)row * OC + c] = acc[i][j][r];
        }
      }
  } else {
#pragma unroll
    for (int i = 0; i < 8; ++i)
#pragma unroll
      for (int j = 0; j < 4; ++j) {
        int c = oc0 + (wc << 6) + (j << 4) + l15;
        float bj = bias[c];
        int rb = m0 + (wr << 7) + (i << 4) + (quad << 2);
#pragma unroll
        for (int r = 0; r < 4; ++r) {
          int row = rb + r;
          if (row >= M) continue;
          float v = acc[i][j][r] + bj;
          if (flags & 2) v = fmaxf(v, 0.f);
          long off = (long)row * OC + c;
          if (flags & 4) ((u16*)Yv)[off] = f2bf(v);
          else if (flags & 1) ((float*)Yv)[off] += v;
          else ((float*)Yv)[off] = v;
        }
      }
  }
}

// ---------------- combine split-K partials: out = (sum_s SP[s]) + bias ----------------
__global__ __launch_bounds__(256) void k_combine(const float* __restrict__ SP,
                                                 const float* __restrict__ bias,
                                                 void* __restrict__ out,
                                                 long MOC, int lgOC, int nsplit, int flags) {
  long idx = (long)blockIdx.x * 256 + threadIdx.x;
  if (idx >= MOC) return;
  float v = bias[idx & ((1 << lgOC) - 1)];
  for (int s = 0; s < nsplit; ++s) v += SP[s * MOC + idx];
  if (flags & 2) v = fmaxf(v, 0.f);
  if (flags & 4) ((u16*)out)[idx] = f2bf(v);
  else if (flags & 1) ((float*)out)[idx] += v;
  else ((float*)out)[idx] = v;
}

// ---------------- TLG windowed cross attention: 8q x 8k per (window, head), bf16 ----------------
__global__ __launch_bounds__(256) void k_tlg_attn(const u16* __restrict__ Q,
                                                  const u16* __restrict__ K,
                                                  const u16* __restrict__ V,
                                                  u16* __restrict__ Y) {
  int gw = blockIdx.x * 4 + (threadIdx.x >> 6);
  int lane = threadIdx.x & 63;
  int head = gw & 7;
  int win = gw >> 3;
  int wB = win & 7, hB = (win >> 3) & 7, dB = (win >> 6) & 7, l = win >> 9;
  int i = lane >> 3, j = lane & 7;
  int nq = (l << 12) | ((dB * 2 + (i >> 2)) << 8) | ((hB * 2 + ((i >> 1) & 1)) << 4) |
           (wB * 2 + (i & 1));
  int lk = l ^ 2;
  int nk = (lk << 12) | ((dB * 2 + (j >> 2)) << 8) | ((hB * 2 + ((j >> 1) & 1)) << 4) |
           (wB * 2 + (j & 1));
  int hoff = head * 16;
  const u16* qp = Q + (long)nq * 128 + hoff;
  const u16* kp = K + (long)nk * 128 + hoff;
  float s = 0.f;
#pragma unroll
  for (int t = 0; t < 16; t += 4) {
    float4 a = load4bf(qp + t);
    float4 b = load4bf(kp + t);
    s += a.x * b.x + a.y * b.y + a.z * b.z + a.w * b.w;
  }
  s *= 0.25f;
  float mx = s;
#pragma unroll
  for (int o = 1; o < 8; o <<= 1) mx = fmaxf(mx, __shfl_xor(mx, o));
  float e = __expf(s - mx);
  float sum = e;
#pragma unroll
  for (int o = 1; o < 8; o <<= 1) sum += __shfl_xor(sum, o);
  float p = e / sum;
  const u16* vp = V + (long)nk * 128 + hoff;
  float y[16];
#pragma unroll
  for (int t = 0; t < 16; t += 4) {
    float4 vv = load4bf(vp + t);
    y[t] = p * vv.x; y[t + 1] = p * vv.y; y[t + 2] = p * vv.z; y[t + 3] = p * vv.w;
  }
#pragma unroll
  for (int o = 1; o < 8; o <<= 1) {
#pragma unroll
    for (int t = 0; t < 16; ++t) y[t] += __shfl_xor(y[t], o);
  }
  if (j == 0) {
    u16* yp = Y + (long)nq * 128 + hoff;
    u16 tmp[16];
#pragma unroll
    for (int t = 0; t < 16; ++t) tmp[t] = f2bf(y[t]);
    *(uint4*)(yp) = *(uint4*)tmp;
    *(uint4*)(yp + 8) = *(uint4*)(tmp + 8);
  }
}

// ---------------- SLG K/V repack for flash attn ----------------
__global__ __launch_bounds__(256) void k_pack_kh(const u16* __restrict__ Kin,
                                                 u16* __restrict__ Kh) {
  int idx = blockIdx.x * 256 + threadIdx.x;
  if (idx >= 8 * 1032 * 16) return;
  int d = idx & 15;
  int r = idx >> 4;
  int k = r % 1032, h = r / 1032;
  Kh[idx] = Kin[k * 128 + h * 16 + d];
}
__global__ __launch_bounds__(256) void k_pack_vt(const u16* __restrict__ Vin,
                                                 u16* __restrict__ Vt) {
  int idx = blockIdx.x * 256 + threadIdx.x;
  if (idx >= 8 * 16 * 1032) return;
  int k = idx % 1032;
  int r = idx / 1032;
  int d = r & 15, h = r >> 4;
  Vt[idx] = Vin[k * 128 + h * 16 + d];
}

// ---------------- SLG MFMA flash attention ----------------
__global__ __launch_bounds__(256) void k_slg_flash(const u16* __restrict__ Q,
                                                   const u16* __restrict__ Kh,
                                                   const u16* __restrict__ Vt,
                                                   u16* __restrict__ Y) {
  constexpr int NK = 1032;
  constexpr int NTILE = 17;
  __shared__ __align__(16) u16 Ks[64 * 24];
  __shared__ __align__(16) u16 Vs[16 * 72];
  __shared__ __align__(16) u16 Ps[4][16 * 72];
  int tid = threadIdx.x;
  int wave = tid >> 6, lane = tid & 63;
  int quad = lane >> 4, l15 = lane & 15;
  int h = blockIdx.x & 7;
  int q0 = (blockIdx.x >> 3) * 64 + wave * 16;

  const bf16x8 Zb = {0, 0, 0, 0, 0, 0, 0, 0};
  bf16x8 qf = Zb;
  if (quad < 2) qf = *(const bf16x8*)(Q + (long)(q0 + l15) * 128 + h * 16 + quad * 8);

  const u16* Kbase = Kh + (long)h * NK * 16;
  const u16* Vbase = Vt + (long)h * 16 * NK;

  float mrow[4], lrow[4];
  f32x4 oacc = {0.f, 0.f, 0.f, 0.f};
#pragma unroll
  for (int r = 0; r < 4; ++r) { mrow[r] = -1e30f; lrow[r] = 0.f; }

  int skey = tid >> 2, sch = (tid & 3) * 4;
  int svd = tid >> 4, svc = (tid & 15) * 4;

  for (int t = 0; t < NTILE; ++t) {
    int k0 = t * 64;
    __syncthreads();
    {
      short4 v = {0, 0, 0, 0};
      int key = k0 + skey;
      if (key < NK) v = *(const short4*)(Kbase + key * 16 + sch);
      *(short4*)&Ks[skey * 24 + sch] = v;
    }
    {
      short4 v = {0, 0, 0, 0};
      int colb = k0 + svc;
      if (colb < NK) v = *(const short4*)(Vbase + svd * NK + colb);
      *(short4*)&Vs[svd * 72 + svc] = v;
    }
    __syncthreads();

    f32x4 s[4];
#pragma unroll
    for (int sub = 0; sub < 4; ++sub) {
      bf16x8 b = Zb;
      if (quad < 2) b = *(const bf16x8*)&Ks[(sub * 16 + l15) * 24 + quad * 8];
      f32x4 zero = {0.f, 0.f, 0.f, 0.f};
      s[sub] = __builtin_amdgcn_mfma_f32_16x16x32_bf16(qf, b, zero, 0, 0, 0);
    }
    float pv[4][4];
    float tmax[4] = {-1e30f, -1e30f, -1e30f, -1e30f};
#pragma unroll
    for (int sub = 0; sub < 4; ++sub) {
      int key = k0 + sub * 16 + l15;
      bool valid = key < NK;
#pragma unroll
      for (int r = 0; r < 4; ++r) {
        float sv = valid ? s[sub][r] * 0.25f : -1e30f;
        pv[sub][r] = sv;
        tmax[r] = fmaxf(tmax[r], sv);
      }
    }
#pragma unroll
    for (int o = 1; o < 16; o <<= 1)
#pragma unroll
      for (int r = 0; r < 4; ++r) tmax[r] = fmaxf(tmax[r], __shfl_xor(tmax[r], o));

    float al[4], tsum[4] = {0.f, 0.f, 0.f, 0.f};
#pragma unroll
    for (int r = 0; r < 4; ++r) {
      float mn = fmaxf(mrow[r], tmax[r]);
      al[r] = __expf(mrow[r] - mn);
      mrow[r] = mn;
    }
#pragma unroll
    for (int sub = 0; sub < 4; ++sub)
#pragma unroll
      for (int r = 0; r < 4; ++r) {
        float pe = __expf(pv[sub][r] - mrow[r]);
        tsum[r] += pe;
        Ps[wave][(quad * 4 + r) * 72 + sub * 16 + l15] = f2bf(pe);
      }
#pragma unroll
    for (int o = 1; o < 16; o <<= 1)
#pragma unroll
      for (int r = 0; r < 4; ++r) tsum[r] += __shfl_xor(tsum[r], o);
#pragma unroll
    for (int r = 0; r < 4; ++r) {
      lrow[r] = lrow[r] * al[r] + tsum[r];
      oacc[r] *= al[r];
    }
    bf16x8 pa0 = *(const bf16x8*)&Ps[wave][l15 * 72 + quad * 8];
    bf16x8 pa1 = *(const bf16x8*)&Ps[wave][l15 * 72 + 32 + quad * 8];
    bf16x8 vb0 = *(const bf16x8*)&Vs[l15 * 72 + quad * 8];
    bf16x8 vb1 = *(const bf16x8*)&Vs[l15 * 72 + 32 + quad * 8];
    oacc = __builtin_amdgcn_mfma_f32_16x16x32_bf16(pa0, vb0, oacc, 0, 0, 0);
    oacc = __builtin_amdgcn_mfma_f32_16x16x32_bf16(pa1, vb1, oacc, 0, 0, 0);
  }

#pragma unroll
  for (int r = 0; r < 4; ++r) {
    float inv = 1.0f / lrow[r];
    Y[(long)(q0 + quad * 4 + r) * 128 + h * 16 + l15] = f2bf(oacc[r] * inv);
  }
}

static inline int ilg(int v) { int r = 0; while ((1 << r) < v) ++r; return r; }

extern "C" void kernel_launch(void* const* d_in, const int* in_sizes, int n_in,
                              void* d_out, int out_size, void* d_ws, size_t ws_size,
                              hipStream_t stream) {
  (void)in_sizes; (void)n_in; (void)out_size; (void)ws_size;
  const float* x    = (const float*)d_in[0];
  const float* n1_w = (const float*)d_in[1];  const float* n1_b = (const float*)d_in[2];
  const float* n2_w = (const float*)d_in[3];  const float* n2_b = (const float*)d_in[4];
  const float* n3_w = (const float*)d_in[5];  const float* n3_b = (const float*)d_in[6];
  const float* sn_w = (const float*)d_in[7];  const float* sn_b = (const float*)d_in[8];
  const float* tq_w = (const float*)d_in[9];  const float* tq_b = (const float*)d_in[10];
  const float* tk_w = (const float*)d_in[11]; const float* tk_b = (const float*)d_in[12];
  const float* tv_w = (const float*)d_in[13]; const float* tv_b = (const float*)d_in[14];
  const float* tp_w = (const float*)d_in[15]; const float* tp_b = (const float*)d_in[16];
  const float* sq_w = (const float*)d_in[17]; const float* sq_b = (const float*)d_in[18];
  const float* sk_w = (const float*)d_in[19]; const float* sk_b = (const float*)d_in[20];
  const float* sv_w = (const float*)d_in[21]; const float* sv_b = (const float*)d_in[22];
  const float* sp_w = (const float*)d_in[23]; const float* sp_b = (const float*)d_in[24];
  const float* sf_w = (const float*)d_in[25]; const float* sf_b = (const float*)d_in[26];
  const float* sc_w = (const float*)d_in[27]; const float* sc_b = (const float*)d_in[28];
  const float* m1_w = (const float*)d_in[29]; const float* m1_b = (const float*)d_in[30];
  const float* m2_w = (const float*)d_in[31]; const float* m2_b = (const float*)d_in[32];

  char* p = (char*)d_ws;
  auto alloc = [&](size_t bytes) { char* r = p; p += (bytes + 255) & ~(size_t)255; return r; };
  const long N = 16384;
  float* X0 = (float*)alloc(N * 128 * 4);
  u16* XN = (u16*)alloc(N * 128 * 2);
  u16* Qb = (u16*)alloc(N * 128 * 2);
  u16* Kb = (u16*)alloc(N * 128 * 2);
  u16* Vb = (u16*)alloc(N * 128 * 2);
  u16* Yb = (u16*)alloc(N * 128 * 2);
  u16* H  = (u16*)alloc(N * 512 * 2);
  u16* XC = (u16*)alloc(8 * 128 * 2);
  u16* XF = (u16*)alloc(1024 * 128 * 2);
  float* Kf = (float*)alloc(1032 * 128 * 4);
  float* Vf = (float*)alloc(1032 * 128 * 4);
  u16* Kh = (u16*)alloc(8 * 1032 * 16 * 2);
  u16* Vt = (u16*)alloc(8 * 16 * 1032 * 2);
  float* SPb = (float*)alloc(2L * N * 512 * 4);  // split-K partials (64 MB)
  u16* ZPb = (u16*)alloc(2048);                   // zero page for masked gather rows
  u16* tq2 = (u16*)alloc(49152 * 2);  u16* tk2 = (u16*)alloc(49152 * 2);
  u16* tv2 = (u16*)alloc(49152 * 2);  u16* tp2 = (u16*)alloc(49152 * 2);
  u16* sq2 = (u16*)alloc(442368 * 2); u16* sk2 = (u16*)alloc(442368 * 2);
  u16* sv2 = (u16*)alloc(442368 * 2); u16* sp2 = (u16*)alloc(442368 * 2);
  u16* sf2 = (u16*)alloc(442368 * 2); u16* sc2 = (u16*)alloc(442368 * 2);
  u16* m12 = (u16*)alloc(5308416L * 2);
  u16* m22 = (u16*)alloc(5308416L * 2);

  k_zeropage<<<1, 256, 0, stream>>>(ZPb);

  auto rp = [&](const float* W, u16* Wb, int OC, int IC, int NT) {
    dim3 g(OC, IC / 128);
    k_repack2<<<g, 256, 0, stream>>>(W, Wb, OC, IC, NT);
  };
  rp(tq_w, tq2, 128, 128, 3);  rp(tk_w, tk2, 128, 128, 3);
  rp(tv_w, tv2, 128, 128, 3);  rp(tp_w, tp2, 128, 128, 3);
  rp(sq_w, sq2, 128, 128, 27); rp(sk_w, sk2, 128, 128, 27);
  rp(sv_w, sv2, 128, 128, 27); rp(sp_w, sp2, 128, 128, 27);
  rp(sf_w, sf2, 128, 128, 27); rp(sc_w, sc2, 128, 128, 27);
  rp(m1_w, m12, 512, 128, 81); rp(m2_w, m22, 128, 512, 81);

  auto conv = [&](const u16* Xp, const u16* Wp, const float* Bp, void* Yp,
                  int M, int IC, int OC, int mode, int NT,
                  int Do, int Ho, int Wo, int Li, int Di, int Hi, int Wi,
                  int sL, int sD, int sH, int sW, int flags) {
    int lgWo = ilg(Wo), lgHo = ilg(Ho), lgDo = ilg(Do);
    int lgWi = ilg(Wi), lgHi = ilg(Hi), lgDi = ilg(Di);
    dim3 g((M + 63) / 64, OC / 64);
    k_conv_mfma<<<g, 256, 0, stream>>>(Xp, Wp, Bp, Yp, M, IC, OC, mode, NT,
                                       lgWo, lgHo, lgDo, lgWi, lgHi, lgDi,
                                       Li, Di, Hi, Wi, sL, sD, sH, sW, flags);
  };
  auto conv_gl = [&](const u16* Xp, const u16* Wp, const float* Bp, void* Yp,
                     int M, int IC, int OC, int mode, int NT, int nsplit, int flags) {
    dim3 g(M / 128, OC / 128, nsplit);
    k_conv_gl<<<g, 256, 0, stream>>>(Xp, Wp, Bp, Yp, SPb, ZPb, M, IC, OC, mode, NT, nsplit,
                                     4, 4, 4, 4, 4, 4, 4, 16, 16, 16, 1, 1, 1, 1, flags);
    if (nsplit > 1) {
      long MOC = (long)M * OC;
      k_combine<<<(int)((MOC + 255) / 256), 256, 0, stream>>>(SPb, Bp, Yp, MOC, ilg(OC),
                                                              nsplit, flags);
    }
  };
  // 256x256 pipelined kernel (needs M%256==0 and OC%256==0)
  auto conv_gl256 = [&](const u16* Xp, const u16* Wp, const float* Bp, void* Yp,
                        int M, int IC, int OC, int mode, int NT, int nsplit, int flags) {
    dim3 g(M / 256, OC / 256, nsplit);
    k_conv_g256<<<g, 512, 0, stream>>>(Xp, Wp, Bp, Yp, SPb, ZPb, M, IC, OC, mode, NT, nsplit,
                                       4, 4, 4, 4, 4, 4, 4, 16, 16, 16, 1, 1, 1, 1, flags);
    if (nsplit > 1) {
      long MOC = (long)M * OC;
      k_combine<<<(int)((MOC + 255) / 256), 256, 0, stream>>>(SPb, Bp, Yp, MOC, ilg(OC),
                                                              nsplit, flags);
    }
  };

  k_tin<<<dim3(128, 4, 4), 256, 0, stream>>>(x, X0);

  // ---- TLG branch ----
  k_ln_f2b<<<4096, 256, 0, stream>>>(X0, n1_w, n1_b, XN, 16384);
  conv_gl(XN, tq2, tq_b, Qb, 16384, 128, 128, 0, 3, 3, 4);
  conv_gl(XN, tk2, tk_b, Kb, 16384, 128, 128, 0, 3, 3, 4);
  conv_gl(XN, tv2, tv_b, Vb, 16384, 128, 128, 0, 3, 3, 4);
  k_tlg_attn<<<4096, 256, 0, stream>>>(Qb, Kb, Vb, Yb);
  conv_gl(Yb, tp2, tp_b, X0, 16384, 128, 128, 0, 3, 3, 1);

  // ---- SLG branch ----
  k_ln_f2b<<<4096, 256, 0, stream>>>(X0, n2_w, n2_b, XN, 16384);
  conv_gl(XN, sq2, sq_b, Qb, 16384, 128, 128, 1, 27, 7, 4);
  conv(XN, sc2, sc_b, XC, 8,    128, 128, 1, 27, 2, 2, 2,   4, 16, 16, 16, 4, 8, 8, 8, 4);
  conv(XN, sf2, sf_b, XF, 1024, 128, 128, 1, 27, 8, 8, 8,   4, 16, 16, 16, 2, 2, 2, 2, 4);
  conv(XC, sk2, sk_b, Kf,            8,    128, 128, 1, 27, 2, 2, 2, 1, 2, 2, 2, 1, 1, 1, 1, 0);
  conv(XF, sk2, sk_b, Kf + 8 * 128,  1024, 128, 128, 1, 27, 8, 8, 8, 2, 8, 8, 8, 1, 1, 1, 1, 0);
  conv(XC, sv2, sv_b, Vf,            8,    128, 128, 1, 27, 2, 2, 2, 1, 2, 2, 2, 1, 1, 1, 1, 0);
  conv(XF, sv2, sv_b, Vf + 8 * 128,  1024, 128, 128, 1, 27, 8, 8, 8, 2, 8, 8, 8, 1, 1, 1, 1, 0);
  k_ln_f2b<<<258, 256, 0, stream>>>(Kf, sn_w, sn_b, Kb, 1032);
  k_ln_f2b<<<258, 256, 0, stream>>>(Vf, sn_w, sn_b, Vb, 1032);
  k_pack_kh<<<516, 256, 0, stream>>>(Kb, Kh);
  k_pack_vt<<<516, 256, 0, stream>>>(Vb, Vt);
  k_slg_flash<<<2048, 256, 0, stream>>>(Qb, Kh, Vt, Yb);
  conv_gl(Yb, sp2, sp_b, X0, 16384, 128, 128, 1, 27, 7, 1);

  // ---- MLP branch ----
  k_ln_f2b<<<4096, 256, 0, stream>>>(X0, n3_w, n3_b, XN, 16384);
  conv_gl256(XN, m12, m1_b, H, 16384, 128, 512, 2, 81, 2, 6);
  conv_gl(H, m22, m2_b, X0, 16384, 512, 128, 2, 81, 8, 1);

  k_tout<<<dim3(128, 4, 4), 256, 0, stream>>>(X0, (float*)d_out);
}

// Round 5
// 1018.796 us; speedup vs baseline: 1.1968x; 1.1968x over previous
//
#include <hip/hip_runtime.h>

typedef unsigned short u16;
typedef __attribute__((ext_vector_type(8))) short bf16x8;
typedef __attribute__((ext_vector_type(4))) float f32x4;

#define PITCH 40   // small-conv kernel LDS pitch (shorts)

__device__ __forceinline__ u16 f2bf(float f) {
  union { float f; unsigned u; } v; v.f = f;
  unsigned r = v.u + 0x7fffu + ((v.u >> 16) & 1u);
  return (u16)(r >> 16);
}
__device__ __forceinline__ float bf2f(u16 h) {
  union { unsigned u; float f; } v; v.u = ((unsigned)h) << 16;
  return v.f;
}
__device__ __forceinline__ float4 load4bf(const u16* p) {
  ushort4 h = *(const ushort4*)p;
  return make_float4(bf2f(h.x), bf2f(h.y), bf2f(h.z), bf2f(h.w));
}
// async global->LDS, 16B per lane; LDS dest = wave-uniform base + lane*16
__device__ __forceinline__ void gll16(const u16* g, u16* l) {
  __builtin_amdgcn_global_load_lds(
      (const __attribute__((address_space(1))) unsigned int*)g,
      (__attribute__((address_space(3))) unsigned int*)l, 16, 0, 0);
}

// ---------------- tiled transpose (l,c,s) -> token-major [(l,s), c] fp32 ----------------
__global__ __launch_bounds__(256) void k_tin(const float* __restrict__ x,
                                             float* __restrict__ xt) {
  __shared__ float t[32][33];
  int s0 = blockIdx.x * 32, c0 = blockIdx.y * 32, l = blockIdx.z;
  int r = threadIdx.x >> 3, q4 = (threadIdx.x & 7) * 4;
  float4 v = *(const float4*)(x + ((long)(l * 128 + c0 + r) << 12) + s0 + q4);
  t[r][q4] = v.x; t[r][q4 + 1] = v.y; t[r][q4 + 2] = v.z; t[r][q4 + 3] = v.w;
  __syncthreads();
  float4 o = {t[q4][r], t[q4 + 1][r], t[q4 + 2][r], t[q4 + 3][r]};
  *(float4*)(xt + ((long)(l * 4096 + s0 + r) << 7) + c0 + q4) = o;
}

__global__ __launch_bounds__(256) void k_tout(const float* __restrict__ xt,
                                              float* __restrict__ out) {
  __shared__ float t[32][33];
  int s0 = blockIdx.x * 32, c0 = blockIdx.y * 32, l = blockIdx.z;
  int r = threadIdx.x >> 3, q4 = (threadIdx.x & 7) * 4;
  float4 v = *(const float4*)(xt + ((long)(l * 4096 + s0 + r) << 7) + c0 + q4);
  t[r][q4] = v.x; t[r][q4 + 1] = v.y; t[r][q4 + 2] = v.z; t[r][q4 + 3] = v.w;
  __syncthreads();
  float4 o = {t[q4][r], t[q4 + 1][r], t[q4 + 2][r], t[q4 + 3][r]};
  *(float4*)(out + ((long)(l * 128 + c0 + r) << 12) + s0 + q4) = o;
}

__global__ __launch_bounds__(256) void k_zeropage(u16* __restrict__ zp) {
  zp[threadIdx.x] = 0; zp[threadIdx.x + 256] = 0;
  zp[threadIdx.x + 512] = 0; zp[threadIdx.x + 768] = 0;
}

// ---------------- layernorm fp32 in -> bf16 out, one wave per row; dual-output ----------------
__global__ __launch_bounds__(256) void k_ln_f2b(const float* __restrict__ X,
                                                const float* __restrict__ g,
                                                const float* __restrict__ b,
                                                u16* __restrict__ Y, int M,
                                                u16* __restrict__ Y2, int M1) {
  int n = blockIdx.x * 4 + (threadIdx.x >> 6);
  if (n >= M) return;
  int lane = threadIdx.x & 63;
  const float* row = X + (long)n * 128;
  float2 v = *(const float2*)(row + lane * 2);
  float s = v.x + v.y;
#pragma unroll
  for (int o = 32; o > 0; o >>= 1) s += __shfl_xor(s, o);
  float mu = s * (1.0f / 128.0f);
  float dx = v.x - mu, dy = v.y - mu;
  float q = dx * dx + dy * dy;
#pragma unroll
  for (int o = 32; o > 0; o >>= 1) q += __shfl_xor(q, o);
  float rs = rsqrtf(q * (1.0f / 128.0f) + 1e-5f);
  float2 gv = *(const float2*)(g + lane * 2);
  float2 bv = *(const float2*)(b + lane * 2);
  ushort2 o2;
  o2.x = f2bf(dx * rs * gv.x + bv.x);
  o2.y = f2bf(dy * rs * gv.y + bv.y);
  u16* yp = (n < M1) ? Y + (long)n * 128 : Y2 + (long)(n - M1) * 128;
  *(ushort2*)(yp + lane * 2) = o2;
}

// ---------------- coalesced weight repack: W[oc][ic][t] fp32 -> Wb[t][oc][ic] bf16 ----------
__global__ __launch_bounds__(256) void k_repack2(const float* __restrict__ W,
                                                 u16* __restrict__ Wb,
                                                 int OC, int IC, int NT) {
  __shared__ float ws[128 * 81];
  int oc = blockIdx.x, ic0 = blockIdx.y * 128;
  const float* src = W + ((long)oc * IC + ic0) * NT;
  int n = 128 * NT;
  for (int i = threadIdx.x; i < n; i += 256) ws[i] = src[i];
  __syncthreads();
  u16* dst = Wb + (long)oc * IC + ic0;
  long tstep = (long)OC * IC;
  for (int idx = threadIdx.x; idx < n; idx += 256) {
    int t = idx >> 7, i = idx & 127;
    dst[(long)t * tstep + i] = f2bf(ws[i * NT + t]);
  }
}

// multi-slot repack for the 128x128 weights (blockIdx.z selects slot)
struct RPargs { const float* w[6]; u16* wb[6]; };
__global__ __launch_bounds__(256) void k_repack_multi(RPargs a, int NT) {
  __shared__ float ws[128 * 27];
  int oc = blockIdx.x, slot = blockIdx.z;
  const int IC = 128;
  const float* src = a.w[slot] + (long)oc * IC * NT;
  int n = IC * NT;
  for (int i = threadIdx.x; i < n; i += 256) ws[i] = src[i];
  __syncthreads();
  u16* dst = a.wb[slot] + (long)oc * IC;
  long tstep = (long)128 * IC;
  for (int idx = threadIdx.x; idx < n; idx += 256) {
    int t = idx >> 7, i = idx & 127;
    dst[(long)t * tstep + i] = f2bf(ws[i * NT + t]);
  }
}

// ---------------- small conv-as-gather-GEMM (64 x 64 tile) for small M ----------------
// multi-group: blockIdx.z selects weight (+wgs), bias (biasB), fp32 output (+ygs floats)
__global__ __launch_bounds__(256) void k_conv_mfma(
    const u16* __restrict__ X, const u16* __restrict__ W3,
    const float* __restrict__ bias, void* __restrict__ Yv,
    int M, int IC, int OC, int mode, int NT,
    int lgWo, int lgHo, int lgDo,
    int lgWi, int lgHi, int lgDi,
    int Li, int Di, int Hi, int Wi,
    int sL, int sD, int sH, int sW, int flags,
    long wgs, long ygs, const float* __restrict__ biasB) {
  __shared__ u16 As[64 * PITCH];
  __shared__ u16 Bs[64 * PITCH];
  int tid = threadIdx.x;
  int wave = tid >> 6, lane = tid & 63;
  int quad = lane >> 4, l15 = lane & 15;
  int m0 = blockIdx.x * 64;
  int oc0 = blockIdx.y * 64;
  int grp = blockIdx.z;
  W3 += (long)grp * wgs;
  if (grp) { bias = biasB; Yv = (void*)((float*)Yv + (long)grp * ygs); }

  int srl = tid >> 2;
  int sao = (tid & 3) * 8;
  int sboc = tid >> 2, sbo = (tid & 3) * 8;

  int sm = m0 + srl;
  bool mv = sm < M;
  int w = sm & ((1 << lgWo) - 1);
  int h = (sm >> lgWo) & ((1 << lgHo) - 1);
  int d = (sm >> (lgWo + lgHo)) & ((1 << lgDo) - 1);
  int l = sm >> (lgWo + lgHo + lgDo);

  int c0 = 0, c1 = 0, c2 = 0, c3 = 0;
  auto comp_nb = [&]() -> long {
    if (!mv) return -1;
    int li, di, hi, wi; bool ok;
    if (mode == 0) {
      int dl = c0 - 1;
      int ll = (l & 1) + dl;
      ok = (ll >= 0 && ll < 2);
      li = l + dl; di = d; hi = h; wi = w;
    } else if (mode == 1) {
      li = l * sL; di = d * sD + c2 - 1; hi = h * sH + c1 - 1; wi = w * sW + c0 - 1;
      ok = ((unsigned)di < (unsigned)Di) && ((unsigned)hi < (unsigned)Hi) &&
           ((unsigned)wi < (unsigned)Wi);
    } else {
      li = l + c3 - 1; di = d + c2 - 1; hi = h + c1 - 1; wi = w + c0 - 1;
      ok = ((unsigned)li < (unsigned)Li) && ((unsigned)di < (unsigned)Di) &&
           ((unsigned)hi < (unsigned)Hi) && ((unsigned)wi < (unsigned)Wi);
    }
    if (!ok) return -1;
    return ((((long)((li << lgDi) + di) << lgHi) + hi) << lgWi) + wi;
  };

  long nb = comp_nb();
  const u16* wt = W3 + (long)(oc0 + sboc) * IC + sbo;
  long wstep = (long)OC * IC;
  int kmask = (IC >> 5) - 1;
  int total = NT * (IC >> 5);

  const bf16x8 Z = {0, 0, 0, 0, 0, 0, 0, 0};
  bf16x8 ra0 = Z, rb;
  if (nb >= 0) ra0 = *(const bf16x8*)(X + nb * IC + sao);
  rb = *(const bf16x8*)wt;

  f32x4 acc[4];
#pragma unroll
  for (int j = 0; j < 4; ++j) acc[j] = {0.f, 0.f, 0.f, 0.f};

  int wrow = wave * 16;

  for (int ks = 0; ks < total; ++ks) {
    __syncthreads();
    *(bf16x8*)&As[srl * PITCH + sao] = ra0;
    *(bf16x8*)&Bs[sboc * PITCH + sbo] = rb;
    __syncthreads();
    int ksn = ks + 1;
    if (ksn < total) {
      int k0n = (ksn & kmask) << 5;
      if ((ksn & kmask) == 0) {
        wt += wstep;
        if (++c0 == 3) { c0 = 0; if (++c1 == 3) { c1 = 0; if (++c2 == 3) { c2 = 0; ++c3; } } }
        nb = comp_nb();
      }
      ra0 = Z;
      if (nb >= 0) ra0 = *(const bf16x8*)(X + nb * IC + k0n + sao);
      rb = *(const bf16x8*)(wt + k0n);
    }
    bf16x8 a0 = *(const bf16x8*)&As[(wrow + l15) * PITCH + quad * 8];
#pragma unroll
    for (int j = 0; j < 4; ++j) {
      bf16x8 b = *(const bf16x8*)&Bs[(j * 16 + l15) * PITCH + quad * 8];
      acc[j] = __builtin_amdgcn_mfma_f32_16x16x32_bf16(a0, b, acc[j], 0, 0, 0);
    }
  }

  int col = oc0 + l15;
#pragma unroll
  for (int j = 0; j < 4; ++j) {
    float bj = bias[col + j * 16];
    int rbase = m0 + wrow + quad * 4;
#pragma unroll
    for (int r = 0; r < 4; ++r) {
      int row = rbase + r;
      if (row >= M) continue;
      float v = acc[j][r] + bj;
      if (flags & 2) v = fmaxf(v, 0.f);
      long off = (long)row * OC + col + j * 16;
      if (flags & 4) ((u16*)Yv)[off] = f2bf(v);
      else if (flags & 1) ((float*)Yv)[off] += v;
      else ((float*)Yv)[off] = v;
    }
  }
}

// ---------------- big conv-GEMM: 128x128 tile, BK=64, single-buffer global_load_lds ----------
// multi-group: blockIdx.z = grp*NSPLIT + split; grp selects weight (+wgs) and SP region.
__global__ __launch_bounds__(256, 4) void k_conv_gl(
    const u16* __restrict__ X, const u16* __restrict__ W3,
    const float* __restrict__ bias, void* __restrict__ Yv, float* __restrict__ SP,
    const u16* __restrict__ ZP,
    int M, int IC, int OC, int mode, int NT, int NSPLIT, long wgs,
    int lgWo, int lgHo, int lgDo,
    int lgWi, int lgHi, int lgDi,
    int Li, int Di, int Hi, int Wi,
    int sL, int sD, int sH, int sW, int flags) {
  __shared__ __align__(16) u16 As[128 * 64];
  __shared__ __align__(16) u16 Bs[128 * 64];
  int tid = threadIdx.x;
  int wave = tid >> 6, lane = tid & 63;
  int quad = lane >> 4, l15 = lane & 15;
  int m0 = blockIdx.x * 128, oc0 = blockIdx.y * 128;
  int mi = wave & 1, ni = wave >> 1;
  int zz = blockIdx.z;
  int grp = zz / NSPLIT, split = zz % NSPLIT;
  W3 += (long)grp * wgs;

  int rp[4], cA[4], sm[4];
#pragma unroll
  for (int q = 0; q < 4; ++q) {
    rp[q] = wave * 32 + q * 8 + (lane >> 3);
    cA[q] = ((lane & 7) - (rp[q] >> 1)) & 7;
    sm[q] = m0 + rp[q];
  }

  int tap_per = (NT + NSPLIT - 1) / NSPLIT;
  int t0 = split * tap_per;
  int t1 = min(NT, t0 + tap_per);
  int kc = IC >> 6;
  int total = (t1 - t0) * kc;

  int c0 = t0 % 3, c1 = (t0 / 3) % 3, c2 = (t0 / 9) % 3, c3 = t0 / 27;
  auto comp_nb = [&](int smv) -> int {
    if (smv >= M) return -1;
    int w = smv & ((1 << lgWo) - 1);
    int h = (smv >> lgWo) & ((1 << lgHo) - 1);
    int d = (smv >> (lgWo + lgHo)) & ((1 << lgDo) - 1);
    int l = smv >> (lgWo + lgHo + lgDo);
    int li, di, hi, wi; bool ok;
    if (mode == 0) {
      int dl = c0 - 1;
      int ll = (l & 1) + dl;
      ok = (ll >= 0 && ll < 2);
      li = l + dl; di = d; hi = h; wi = w;
    } else if (mode == 1) {
      li = l * sL; di = d * sD + c2 - 1; hi = h * sH + c1 - 1; wi = w * sW + c0 - 1;
      ok = ((unsigned)di < (unsigned)Di) && ((unsigned)hi < (unsigned)Hi) &&
           ((unsigned)wi < (unsigned)Wi);
    } else {
      li = l + c3 - 1; di = d + c2 - 1; hi = h + c1 - 1; wi = w + c0 - 1;
      ok = ((unsigned)li < (unsigned)Li) && ((unsigned)di < (unsigned)Di) &&
           ((unsigned)hi < (unsigned)Hi) && ((unsigned)wi < (unsigned)Wi);
    }
    if (!ok) return -1;
    return (((li << lgDi) + di) << lgHi | hi) << lgWi | wi;
  };

  int nb[4];
#pragma unroll
  for (int q = 0; q < 4; ++q) nb[q] = comp_nb(sm[q]);
  long wstep = (long)OC * IC;
  const u16* wbase = W3 + (long)t0 * wstep + (long)oc0 * IC;

  f32x4 acc[4][4];
#pragma unroll
  for (int i = 0; i < 4; ++i)
#pragma unroll
    for (int j = 0; j < 4; ++j) acc[i][j] = {0.f, 0.f, 0.f, 0.f};

  int kk = 0;
  for (int ks = 0; ks < total; ++ks) {
    if (kk == kc) {
      kk = 0;
      if (++c0 == 3) { c0 = 0; if (++c1 == 3) { c1 = 0; if (++c2 == 3) { c2 = 0; ++c3; } } }
#pragma unroll
      for (int q = 0; q < 4; ++q) nb[q] = comp_nb(sm[q]);
      wbase += wstep;
    }
    int k0 = kk << 6;
    ++kk;
    __syncthreads();
#pragma unroll
    for (int q = 0; q < 4; ++q) {
      const u16* a = (nb[q] >= 0) ? X + (long)nb[q] * IC + k0 + cA[q] * 8 : ZP;
      gll16(a, &As[(wave * 4 + q) * 512]);
    }
#pragma unroll
    for (int q = 0; q < 4; ++q) {
      const u16* bsrc = wbase + (long)rp[q] * IC + k0 + cA[q] * 8;
      gll16(bsrc, &Bs[(wave * 4 + q) * 512]);
    }
    __syncthreads();
#pragma unroll
    for (int ksub = 0; ksub < 2; ++ksub) {
      bf16x8 af[4], bf[4];
#pragma unroll
      for (int i = 0; i < 4; ++i) {
        int row = mi * 64 + i * 16 + l15;
        int pa = ((ksub * 4 + quad) + (row >> 1)) & 7;
        af[i] = *(const bf16x8*)&As[row * 64 + pa * 8];
      }
#pragma unroll
      for (int j = 0; j < 4; ++j) {
        int row = ni * 64 + j * 16 + l15;
        int pb = ((ksub * 4 + quad) + (row >> 1)) & 7;
        bf[j] = *(const bf16x8*)&Bs[row * 64 + pb * 8];
      }
#pragma unroll
      for (int i = 0; i < 4; ++i)
#pragma unroll
        for (int j = 0; j < 4; ++j)
          acc[i][j] = __builtin_amdgcn_mfma_f32_16x16x32_bf16(af[i], bf[j], acc[i][j], 0, 0, 0);
    }
  }

  if (NSPLIT > 1) {
    float* out = SP + (long)(grp * NSPLIT + split) * M * OC;
#pragma unroll
    for (int j = 0; j < 4; ++j) {
      int c = oc0 + ni * 64 + j * 16 + l15;
#pragma unroll
      for (int i = 0; i < 4; ++i) {
        int rbase = m0 + mi * 64 + i * 16 + quad * 4;
#pragma unroll
        for (int r = 0; r < 4; ++r) {
          int row = rbase + r;
          if (row < M) out[(long)row * OC + c] = acc[i][j][r];
        }
      }
    }
  } else {
#pragma unroll
    for (int j = 0; j < 4; ++j) {
      int c = oc0 + ni * 64 + j * 16 + l15;
      float bj = bias[c];
#pragma unroll
      for (int i = 0; i < 4; ++i) {
        int rbase = m0 + mi * 64 + i * 16 + quad * 4;
#pragma unroll
        for (int r = 0; r < 4; ++r) {
          int row = rbase + r;
          if (row >= M) continue;
          float v = acc[i][j][r] + bj;
          if (flags & 2) v = fmaxf(v, 0.f);
          long off = (long)row * OC + c;
          if (flags & 4) ((u16*)Yv)[off] = f2bf(v);
          else if (flags & 1) ((float*)Yv)[off] += v;
          else ((float*)Yv)[off] = v;
        }
      }
    }
  }
}

// ---------------- 256x256 8-phase conv-GEMM (R3 form: best measured), BK=64, 8 waves -------
// ds_reads issued before the phase barrier (pinned via sched_barrier); compiler emits
// counted lgkmcnt before dependent MFMA; vmcnt(8) twice per K-tile, never 0 in loop.
__global__ __launch_bounds__(512, 2) void k_conv_g256(
    const u16* __restrict__ X, const u16* __restrict__ W3,
    const float* __restrict__ bias, void* __restrict__ Yv, float* __restrict__ SP,
    const u16* __restrict__ ZP,
    int M, int IC, int OC, int mode, int NT, int NSPLIT,
    int lgWo, int lgHo, int lgDo,
    int lgWi, int lgHi, int lgDi,
    int Li, int Di, int Hi, int Wi,
    int sL, int sD, int sH, int sW, int flags) {
  __shared__ __align__(16) u16 Ab[4][8192];   // 64 KiB, region = buf*2+ks
  __shared__ __align__(16) u16 Bb[4][8192];   // 64 KiB
  int tid = threadIdx.x;
  int wave = tid >> 6, lane = tid & 63;
  int quad = lane >> 4, l15 = lane & 15;
  int wr = wave >> 2, wc = wave & 3;
  int m0 = blockIdx.x * 256, oc0 = blockIdx.y * 256;

  int srow0 = tid >> 2;
  int spc = tid & 3;
  int lc0 = (spc - (srow0 >> 1)) & 3;
  int lc1 = (spc - ((srow0 + 128) >> 1)) & 3;

  int kc = IC >> 6;
  int hsPerTap = kc << 1;
  int tap_per = (NT + NSPLIT - 1) / NSPLIT;
  int t0 = blockIdx.z * tap_per;
  int t1 = min(NT, t0 + tap_per);
  int TOT = (t1 - t0) * kc;
  int TOTH = TOT * 2;

  int c0 = t0 % 3, c1 = (t0 / 3) % 3, c2 = (t0 / 9) % 3, c3 = t0 / 27;
  auto comp_nb = [&](int smv) -> int {
    if (smv >= M) return -1;
    int w = smv & ((1 << lgWo) - 1);
    int h = (smv >> lgWo) & ((1 << lgHo) - 1);
    int d = (smv >> (lgWo + lgHo)) & ((1 << lgDo) - 1);
    int l = smv >> (lgWo + lgHo + lgDo);
    int li, di, hi, wi; bool ok;
    if (mode == 0) {
      int dl = c0 - 1;
      int ll = (l & 1) + dl;
      ok = (ll >= 0 && ll < 2);
      li = l + dl; di = d; hi = h; wi = w;
    } else if (mode == 1) {
      li = l * sL; di = d * sD + c2 - 1; hi = h * sH + c1 - 1; wi = w * sW + c0 - 1;
      ok = ((unsigned)di < (unsigned)Di) && ((unsigned)hi < (unsigned)Hi) &&
           ((unsigned)wi < (unsigned)Wi);
    } else {
      li = l + c3 - 1; di = d + c2 - 1; hi = h + c1 - 1; wi = w + c0 - 1;
      ok = ((unsigned)li < (unsigned)Li) && ((unsigned)di < (unsigned)Di) &&
           ((unsigned)hi < (unsigned)Hi) && ((unsigned)wi < (unsigned)Wi);
    }
    if (!ok) return -1;
    return (((li << lgDi) + di) << lgHi | hi) << lgWi | wi;
  };

  int nb0 = comp_nb(m0 + srow0);
  int nb1 = comp_nb(m0 + srow0 + 128);
  const u16* ap0;
  const u16* ap1;
  auto setAp = [&]() {
    ap0 = (nb0 >= 0) ? X + (long)nb0 * IC + lc0 * 8 : ZP;
    ap1 = (nb1 >= 0) ? X + (long)nb1 * IC + lc1 * 8 : ZP;
  };
  setAp();
  int ahs = 0, sA = 0;
  u16* adst = &Ab[0][wave << 9];
  auto stageA = [&]() {
    u16* d = adst + ((sA & 3) << 13);
    ++sA;
    if (sA > TOTH) { gll16(ZP, d); gll16(ZP, d + 4096); return; }
    gll16(ap0 + (ahs << 5), d);
    gll16(ap1 + (ahs << 5), d + 4096);
    if (++ahs == hsPerTap) {
      ahs = 0;
      if (++c0 == 3) { c0 = 0; if (++c1 == 3) { c1 = 0; if (++c2 == 3) { c2 = 0; ++c3; } } }
      nb0 = comp_nb(m0 + srow0);
      nb1 = comp_nb(m0 + srow0 + 128);
      setAp();
    }
  };

  long wstep = (long)OC * IC;
  const u16* bp = W3 + ((long)t0 * OC + oc0 + srow0) * IC + lc0 * 8;
  long bdlt = (long)128 * IC + (lc1 - lc0) * 8;
  long btap = wstep - (long)(hsPerTap - 1) * 32;
  int bhs = 0, sB = 0;
  u16* bdst = &Bb[0][wave << 9];
  auto stageB = [&]() {
    u16* d = bdst + ((sB & 3) << 13);
    ++sB;
    if (sB > TOTH) { gll16(ZP, d); gll16(ZP, d + 4096); return; }
    gll16(bp, d);
    gll16(bp + bdlt, d + 4096);
    if (++bhs == hsPerTap) { bhs = 0; bp += btap; }
    else bp += 32;
  };

  int rowA0 = (wr << 7) + l15;
  int rA0 = rowA0 * 32 + (((quad + (rowA0 >> 1)) & 3) << 3);
  int rowB0 = (wc << 6) + l15;
  int rB0 = rowB0 * 32 + (((quad + (rowB0 >> 1)) & 3) << 3);
  const u16* Abase = &Ab[0][0];
  const u16* Bbase = &Bb[0][0];

  f32x4 acc[8][4];
#pragma unroll
  for (int i = 0; i < 8; ++i)
#pragma unroll
    for (int j = 0; j < 4; ++j) acc[i][j] = {0.f, 0.f, 0.f, 0.f};

  bf16x8 af[4], bfr[4];
  auto rdAB = [&](int reg) {
    const u16* pA = Abase + (reg << 13) + rA0;
    const u16* pB = Bbase + (reg << 13) + rB0;
    af[0] = *(const bf16x8*)(pA);
    bfr[0] = *(const bf16x8*)(pB);
    bfr[1] = *(const bf16x8*)(pB + (1 << 9));
    bfr[2] = *(const bf16x8*)(pB + (2 << 9));
    bfr[3] = *(const bf16x8*)(pB + (3 << 9));
    af[1] = *(const bf16x8*)(pA + (1 << 9));
    af[2] = *(const bf16x8*)(pA + (2 << 9));
    af[3] = *(const bf16x8*)(pA + (3 << 9));
  };
  auto rdA = [&](int reg, int ih) {
    const u16* pA = Abase + (reg << 13) + (ih << 11) + rA0;
#pragma unroll
    for (int i = 0; i < 4; ++i) af[i] = *(const bf16x8*)(pA + (i << 9));
  };
  auto mf = [&](int ih) {
    __builtin_amdgcn_s_setprio(1);
#pragma unroll
    for (int i = 0; i < 4; ++i)
#pragma unroll
      for (int j = 0; j < 4; ++j)
        acc[(ih << 2) + i][j] =
            __builtin_amdgcn_mfma_f32_16x16x32_bf16(af[i], bfr[j], acc[(ih << 2) + i][j], 0, 0, 0);
    __builtin_amdgcn_s_setprio(0);
  };

  stageA(); stageB();
  stageA(); stageB();
  stageA(); stageB();
  asm volatile("s_waitcnt vmcnt(8)" ::: "memory");
  __builtin_amdgcn_s_barrier();

  for (int n = 0; n < TOT; ++n) {
    int rg = (n & 1) << 1;
    rdAB(rg);
    stageA();
    __builtin_amdgcn_sched_barrier(0);
    __builtin_amdgcn_s_barrier();
    mf(0);
    __builtin_amdgcn_s_barrier();
    rdA(rg, 1);
    stageB();
    __builtin_amdgcn_sched_barrier(0);
    __builtin_amdgcn_s_barrier();
    mf(1);
    __builtin_amdgcn_sched_barrier(0);
    asm volatile("s_waitcnt vmcnt(8)" ::: "memory");
    __builtin_amdgcn_s_barrier();
    rdAB(rg + 1);
    stageA();
    __builtin_amdgcn_sched_barrier(0);
    __builtin_amdgcn_s_barrier();
    mf(0);
    __builtin_amdgcn_s_barrier();
    rdA(rg + 1, 1);
    stageB();
    __builtin_amdgcn_sched_barrier(0);
    __builtin_amdgcn_s_barrier();
    mf(1);
    __builtin_amdgcn_sched_barrier(0);
    asm volatile("s_waitcnt vmcnt(8)" ::: "memory");
    __builtin_amdgcn_s_barrier();
  }

  if (NSPLIT > 1) {
    float* outp = SP + (long)blockIdx.z * M * OC;
#pragma unroll
    for (int i = 0; i < 8; ++i)
#pragma unroll
      for (int j = 0; j < 4; ++j) {
        int c = oc0 + (wc << 6) + (j << 4) + l15;
        int rb = m0 + (wr << 7) + (i << 4) + (quad << 2);
#pragma unroll
        for (int r = 0; r < 4; ++r) {
          int row = rb + r;
          if (row < M) outp[(long)row * OC + c] = acc[i][j][r];
        }
      }
  } else {
#pragma unroll
    for (int i = 0; i < 8; ++i)
#pragma unroll
      for (int j = 0; j < 4; ++j) {
        int c = oc0 + (wc << 6) + (j << 4) + l15;
        float bj = bias[c];
        int rb = m0 + (wr << 7) + (i << 4) + (quad << 2);
#pragma unroll
        for (int r = 0; r < 4; ++r) {
          int row = rb + r;
          if (row >= M) continue;
          float v = acc[i][j][r] + bj;
          if (flags & 2) v = fmaxf(v, 0.f);
          long off = (long)row * OC + c;
          if (flags & 4) ((u16*)Yv)[off] = f2bf(v);
          else if (flags & 1) ((float*)Yv)[off] += v;
          else ((float*)Yv)[off] = v;
        }
      }
  }
}

// ---------------- combine split-K partials: out = (sum_s SP[s]) + bias ----------------
__global__ __launch_bounds__(256) void k_combine(const float* __restrict__ SP,
                                                 const float* __restrict__ bias,
                                                 void* __restrict__ out,
                                                 long MOC, int lgOC, int nsplit, int flags) {
  long idx = (long)blockIdx.x * 256 + threadIdx.x;
  if (idx >= MOC) return;
  float v = bias[idx & ((1 << lgOC) - 1)];
  for (int s = 0; s < nsplit; ++s) v += SP[s * MOC + idx];
  if (flags & 2) v = fmaxf(v, 0.f);
  if (flags & 4) ((u16*)out)[idx] = f2bf(v);
  else if (flags & 1) ((float*)out)[idx] += v;
  else ((float*)out)[idx] = v;
}

// 3-group combine: outputs adjacent, MOC a power of two (lgMOC); bias per group
__global__ __launch_bounds__(256) void k_combine3(const float* __restrict__ SP,
                                                  const float* __restrict__ b0,
                                                  const float* __restrict__ b1,
                                                  const float* __restrict__ b2,
                                                  u16* __restrict__ out,
                                                  int lgMOC, int lgOC, int nsplit, int ngrp) {
  long idx = (long)blockIdx.x * 256 + threadIdx.x;
  long tot = (long)ngrp << lgMOC;
  if (idx >= tot) return;
  int grp = (int)(idx >> lgMOC);
  long sub = idx & ((1L << lgMOC) - 1);
  const float* bp = (grp == 0) ? b0 : ((grp == 1) ? b1 : b2);
  float v = bp[sub & ((1 << lgOC) - 1)];
  const float* sp = SP + (((long)grp * nsplit) << lgMOC);
  for (int s = 0; s < nsplit; ++s) v += sp[((long)s << lgMOC) + sub];
  out[idx] = f2bf(v);
}

// ---------------- TLG windowed cross attention: 8q x 8k per (window, head), bf16 ----------------
__global__ __launch_bounds__(256) void k_tlg_attn(const u16* __restrict__ Q,
                                                  const u16* __restrict__ K,
                                                  const u16* __restrict__ V,
                                                  u16* __restrict__ Y) {
  int gw = blockIdx.x * 4 + (threadIdx.x >> 6);
  int lane = threadIdx.x & 63;
  int head = gw & 7;
  int win = gw >> 3;
  int wB = win & 7, hB = (win >> 3) & 7, dB = (win >> 6) & 7, l = win >> 9;
  int i = lane >> 3, j = lane & 7;
  int nq = (l << 12) | ((dB * 2 + (i >> 2)) << 8) | ((hB * 2 + ((i >> 1) & 1)) << 4) |
           (wB * 2 + (i & 1));
  int lk = l ^ 2;
  int nk = (lk << 12) | ((dB * 2 + (j >> 2)) << 8) | ((hB * 2 + ((j >> 1) & 1)) << 4) |
           (wB * 2 + (j & 1));
  int hoff = head * 16;
  const u16* qp = Q + (long)nq * 128 + hoff;
  const u16* kp = K + (long)nk * 128 + hoff;
  float s = 0.f;
#pragma unroll
  for (int t = 0; t < 16; t += 4) {
    float4 a = load4bf(qp + t);
    float4 b = load4bf(kp + t);
    s += a.x * b.x + a.y * b.y + a.z * b.z + a.w * b.w;
  }
  s *= 0.25f;
  float mx = s;
#pragma unroll
  for (int o = 1; o < 8; o <<= 1) mx = fmaxf(mx, __shfl_xor(mx, o));
  float e = __expf(s - mx);
  float sum = e;
#pragma unroll
  for (int o = 1; o < 8; o <<= 1) sum += __shfl_xor(sum, o);
  float p = e / sum;
  const u16* vp = V + (long)nk * 128 + hoff;
  float y[16];
#pragma unroll
  for (int t = 0; t < 16; t += 4) {
    float4 vv = load4bf(vp + t);
    y[t] = p * vv.x; y[t + 1] = p * vv.y; y[t + 2] = p * vv.z; y[t + 3] = p * vv.w;
  }
#pragma unroll
  for (int o = 1; o < 8; o <<= 1) {
#pragma unroll
    for (int t = 0; t < 16; ++t) y[t] += __shfl_xor(y[t], o);
  }
  if (j == 0) {
    u16* yp = Y + (long)nq * 128 + hoff;
    u16 tmp[16];
#pragma unroll
    for (int t = 0; t < 16; ++t) tmp[t] = f2bf(y[t]);
    *(uint4*)(yp) = *(uint4*)tmp;
    *(uint4*)(yp + 8) = *(uint4*)(tmp + 8);
  }
}

// ---------------- SLG K/V repack for flash attn (fused) ----------------
__global__ __launch_bounds__(256) void k_pack_kv(const u16* __restrict__ Kin,
                                                 const u16* __restrict__ Vin,
                                                 u16* __restrict__ Kh,
                                                 u16* __restrict__ Vt) {
  int idx = blockIdx.x * 256 + threadIdx.x;
  if (idx < 8 * 1032 * 16) {
    int d = idx & 15;
    int r = idx >> 4;
    int k = r % 1032, h = r / 1032;
    Kh[idx] = Kin[k * 128 + h * 16 + d];
  } else {
    int j = idx - 8 * 1032 * 16;
    int k = j % 1032;
    int r = j / 1032;
    int d = r & 15, h = r >> 4;
    Vt[j] = Vin[k * 128 + h * 16 + d];
  }
}

// ---------------- SLG MFMA flash attention ----------------
__global__ __launch_bounds__(256) void k_slg_flash(const u16* __restrict__ Q,
                                                   const u16* __restrict__ Kh,
                                                   const u16* __restrict__ Vt,
                                                   u16* __restrict__ Y) {
  constexpr int NK = 1032;
  constexpr int NTILE = 17;
  __shared__ __align__(16) u16 Ks[64 * 24];
  __shared__ __align__(16) u16 Vs[16 * 72];
  __shared__ __align__(16) u16 Ps[4][16 * 72];
  int tid = threadIdx.x;
  int wave = tid >> 6, lane = tid & 63;
  int quad = lane >> 4, l15 = lane & 15;
  int h = blockIdx.x & 7;
  int q0 = (blockIdx.x >> 3) * 64 + wave * 16;

  const bf16x8 Zb = {0, 0, 0, 0, 0, 0, 0, 0};
  bf16x8 qf = Zb;
  if (quad < 2) qf = *(const bf16x8*)(Q + (long)(q0 + l15) * 128 + h * 16 + quad * 8);

  const u16* Kbase = Kh + (long)h * NK * 16;
  const u16* Vbase = Vt + (long)h * 16 * NK;

  float mrow[4], lrow[4];
  f32x4 oacc = {0.f, 0.f, 0.f, 0.f};
#pragma unroll
  for (int r = 0; r < 4; ++r) { mrow[r] = -1e30f; lrow[r] = 0.f; }

  int skey = tid >> 2, sch = (tid & 3) * 4;
  int svd = tid >> 4, svc = (tid & 15) * 4;

  for (int t = 0; t < NTILE; ++t) {
    int k0 = t * 64;
    __syncthreads();
    {
      short4 v = {0, 0, 0, 0};
      int key = k0 + skey;
      if (key < NK) v = *(const short4*)(Kbase + key * 16 + sch);
      *(short4*)&Ks[skey * 24 + sch] = v;
    }
    {
      short4 v = {0, 0, 0, 0};
      int colb = k0 + svc;
      if (colb < NK) v = *(const short4*)(Vbase + svd * NK + colb);
      *(short4*)&Vs[svd * 72 + svc] = v;
    }
    __syncthreads();

    f32x4 s[4];
#pragma unroll
    for (int sub = 0; sub < 4; ++sub) {
      bf16x8 b = Zb;
      if (quad < 2) b = *(const bf16x8*)&Ks[(sub * 16 + l15) * 24 + quad * 8];
      f32x4 zero = {0.f, 0.f, 0.f, 0.f};
      s[sub] = __builtin_amdgcn_mfma_f32_16x16x32_bf16(qf, b, zero, 0, 0, 0);
    }
    float pv[4][4];
    float tmax[4] = {-1e30f, -1e30f, -1e30f, -1e30f};
#pragma unroll
    for (int sub = 0; sub < 4; ++sub) {
      int key = k0 + sub * 16 + l15;
      bool valid = key < NK;
#pragma unroll
      for (int r = 0; r < 4; ++r) {
        float sv = valid ? s[sub][r] * 0.25f : -1e30f;
        pv[sub][r] = sv;
        tmax[r] = fmaxf(tmax[r], sv);
      }
    }
#pragma unroll
    for (int o = 1; o < 16; o <<= 1)
#pragma unroll
      for (int r = 0; r < 4; ++r) tmax[r] = fmaxf(tmax[r], __shfl_xor(tmax[r], o));

    float al[4], tsum[4] = {0.f, 0.f, 0.f, 0.f};
#pragma unroll
    for (int r = 0; r < 4; ++r) {
      float mn = fmaxf(mrow[r], tmax[r]);
      al[r] = __expf(mrow[r] - mn);
      mrow[r] = mn;
    }
#pragma unroll
    for (int sub = 0; sub < 4; ++sub)
#pragma unroll
      for (int r = 0; r < 4; ++r) {
        float pe = __expf(pv[sub][r] - mrow[r]);
        tsum[r] += pe;
        Ps[wave][(quad * 4 + r) * 72 + sub * 16 + l15] = f2bf(pe);
      }
#pragma unroll
    for (int o = 1; o < 16; o <<= 1)
#pragma unroll
      for (int r = 0; r < 4; ++r) tsum[r] += __shfl_xor(tsum[r], o);
#pragma unroll
    for (int r = 0; r < 4; ++r) {
      lrow[r] = lrow[r] * al[r] + tsum[r];
      oacc[r] *= al[r];
    }
    bf16x8 pa0 = *(const bf16x8*)&Ps[wave][l15 * 72 + quad * 8];
    bf16x8 pa1 = *(const bf16x8*)&Ps[wave][l15 * 72 + 32 + quad * 8];
    bf16x8 vb0 = *(const bf16x8*)&Vs[l15 * 72 + quad * 8];
    bf16x8 vb1 = *(const bf16x8*)&Vs[l15 * 72 + 32 + quad * 8];
    oacc = __builtin_amdgcn_mfma_f32_16x16x32_bf16(pa0, vb0, oacc, 0, 0, 0);
    oacc = __builtin_amdgcn_mfma_f32_16x16x32_bf16(pa1, vb1, oacc, 0, 0, 0);
  }

#pragma unroll
  for (int r = 0; r < 4; ++r) {
    float inv = 1.0f / lrow[r];
    Y[(long)(q0 + quad * 4 + r) * 128 + h * 16 + l15] = f2bf(oacc[r] * inv);
  }
}

static inline int ilg(int v) { int r = 0; while ((1 << r) < v) ++r; return r; }

extern "C" void kernel_launch(void* const* d_in, const int* in_sizes, int n_in,
                              void* d_out, int out_size, void* d_ws, size_t ws_size,
                              hipStream_t stream) {
  (void)in_sizes; (void)n_in; (void)out_size; (void)ws_size;
  const float* x    = (const float*)d_in[0];
  const float* n1_w = (const float*)d_in[1];  const float* n1_b = (const float*)d_in[2];
  const float* n2_w = (const float*)d_in[3];  const float* n2_b = (const float*)d_in[4];
  const float* n3_w = (const float*)d_in[5];  const float* n3_b = (const float*)d_in[6];
  const float* sn_w = (const float*)d_in[7];  const float* sn_b = (const float*)d_in[8];
  const float* tq_w = (const float*)d_in[9];  const float* tq_b = (const float*)d_in[10];
  const float* tk_w = (const float*)d_in[11]; const float* tk_b = (const float*)d_in[12];
  const float* tv_w = (const float*)d_in[13]; const float* tv_b = (const float*)d_in[14];
  const float* tp_w = (const float*)d_in[15]; const float* tp_b = (const float*)d_in[16];
  const float* sq_w = (const float*)d_in[17]; const float* sq_b = (const float*)d_in[18];
  const float* sk_w = (const float*)d_in[19]; const float* sk_b = (const float*)d_in[20];
  const float* sv_w = (const float*)d_in[21]; const float* sv_b = (const float*)d_in[22];
  const float* sp_w = (const float*)d_in[23]; const float* sp_b = (const float*)d_in[24];
  const float* sf_w = (const float*)d_in[25]; const float* sf_b = (const float*)d_in[26];
  const float* sc_w = (const float*)d_in[27]; const float* sc_b = (const float*)d_in[28];
  const float* m1_w = (const float*)d_in[29]; const float* m1_b = (const float*)d_in[30];
  const float* m2_w = (const float*)d_in[31]; const float* m2_b = (const float*)d_in[32];

  char* p = (char*)d_ws;
  auto alloc = [&](size_t bytes) { char* r = p; p += (bytes + 255) & ~(size_t)255; return r; };
  const long N = 16384;
  float* X0 = (float*)alloc(N * 128 * 4);
  u16* XN = (u16*)alloc(N * 128 * 2);
  u16* Qb = (u16*)alloc(N * 128 * 2);   // Qb,Kb,Vb adjacent (each 4 MiB, 256-aligned exact)
  u16* Kb = (u16*)alloc(N * 128 * 2);
  u16* Vb = (u16*)alloc(N * 128 * 2);
  u16* Yb = (u16*)alloc(N * 128 * 2);
  u16* H  = (u16*)alloc(N * 512 * 2);
  u16* XC = (u16*)alloc(8 * 128 * 2);
  u16* XF = (u16*)alloc(1024 * 128 * 2);
  float* Kf = (float*)alloc(1032 * 128 * 4);  // Kf,Vf adjacent (528384 B, 256-aligned exact)
  float* Vf = (float*)alloc(1032 * 128 * 4);
  u16* Kh = (u16*)alloc(8 * 1032 * 16 * 2);
  u16* Vt = (u16*)alloc(8 * 16 * 1032 * 2);
  float* SPb = (float*)alloc(2L * N * 512 * 4);  // split-K partials (64 MB)
  u16* ZPb = (u16*)alloc(2048);                   // zero page for masked gather rows
  u16* tq2 = (u16*)alloc(49152 * 2);  u16* tk2 = (u16*)alloc(49152 * 2);  // adjacent,
  u16* tv2 = (u16*)alloc(49152 * 2);  u16* tp2 = (u16*)alloc(49152 * 2);  // stride 49152
  u16* sq2 = (u16*)alloc(442368 * 2); u16* sk2 = (u16*)alloc(442368 * 2); // sk2->sv2
  u16* sv2 = (u16*)alloc(442368 * 2); u16* sp2 = (u16*)alloc(442368 * 2); // stride 442368
  u16* sf2 = (u16*)alloc(442368 * 2); u16* sc2 = (u16*)alloc(442368 * 2);
  u16* m12 = (u16*)alloc(5308416L * 2);
  u16* m22 = (u16*)alloc(5308416L * 2);

  k_zeropage<<<1, 256, 0, stream>>>(ZPb);

  // fused repacks: 4x NT=3 and 6x NT=27 (all 128x128), then the two big ones
  {
    RPargs r1 = {{tq_w, tk_w, tv_w, tp_w, nullptr, nullptr},
                 {tq2, tk2, tv2, tp2, nullptr, nullptr}};
    k_repack_multi<<<dim3(128, 1, 4), 256, 0, stream>>>(r1, 3);
    RPargs r2 = {{sq_w, sk_w, sv_w, sp_w, sf_w, sc_w},
                 {sq2, sk2, sv2, sp2, sf2, sc2}};
    k_repack_multi<<<dim3(128, 1, 6), 256, 0, stream>>>(r2, 27);
    k_repack2<<<dim3(512, 1), 256, 0, stream>>>(m1_w, m12, 512, 128, 81);
    k_repack2<<<dim3(128, 4), 256, 0, stream>>>(m2_w, m22, 128, 512, 81);
  }

  auto conv = [&](const u16* Xp, const u16* Wp, const float* Bp, void* Yp,
                  int M, int IC, int OC, int mode, int NT,
                  int Do, int Ho, int Wo, int Li, int Di, int Hi, int Wi,
                  int sL, int sD, int sH, int sW, int flags,
                  int ngrp, long wgs, long ygs, const float* BpB) {
    int lgWo = ilg(Wo), lgHo = ilg(Ho), lgDo = ilg(Do);
    int lgWi = ilg(Wi), lgHi = ilg(Hi), lgDi = ilg(Di);
    dim3 g((M + 63) / 64, OC / 64, ngrp);
    k_conv_mfma<<<g, 256, 0, stream>>>(Xp, Wp, Bp, Yp, M, IC, OC, mode, NT,
                                       lgWo, lgHo, lgDo, lgWi, lgHi, lgDi,
                                       Li, Di, Hi, Wi, sL, sD, sH, sW, flags,
                                       wgs, ygs, BpB);
  };
  auto conv_gl = [&](const u16* Xp, const u16* Wp, const float* Bp, void* Yp,
                     int M, int IC, int OC, int mode, int NT, int nsplit, int flags) {
    dim3 g(M / 128, OC / 128, nsplit);
    k_conv_gl<<<g, 256, 0, stream>>>(Xp, Wp, Bp, Yp, SPb, ZPb, M, IC, OC, mode, NT, nsplit,
                                     0L, 4, 4, 4, 4, 4, 4, 4, 16, 16, 16, 1, 1, 1, 1, flags);
    if (nsplit > 1) {
      long MOC = (long)M * OC;
      k_combine<<<(int)((MOC + 255) / 256), 256, 0, stream>>>(SPb, Bp, Yp, MOC, ilg(OC),
                                                              nsplit, flags);
    }
  };
  auto conv_gl256 = [&](const u16* Xp, const u16* Wp, const float* Bp, void* Yp,
                        int M, int IC, int OC, int mode, int NT, int nsplit, int flags) {
    dim3 g(M / 256, OC / 256, nsplit);
    k_conv_g256<<<g, 512, 0, stream>>>(Xp, Wp, Bp, Yp, SPb, ZPb, M, IC, OC, mode, NT, nsplit,
                                       4, 4, 4, 4, 4, 4, 4, 16, 16, 16, 1, 1, 1, 1, flags);
    if (nsplit > 1) {
      long MOC = (long)M * OC;
      k_combine<<<(int)((MOC + 255) / 256), 256, 0, stream>>>(SPb, Bp, Yp, MOC, ilg(OC),
                                                              nsplit, flags);
    }
  };

  k_tin<<<dim3(128, 4, 4), 256, 0, stream>>>(x, X0);

  // ---- TLG branch ----
  k_ln_f2b<<<4096, 256, 0, stream>>>(X0, n1_w, n1_b, XN, 16384, XN, 16384);
  // fused tq/tk/tv conv: z = grp*2 + split (3 grps x 2 splits); SP regions 6 x 8MB
  {
    dim3 g(128, 1, 6);
    k_conv_gl<<<g, 256, 0, stream>>>(XN, tq2, tq_b, Qb, SPb, ZPb, 16384, 128, 128, 0, 3, 2,
                                     49152L, 4, 4, 4, 4, 4, 4, 4, 16, 16, 16, 1, 1, 1, 1, 4);
    k_combine3<<<24576, 256, 0, stream>>>(SPb, tq_b, tk_b, tv_b, Qb, 21, 7, 2, 3);
  }
  k_tlg_attn<<<4096, 256, 0, stream>>>(Qb, Kb, Vb, Yb);
  conv_gl(Yb, tp2, tp_b, X0, 16384, 128, 128, 0, 3, 3, 1);

  // ---- SLG branch ----
  k_ln_f2b<<<4096, 256, 0, stream>>>(X0, n2_w, n2_b, XN, 16384, XN, 16384);
  conv_gl(XN, sq2, sq_b, Qb, 16384, 128, 128, 1, 27, 7, 4);
  conv(XN, sc2, sc_b, XC, 8,    128, 128, 1, 27, 2, 2, 2, 4, 16, 16, 16, 4, 8, 8, 8, 4,
       1, 0L, 0L, sc_b);
  conv(XN, sf2, sf_b, XF, 1024, 128, 128, 1, 27, 8, 8, 8, 4, 16, 16, 16, 2, 2, 2, 2, 4,
       1, 0L, 0L, sf_b);
  // fused k/v coarse (grp0: sk2->Kf, grp1: sv2->Vf) and fine
  conv(XC, sk2, sk_b, Kf, 8, 128, 128, 1, 27, 2, 2, 2, 1, 2, 2, 2, 1, 1, 1, 1, 0,
       2, 442368L, (long)1032 * 128, sv_b);
  conv(XF, sk2, sk_b, Kf + 8 * 128, 1024, 128, 128, 1, 27, 8, 8, 8, 2, 8, 8, 8, 1, 1, 1, 1, 0,
       2, 442368L, (long)1032 * 128, sv_b);
  // fused LN over Kf||Vf -> Kb / Vb
  k_ln_f2b<<<516, 256, 0, stream>>>(Kf, sn_w, sn_b, Kb, 2064, Vb, 1032);
  k_pack_kv<<<1032, 256, 0, stream>>>(Kb, Vb, Kh, Vt);
  k_slg_flash<<<2048, 256, 0, stream>>>(Qb, Kh, Vt, Yb);
  conv_gl(Yb, sp2, sp_b, X0, 16384, 128, 128, 1, 27, 7, 1);

  // ---- MLP branch ----
  k_ln_f2b<<<4096, 256, 0, stream>>>(X0, n3_w, n3_b, XN, 16384, XN, 16384);
  conv_gl256(XN, m12, m1_b, H, 16384, 128, 512, 2, 81, 2, 6);
  conv_gl(H, m22, m2_b, X0, 16384, 512, 128, 2, 81, 8, 1);

  k_tout<<<dim3(128, 4, 4), 256, 0, stream>>>(X0, (float*)d_out);
}

// Round 6
// 877.728 us; speedup vs baseline: 1.3891x; 1.1607x over previous
//
#include <hip/hip_runtime.h>

typedef unsigned short u16;
typedef __attribute__((ext_vector_type(8))) short bf16x8;
typedef __attribute__((ext_vector_type(4))) float f32x4;

#define PITCH 40   // small-conv kernel LDS pitch (shorts)

__device__ __forceinline__ u16 f2bf(float f) {
  union { float f; unsigned u; } v; v.f = f;
  unsigned r = v.u + 0x7fffu + ((v.u >> 16) & 1u);
  return (u16)(r >> 16);
}
__device__ __forceinline__ float bf2f(u16 h) {
  union { unsigned u; float f; } v; v.u = ((unsigned)h) << 16;
  return v.f;
}
__device__ __forceinline__ float4 load4bf(const u16* p) {
  ushort4 h = *(const ushort4*)p;
  return make_float4(bf2f(h.x), bf2f(h.y), bf2f(h.z), bf2f(h.w));
}
// async global->LDS, 16B per lane; LDS dest = wave-uniform base + lane*16
__device__ __forceinline__ void gll16(const u16* g, u16* l) {
  __builtin_amdgcn_global_load_lds(
      (const __attribute__((address_space(1))) unsigned int*)g,
      (__attribute__((address_space(3))) unsigned int*)l, 16, 0, 0);
}

// wave-per-row layernorm core: lane holds channels 2*lane, 2*lane+1
__device__ __forceinline__ ushort2 ln_row(float2 v, float2 gv, float2 bv) {
  float s = v.x + v.y;
#pragma unroll
  for (int o = 32; o > 0; o >>= 1) s += __shfl_xor(s, o);
  float mu = s * (1.0f / 128.0f);
  float dx = v.x - mu, dy = v.y - mu;
  float q = dx * dx + dy * dy;
#pragma unroll
  for (int o = 32; o > 0; o >>= 1) q += __shfl_xor(q, o);
  float rs = rsqrtf(q * (1.0f / 128.0f) + 1e-5f);
  ushort2 o2;
  o2.x = f2bf(dx * rs * gv.x + bv.x);
  o2.y = f2bf(dy * rs * gv.y + bv.y);
  return o2;
}

// ---------------- fused input transpose + LN(n1): x -> X0 (fp32 token-major) + XN (bf16) ----
__global__ __launch_bounds__(256) void k_tin_ln(const float* __restrict__ x,
                                                float* __restrict__ X0,
                                                const float* __restrict__ g,
                                                const float* __restrict__ b,
                                                u16* __restrict__ XN) {
  __shared__ float t[128][33];
  int s0 = blockIdx.x * 32, l = blockIdx.y;
  int tid = threadIdx.x;
#pragma unroll
  for (int r = 0; r < 4; ++r) {
    int lin = r * 256 + tid;
    int c = lin >> 3, sq = (lin & 7) * 4;
    float4 v = *(const float4*)(x + ((long)(l * 128 + c) << 12) + s0 + sq);
    t[c][sq] = v.x; t[c][sq + 1] = v.y; t[c][sq + 2] = v.z; t[c][sq + 3] = v.w;
  }
  __syncthreads();
  int wave = tid >> 6, lane = tid & 63;
  int c2 = lane * 2;
  float2 gv = *(const float2*)(g + c2);
  float2 bv = *(const float2*)(b + c2);
#pragma unroll
  for (int p = 0; p < 8; ++p) {
    int s = p * 4 + wave;
    float2 v = make_float2(t[c2][s], t[c2 + 1][s]);
    long token = (long)l * 4096 + s0 + s;
    *(float2*)(X0 + token * 128 + c2) = v;
    ushort2 o2 = ln_row(v, gv, bv);
    *(ushort2*)(XN + token * 128 + c2) = o2;
  }
}

// ---------------- fused all-weights repack (+zero page) ----------------
// z: 0..3 = tq,tk,tv,tp (NT=3); 4..9 = sq,sk,sv,sp,sf,sc (NT=27);
// 10 = m1 (OC=512,IC=128,NT=81); 11 = m2 (OC=128,IC=512,NT=81).
struct RAargs { const float* w[12]; u16* wb[12]; u16* zp; };
__global__ __launch_bounds__(256) void k_repack_all(RAargs a) {
  __shared__ float ws[128 * 81];
  int z = blockIdx.z, x = blockIdx.x, tid = threadIdx.x;
  if (z == 0 && x == 0) ((unsigned long long*)a.zp)[tid] = 0ull;  // 2048B zero page
  if (z < 10 && x >= 128) return;
  int NT = (z < 4) ? 3 : ((z < 10) ? 27 : 81);
  int OC = (z == 10) ? 512 : 128;
  int IC = (z == 11) ? 512 : 128;
  int oc, ic0;
  if (z == 11) { oc = x & 127; ic0 = (x >> 7) << 7; }
  else { oc = x; ic0 = 0; }
  const float* src = a.w[z] + ((long)oc * IC + ic0) * NT;
  int n = 128 * NT;
  for (int i = tid; i < n; i += 256) ws[i] = src[i];
  __syncthreads();
  u16* dst = a.wb[z] + (long)oc * IC + ic0;
  long tstep = (long)OC * IC;
  for (int idx = tid; idx < n; idx += 256) {
    int t = idx >> 7, i = idx & 127;
    dst[(long)t * tstep + i] = f2bf(ws[i * NT + t]);
  }
}

// ---------------- quad small conv-as-gather-GEMM (64x64 tile), mode=1, IC=OC=128, NT=27 ----
struct QC {
  const u16* X[4]; const u16* W[4]; const float* B[4]; void* Y[4];
  int M[4];
  int lgo[4][3];   // lgWo, lgHo, lgDo
  int lgi[4][3];   // lgWi, lgHi, lgDi
  int di[4][3];    // Di, Hi, Wi
  int st[4][4];    // sL, sD, sH, sW
  int flags[4];
};
__global__ __launch_bounds__(256) void k_conv_quad(QC a) {
  __shared__ u16 As[64 * PITCH];
  __shared__ u16 Bs[64 * PITCH];
  int grp = blockIdx.z;
  int M = a.M[grp];
  int m0 = blockIdx.x * 64;
  if (m0 >= M) return;
  const u16* X = a.X[grp];
  const u16* W3 = a.W[grp];
  const float* bias = a.B[grp];
  void* Yv = a.Y[grp];
  int lgWo = a.lgo[grp][0], lgHo = a.lgo[grp][1], lgDo = a.lgo[grp][2];
  int lgWi = a.lgi[grp][0], lgHi = a.lgi[grp][1], lgDi = a.lgi[grp][2];
  int Di = a.di[grp][0], Hi = a.di[grp][1], Wi = a.di[grp][2];
  int sL = a.st[grp][0], sD = a.st[grp][1], sH = a.st[grp][2], sW = a.st[grp][3];
  int flags = a.flags[grp];

  int tid = threadIdx.x;
  int wave = tid >> 6, lane = tid & 63;
  int quad = lane >> 4, l15 = lane & 15;
  int oc0 = blockIdx.y * 64;

  int srl = tid >> 2;
  int sao = (tid & 3) * 8;
  int sboc = tid >> 2, sbo = (tid & 3) * 8;

  int sm = m0 + srl;
  bool mv = sm < M;
  int w = sm & ((1 << lgWo) - 1);
  int h = (sm >> lgWo) & ((1 << lgHo) - 1);
  int d = (sm >> (lgWo + lgHo)) & ((1 << lgDo) - 1);
  int l = sm >> (lgWo + lgHo + lgDo);

  int c0 = 0, c1 = 0, c2 = 0, c3 = 0;
  auto comp_nb = [&]() -> long {
    if (!mv) return -1;
    int li = l * sL, di = d * sD + c2 - 1, hi = h * sH + c1 - 1, wi = w * sW + c0 - 1;
    bool ok = ((unsigned)di < (unsigned)Di) && ((unsigned)hi < (unsigned)Hi) &&
              ((unsigned)wi < (unsigned)Wi);
    (void)c3;
    if (!ok) return -1;
    return ((((long)((li << lgDi) + di) << lgHi) + hi) << lgWi) + wi;
  };

  long nb = comp_nb();
  const u16* wt = W3 + (long)(oc0 + sboc) * 128 + sbo;
  const long wstep = 128 * 128;
  const int kmask = 3;
  const int total = 27 * 4;

  const bf16x8 Z = {0, 0, 0, 0, 0, 0, 0, 0};
  bf16x8 ra0 = Z, rb;
  if (nb >= 0) ra0 = *(const bf16x8*)(X + nb * 128 + sao);
  rb = *(const bf16x8*)wt;

  f32x4 acc[4];
#pragma unroll
  for (int j = 0; j < 4; ++j) acc[j] = {0.f, 0.f, 0.f, 0.f};

  int wrow = wave * 16;

  for (int ks = 0; ks < total; ++ks) {
    __syncthreads();
    *(bf16x8*)&As[srl * PITCH + sao] = ra0;
    *(bf16x8*)&Bs[sboc * PITCH + sbo] = rb;
    __syncthreads();
    int ksn = ks + 1;
    if (ksn < total) {
      int k0n = (ksn & kmask) << 5;
      if ((ksn & kmask) == 0) {
        wt += wstep;
        if (++c0 == 3) { c0 = 0; if (++c1 == 3) { c1 = 0; if (++c2 == 3) { c2 = 0; ++c3; } } }
        nb = comp_nb();
      }
      ra0 = Z;
      if (nb >= 0) ra0 = *(const bf16x8*)(X + nb * 128 + k0n + sao);
      rb = *(const bf16x8*)(wt + k0n);
    }
    bf16x8 a0 = *(const bf16x8*)&As[(wrow + l15) * PITCH + quad * 8];
#pragma unroll
    for (int j = 0; j < 4; ++j) {
      bf16x8 b = *(const bf16x8*)&Bs[(j * 16 + l15) * PITCH + quad * 8];
      acc[j] = __builtin_amdgcn_mfma_f32_16x16x32_bf16(a0, b, acc[j], 0, 0, 0);
    }
  }

  int col = oc0 + l15;
#pragma unroll
  for (int j = 0; j < 4; ++j) {
    float bj = bias[col + j * 16];
    int rbase = m0 + wrow + quad * 4;
#pragma unroll
    for (int r = 0; r < 4; ++r) {
      int row = rbase + r;
      if (row >= M) continue;
      float v = acc[j][r] + bj;
      if (flags & 2) v = fmaxf(v, 0.f);
      long off = (long)row * 128 + col + j * 16;
      if (flags & 4) ((u16*)Yv)[off] = f2bf(v);
      else if (flags & 1) ((float*)Yv)[off] += v;
      else ((float*)Yv)[off] = v;
    }
  }
}

// ---------------- big conv-GEMM: 128x128 tile, BK=64, single-buffer global_load_lds ----------
// multi-group: blockIdx.z = grp*NSPLIT + split; grp selects weight (+wgs) and SP region.
__global__ __launch_bounds__(256, 4) void k_conv_gl(
    const u16* __restrict__ X, const u16* __restrict__ W3,
    const float* __restrict__ bias, void* __restrict__ Yv, float* __restrict__ SP,
    const u16* __restrict__ ZP,
    int M, int IC, int OC, int mode, int NT, int NSPLIT, long wgs,
    int lgWo, int lgHo, int lgDo,
    int lgWi, int lgHi, int lgDi,
    int Li, int Di, int Hi, int Wi,
    int sL, int sD, int sH, int sW, int flags) {
  __shared__ __align__(16) u16 As[128 * 64];
  __shared__ __align__(16) u16 Bs[128 * 64];
  int tid = threadIdx.x;
  int wave = tid >> 6, lane = tid & 63;
  int quad = lane >> 4, l15 = lane & 15;
  int m0 = blockIdx.x * 128, oc0 = blockIdx.y * 128;
  int mi = wave & 1, ni = wave >> 1;
  int zz = blockIdx.z;
  int grp = zz / NSPLIT, split = zz % NSPLIT;
  W3 += (long)grp * wgs;

  int rp[4], cA[4], sm[4];
#pragma unroll
  for (int q = 0; q < 4; ++q) {
    rp[q] = wave * 32 + q * 8 + (lane >> 3);
    cA[q] = ((lane & 7) - (rp[q] >> 1)) & 7;
    sm[q] = m0 + rp[q];
  }

  int tap_per = (NT + NSPLIT - 1) / NSPLIT;
  int t0 = split * tap_per;
  int t1 = min(NT, t0 + tap_per);
  int kc = IC >> 6;
  int total = (t1 - t0) * kc;

  int c0 = t0 % 3, c1 = (t0 / 3) % 3, c2 = (t0 / 9) % 3, c3 = t0 / 27;
  auto comp_nb = [&](int smv) -> int {
    if (smv >= M) return -1;
    int w = smv & ((1 << lgWo) - 1);
    int h = (smv >> lgWo) & ((1 << lgHo) - 1);
    int d = (smv >> (lgWo + lgHo)) & ((1 << lgDo) - 1);
    int l = smv >> (lgWo + lgHo + lgDo);
    int li, di, hi, wi; bool ok;
    if (mode == 0) {
      int dl = c0 - 1;
      int ll = (l & 1) + dl;
      ok = (ll >= 0 && ll < 2);
      li = l + dl; di = d; hi = h; wi = w;
    } else if (mode == 1) {
      li = l * sL; di = d * sD + c2 - 1; hi = h * sH + c1 - 1; wi = w * sW + c0 - 1;
      ok = ((unsigned)di < (unsigned)Di) && ((unsigned)hi < (unsigned)Hi) &&
           ((unsigned)wi < (unsigned)Wi);
    } else {
      li = l + c3 - 1; di = d + c2 - 1; hi = h + c1 - 1; wi = w + c0 - 1;
      ok = ((unsigned)li < (unsigned)Li) && ((unsigned)di < (unsigned)Di) &&
           ((unsigned)hi < (unsigned)Hi) && ((unsigned)wi < (unsigned)Wi);
    }
    if (!ok) return -1;
    return (((li << lgDi) + di) << lgHi | hi) << lgWi | wi;
  };

  int nb[4];
#pragma unroll
  for (int q = 0; q < 4; ++q) nb[q] = comp_nb(sm[q]);
  long wstep = (long)OC * IC;
  const u16* wbase = W3 + (long)t0 * wstep + (long)oc0 * IC;

  f32x4 acc[4][4];
#pragma unroll
  for (int i = 0; i < 4; ++i)
#pragma unroll
    for (int j = 0; j < 4; ++j) acc[i][j] = {0.f, 0.f, 0.f, 0.f};

  int kk = 0;
  for (int ks = 0; ks < total; ++ks) {
    if (kk == kc) {
      kk = 0;
      if (++c0 == 3) { c0 = 0; if (++c1 == 3) { c1 = 0; if (++c2 == 3) { c2 = 0; ++c3; } } }
#pragma unroll
      for (int q = 0; q < 4; ++q) nb[q] = comp_nb(sm[q]);
      wbase += wstep;
    }
    int k0 = kk << 6;
    ++kk;
    __syncthreads();
#pragma unroll
    for (int q = 0; q < 4; ++q) {
      const u16* a = (nb[q] >= 0) ? X + (long)nb[q] * IC + k0 + cA[q] * 8 : ZP;
      gll16(a, &As[(wave * 4 + q) * 512]);
    }
#pragma unroll
    for (int q = 0; q < 4; ++q) {
      const u16* bsrc = wbase + (long)rp[q] * IC + k0 + cA[q] * 8;
      gll16(bsrc, &Bs[(wave * 4 + q) * 512]);
    }
    __syncthreads();
#pragma unroll
    for (int ksub = 0; ksub < 2; ++ksub) {
      bf16x8 af[4], bf[4];
#pragma unroll
      for (int i = 0; i < 4; ++i) {
        int row = mi * 64 + i * 16 + l15;
        int pa = ((ksub * 4 + quad) + (row >> 1)) & 7;
        af[i] = *(const bf16x8*)&As[row * 64 + pa * 8];
      }
#pragma unroll
      for (int j = 0; j < 4; ++j) {
        int row = ni * 64 + j * 16 + l15;
        int pb = ((ksub * 4 + quad) + (row >> 1)) & 7;
        bf[j] = *(const bf16x8*)&Bs[row * 64 + pb * 8];
      }
#pragma unroll
      for (int i = 0; i < 4; ++i)
#pragma unroll
        for (int j = 0; j < 4; ++j)
          acc[i][j] = __builtin_amdgcn_mfma_f32_16x16x32_bf16(af[i], bf[j], acc[i][j], 0, 0, 0);
    }
  }

  if (NSPLIT > 1) {
    float* out = SP + (long)(grp * NSPLIT + split) * M * OC;
#pragma unroll
    for (int j = 0; j < 4; ++j) {
      int c = oc0 + ni * 64 + j * 16 + l15;
#pragma unroll
      for (int i = 0; i < 4; ++i) {
        int rbase = m0 + mi * 64 + i * 16 + quad * 4;
#pragma unroll
        for (int r = 0; r < 4; ++r) {
          int row = rbase + r;
          if (row < M) out[(long)row * OC + c] = acc[i][j][r];
        }
      }
    }
  } else {
#pragma unroll
    for (int j = 0; j < 4; ++j) {
      int c = oc0 + ni * 64 + j * 16 + l15;
      float bj = bias[c];
#pragma unroll
      for (int i = 0; i < 4; ++i) {
        int rbase = m0 + mi * 64 + i * 16 + quad * 4;
#pragma unroll
        for (int r = 0; r < 4; ++r) {
          int row = rbase + r;
          if (row >= M) continue;
          float v = acc[i][j][r] + bj;
          if (flags & 2) v = fmaxf(v, 0.f);
          long off = (long)row * OC + c;
          if (flags & 4) ((u16*)Yv)[off] = f2bf(v);
          else if (flags & 1) ((float*)Yv)[off] += v;
          else ((float*)Yv)[off] = v;
        }
      }
    }
  }
}

// ---------------- 256x256 8-phase conv-GEMM (R3 form: best measured), BK=64, 8 waves -------
__global__ __launch_bounds__(512, 2) void k_conv_g256(
    const u16* __restrict__ X, const u16* __restrict__ W3,
    const float* __restrict__ bias, void* __restrict__ Yv, float* __restrict__ SP,
    const u16* __restrict__ ZP,
    int M, int IC, int OC, int mode, int NT, int NSPLIT,
    int lgWo, int lgHo, int lgDo,
    int lgWi, int lgHi, int lgDi,
    int Li, int Di, int Hi, int Wi,
    int sL, int sD, int sH, int sW, int flags) {
  __shared__ __align__(16) u16 Ab[4][8192];
  __shared__ __align__(16) u16 Bb[4][8192];
  int tid = threadIdx.x;
  int wave = tid >> 6, lane = tid & 63;
  int quad = lane >> 4, l15 = lane & 15;
  int wr = wave >> 2, wc = wave & 3;
  int m0 = blockIdx.x * 256, oc0 = blockIdx.y * 256;

  int srow0 = tid >> 2;
  int spc = tid & 3;
  int lc0 = (spc - (srow0 >> 1)) & 3;
  int lc1 = (spc - ((srow0 + 128) >> 1)) & 3;

  int kc = IC >> 6;
  int hsPerTap = kc << 1;
  int tap_per = (NT + NSPLIT - 1) / NSPLIT;
  int t0 = blockIdx.z * tap_per;
  int t1 = min(NT, t0 + tap_per);
  int TOT = (t1 - t0) * kc;
  int TOTH = TOT * 2;

  int c0 = t0 % 3, c1 = (t0 / 3) % 3, c2 = (t0 / 9) % 3, c3 = t0 / 27;
  auto comp_nb = [&](int smv) -> int {
    if (smv >= M) return -1;
    int w = smv & ((1 << lgWo) - 1);
    int h = (smv >> lgWo) & ((1 << lgHo) - 1);
    int d = (smv >> (lgWo + lgHo)) & ((1 << lgDo) - 1);
    int l = smv >> (lgWo + lgHo + lgDo);
    int li, di, hi, wi; bool ok;
    if (mode == 0) {
      int dl = c0 - 1;
      int ll = (l & 1) + dl;
      ok = (ll >= 0 && ll < 2);
      li = l + dl; di = d; hi = h; wi = w;
    } else if (mode == 1) {
      li = l * sL; di = d * sD + c2 - 1; hi = h * sH + c1 - 1; wi = w * sW + c0 - 1;
      ok = ((unsigned)di < (unsigned)Di) && ((unsigned)hi < (unsigned)Hi) &&
           ((unsigned)wi < (unsigned)Wi);
    } else {
      li = l + c3 - 1; di = d + c2 - 1; hi = h + c1 - 1; wi = w + c0 - 1;
      ok = ((unsigned)li < (unsigned)Li) && ((unsigned)di < (unsigned)Di) &&
           ((unsigned)hi < (unsigned)Hi) && ((unsigned)wi < (unsigned)Wi);
    }
    if (!ok) return -1;
    return (((li << lgDi) + di) << lgHi | hi) << lgWi | wi;
  };

  int nb0 = comp_nb(m0 + srow0);
  int nb1 = comp_nb(m0 + srow0 + 128);
  const u16* ap0;
  const u16* ap1;
  auto setAp = [&]() {
    ap0 = (nb0 >= 0) ? X + (long)nb0 * IC + lc0 * 8 : ZP;
    ap1 = (nb1 >= 0) ? X + (long)nb1 * IC + lc1 * 8 : ZP;
  };
  setAp();
  int ahs = 0, sA = 0;
  u16* adst = &Ab[0][wave << 9];
  auto stageA = [&]() {
    u16* d = adst + ((sA & 3) << 13);
    ++sA;
    if (sA > TOTH) { gll16(ZP, d); gll16(ZP, d + 4096); return; }
    gll16(ap0 + (ahs << 5), d);
    gll16(ap1 + (ahs << 5), d + 4096);
    if (++ahs == hsPerTap) {
      ahs = 0;
      if (++c0 == 3) { c0 = 0; if (++c1 == 3) { c1 = 0; if (++c2 == 3) { c2 = 0; ++c3; } } }
      nb0 = comp_nb(m0 + srow0);
      nb1 = comp_nb(m0 + srow0 + 128);
      setAp();
    }
  };

  long wstep = (long)OC * IC;
  const u16* bp = W3 + ((long)t0 * OC + oc0 + srow0) * IC + lc0 * 8;
  long bdlt = (long)128 * IC + (lc1 - lc0) * 8;
  long btap = wstep - (long)(hsPerTap - 1) * 32;
  int bhs = 0, sB = 0;
  u16* bdst = &Bb[0][wave << 9];
  auto stageB = [&]() {
    u16* d = bdst + ((sB & 3) << 13);
    ++sB;
    if (sB > TOTH) { gll16(ZP, d); gll16(ZP, d + 4096); return; }
    gll16(bp, d);
    gll16(bp + bdlt, d + 4096);
    if (++bhs == hsPerTap) { bhs = 0; bp += btap; }
    else bp += 32;
  };

  int rowA0 = (wr << 7) + l15;
  int rA0 = rowA0 * 32 + (((quad + (rowA0 >> 1)) & 3) << 3);
  int rowB0 = (wc << 6) + l15;
  int rB0 = rowB0 * 32 + (((quad + (rowB0 >> 1)) & 3) << 3);
  const u16* Abase = &Ab[0][0];
  const u16* Bbase = &Bb[0][0];

  f32x4 acc[8][4];
#pragma unroll
  for (int i = 0; i < 8; ++i)
#pragma unroll
    for (int j = 0; j < 4; ++j) acc[i][j] = {0.f, 0.f, 0.f, 0.f};

  bf16x8 af[4], bfr[4];
  auto rdAB = [&](int reg) {
    const u16* pA = Abase + (reg << 13) + rA0;
    const u16* pB = Bbase + (reg << 13) + rB0;
    af[0] = *(const bf16x8*)(pA);
    bfr[0] = *(const bf16x8*)(pB);
    bfr[1] = *(const bf16x8*)(pB + (1 << 9));
    bfr[2] = *(const bf16x8*)(pB + (2 << 9));
    bfr[3] = *(const bf16x8*)(pB + (3 << 9));
    af[1] = *(const bf16x8*)(pA + (1 << 9));
    af[2] = *(const bf16x8*)(pA + (2 << 9));
    af[3] = *(const bf16x8*)(pA + (3 << 9));
  };
  auto rdA = [&](int reg, int ih) {
    const u16* pA = Abase + (reg << 13) + (ih << 11) + rA0;
#pragma unroll
    for (int i = 0; i < 4; ++i) af[i] = *(const bf16x8*)(pA + (i << 9));
  };
  auto mf = [&](int ih) {
    __builtin_amdgcn_s_setprio(1);
#pragma unroll
    for (int i = 0; i < 4; ++i)
#pragma unroll
      for (int j = 0; j < 4; ++j)
        acc[(ih << 2) + i][j] =
            __builtin_amdgcn_mfma_f32_16x16x32_bf16(af[i], bfr[j], acc[(ih << 2) + i][j], 0, 0, 0);
    __builtin_amdgcn_s_setprio(0);
  };

  stageA(); stageB();
  stageA(); stageB();
  stageA(); stageB();
  asm volatile("s_waitcnt vmcnt(8)" ::: "memory");
  __builtin_amdgcn_s_barrier();

  for (int n = 0; n < TOT; ++n) {
    int rg = (n & 1) << 1;
    rdAB(rg);
    stageA();
    __builtin_amdgcn_sched_barrier(0);
    __builtin_amdgcn_s_barrier();
    mf(0);
    __builtin_amdgcn_s_barrier();
    rdA(rg, 1);
    stageB();
    __builtin_amdgcn_sched_barrier(0);
    __builtin_amdgcn_s_barrier();
    mf(1);
    __builtin_amdgcn_sched_barrier(0);
    asm volatile("s_waitcnt vmcnt(8)" ::: "memory");
    __builtin_amdgcn_s_barrier();
    rdAB(rg + 1);
    stageA();
    __builtin_amdgcn_sched_barrier(0);
    __builtin_amdgcn_s_barrier();
    mf(0);
    __builtin_amdgcn_s_barrier();
    rdA(rg + 1, 1);
    stageB();
    __builtin_amdgcn_sched_barrier(0);
    __builtin_amdgcn_s_barrier();
    mf(1);
    __builtin_amdgcn_sched_barrier(0);
    asm volatile("s_waitcnt vmcnt(8)" ::: "memory");
    __builtin_amdgcn_s_barrier();
  }

  if (NSPLIT > 1) {
    float* outp = SP + (long)blockIdx.z * M * OC;
#pragma unroll
    for (int i = 0; i < 8; ++i)
#pragma unroll
      for (int j = 0; j < 4; ++j) {
        int c = oc0 + (wc << 6) + (j << 4) + l15;
        int rb = m0 + (wr << 7) + (i << 4) + (quad << 2);
#pragma unroll
        for (int r = 0; r < 4; ++r) {
          int row = rb + r;
          if (row < M) outp[(long)row * OC + c] = acc[i][j][r];
        }
      }
  } else {
#pragma unroll
    for (int i = 0; i < 8; ++i)
#pragma unroll
      for (int j = 0; j < 4; ++j) {
        int c = oc0 + (wc << 6) + (j << 4) + l15;
        float bj = bias[c];
        int rb = m0 + (wr << 7) + (i << 4) + (quad << 2);
#pragma unroll
        for (int r = 0; r < 4; ++r) {
          int row = rb + r;
          if (row >= M) continue;
          float v = acc[i][j][r] + bj;
          if (flags & 2) v = fmaxf(v, 0.f);
          long off = (long)row * OC + c;
          if (flags & 4) ((u16*)Yv)[off] = f2bf(v);
          else if (flags & 1) ((float*)Yv)[off] += v;
          else ((float*)Yv)[off] = v;
        }
      }
  }
}

// ---------------- combine split-K partials: out = (sum_s SP[s]) + bias ----------------
__global__ __launch_bounds__(256) void k_combine(const float* __restrict__ SP,
                                                 const float* __restrict__ bias,
                                                 void* __restrict__ out,
                                                 long MOC, int lgOC, int nsplit, int flags) {
  long idx = (long)blockIdx.x * 256 + threadIdx.x;
  if (idx >= MOC) return;
  float v = bias[idx & ((1 << lgOC) - 1)];
  for (int s = 0; s < nsplit; ++s) v += SP[s * MOC + idx];
  if (flags & 2) v = fmaxf(v, 0.f);
  if (flags & 4) ((u16*)out)[idx] = f2bf(v);
  else if (flags & 1) ((float*)out)[idx] += v;
  else ((float*)out)[idx] = v;
}

// 3-group combine: outputs adjacent, MOC a power of two (lgMOC); bias per group
__global__ __launch_bounds__(256) void k_combine3(const float* __restrict__ SP,
                                                  const float* __restrict__ b0,
                                                  const float* __restrict__ b1,
                                                  const float* __restrict__ b2,
                                                  u16* __restrict__ out,
                                                  int lgMOC, int lgOC, int nsplit, int ngrp) {
  long idx = (long)blockIdx.x * 256 + threadIdx.x;
  long tot = (long)ngrp << lgMOC;
  if (idx >= tot) return;
  int grp = (int)(idx >> lgMOC);
  long sub = idx & ((1L << lgMOC) - 1);
  const float* bp = (grp == 0) ? b0 : ((grp == 1) ? b1 : b2);
  float v = bp[sub & ((1 << lgOC) - 1)];
  const float* sp = SP + (((long)grp * nsplit) << lgMOC);
  for (int s = 0; s < nsplit; ++s) v += sp[((long)s << lgMOC) + sub];
  out[idx] = f2bf(v);
}

// ---------------- fused split-K combine + residual-accumulate into X0 + LN -> XN ------------
// one wave per token row (M=16384, OC=128, MOC=2^21)
__global__ __launch_bounds__(256) void k_comb_ln(const float* __restrict__ SP,
                                                 const float* __restrict__ bias,
                                                 float* __restrict__ X0,
                                                 const float* __restrict__ g,
                                                 const float* __restrict__ b,
                                                 u16* __restrict__ XN, int nsplit) {
  int n = blockIdx.x * 4 + (threadIdx.x >> 6);
  int lane = threadIdx.x & 63;
  long off = (long)n * 128 + lane * 2;
  float2 v = *(const float2*)(bias + lane * 2);
  for (int s = 0; s < nsplit; ++s) {
    float2 sv = *(const float2*)(SP + (((long)s) << 21) + off);
    v.x += sv.x; v.y += sv.y;
  }
  float2 x0 = *(const float2*)(X0 + off);
  v.x += x0.x; v.y += x0.y;
  *(float2*)(X0 + off) = v;
  float2 gv = *(const float2*)(g + lane * 2);
  float2 bv = *(const float2*)(b + lane * 2);
  ushort2 o2 = ln_row(v, gv, bv);
  *(ushort2*)(XN + off) = o2;
}

// ---------------- fused m2 combine + residual + transposed output write --------------------
// out[(l*128+c)*4096 + s] = X0[token*128+c] + bias[c] + sum_{s=0..7} SP[s]; token = l*4096+s
__global__ __launch_bounds__(256) void k_comb_out(const float* __restrict__ SP,
                                                  const float* __restrict__ X0,
                                                  const float* __restrict__ bias,
                                                  float* __restrict__ out) {
  __shared__ float t[32][33];
  int s0 = blockIdx.x * 32, c0 = blockIdx.y * 32, l = blockIdx.z;
  int r = threadIdx.x >> 3, q4 = (threadIdx.x & 7) * 4;
  long token = (long)l * 4096 + s0 + r;
  long off = token * 128 + c0 + q4;
  float4 v = *(const float4*)(bias + c0 + q4);
#pragma unroll
  for (int s = 0; s < 8; ++s) {
    float4 sv = *(const float4*)(SP + (((long)s) << 21) + off);
    v.x += sv.x; v.y += sv.y; v.z += sv.z; v.w += sv.w;
  }
  float4 x0 = *(const float4*)(X0 + off);
  v.x += x0.x; v.y += x0.y; v.z += x0.z; v.w += x0.w;
  t[r][q4] = v.x; t[r][q4 + 1] = v.y; t[r][q4 + 2] = v.z; t[r][q4 + 3] = v.w;
  __syncthreads();
  float4 o = {t[q4][r], t[q4 + 1][r], t[q4 + 2][r], t[q4 + 3][r]};
  *(float4*)(out + ((long)(l * 128 + c0 + r) << 12) + s0 + q4) = o;
}

// ---------------- TLG windowed cross attention: 8q x 8k per (window, head), bf16 ----------------
__global__ __launch_bounds__(256) void k_tlg_attn(const u16* __restrict__ Q,
                                                  const u16* __restrict__ K,
                                                  const u16* __restrict__ V,
                                                  u16* __restrict__ Y) {
  int gw = blockIdx.x * 4 + (threadIdx.x >> 6);
  int lane = threadIdx.x & 63;
  int head = gw & 7;
  int win = gw >> 3;
  int wB = win & 7, hB = (win >> 3) & 7, dB = (win >> 6) & 7, l = win >> 9;
  int i = lane >> 3, j = lane & 7;
  int nq = (l << 12) | ((dB * 2 + (i >> 2)) << 8) | ((hB * 2 + ((i >> 1) & 1)) << 4) |
           (wB * 2 + (i & 1));
  int lk = l ^ 2;
  int nk = (lk << 12) | ((dB * 2 + (j >> 2)) << 8) | ((hB * 2 + ((j >> 1) & 1)) << 4) |
           (wB * 2 + (j & 1));
  int hoff = head * 16;
  const u16* qp = Q + (long)nq * 128 + hoff;
  const u16* kp = K + (long)nk * 128 + hoff;
  float s = 0.f;
#pragma unroll
  for (int t = 0; t < 16; t += 4) {
    float4 a = load4bf(qp + t);
    float4 b = load4bf(kp + t);
    s += a.x * b.x + a.y * b.y + a.z * b.z + a.w * b.w;
  }
  s *= 0.25f;
  float mx = s;
#pragma unroll
  for (int o = 1; o < 8; o <<= 1) mx = fmaxf(mx, __shfl_xor(mx, o));
  float e = __expf(s - mx);
  float sum = e;
#pragma unroll
  for (int o = 1; o < 8; o <<= 1) sum += __shfl_xor(sum, o);
  float p = e / sum;
  const u16* vp = V + (long)nk * 128 + hoff;
  float y[16];
#pragma unroll
  for (int t = 0; t < 16; t += 4) {
    float4 vv = load4bf(vp + t);
    y[t] = p * vv.x; y[t + 1] = p * vv.y; y[t + 2] = p * vv.z; y[t + 3] = p * vv.w;
  }
#pragma unroll
  for (int o = 1; o < 8; o <<= 1) {
#pragma unroll
    for (int t = 0; t < 16; ++t) y[t] += __shfl_xor(y[t], o);
  }
  if (j == 0) {
    u16* yp = Y + (long)nq * 128 + hoff;
    u16 tmp[16];
#pragma unroll
    for (int t = 0; t < 16; ++t) tmp[t] = f2bf(y[t]);
    *(uint4*)(yp) = *(uint4*)tmp;
    *(uint4*)(yp + 8) = *(uint4*)(tmp + 8);
  }
}

// ---------------- fused K/V layernorm + pack: Kf||Vf (fp32) -> Kh, Vt (bf16, attn layouts) ---
__global__ __launch_bounds__(256) void k_ln_kv(const float* __restrict__ X,
                                               const float* __restrict__ g,
                                               const float* __restrict__ b,
                                               u16* __restrict__ Kh,
                                               u16* __restrict__ Vt) {
  int n = blockIdx.x * 4 + (threadIdx.x >> 6);
  if (n >= 2064) return;
  int lane = threadIdx.x & 63;
  float2 v = *(const float2*)(X + (long)n * 128 + lane * 2);
  float2 gv = *(const float2*)(g + lane * 2);
  float2 bv = *(const float2*)(b + lane * 2);
  ushort2 o2 = ln_row(v, gv, bv);
  int isK = n < 1032;
  int k = isK ? n : n - 1032;
  int h = lane >> 3, d = (lane & 7) * 2;
  if (isK) {
    *(ushort2*)(Kh + (((long)h * 1032 + k) << 4) + d) = o2;
  } else {
    Vt[((long)(h * 16 + d)) * 1032 + k] = o2.x;
    Vt[((long)(h * 16 + d) + 1) * 1032 + k] = o2.y;
  }
}

// ---------------- SLG MFMA flash attention ----------------
__global__ __launch_bounds__(256) void k_slg_flash(const u16* __restrict__ Q,
                                                   const u16* __restrict__ Kh,
                                                   const u16* __restrict__ Vt,
                                                   u16* __restrict__ Y) {
  constexpr int NK = 1032;
  constexpr int NTILE = 17;
  __shared__ __align__(16) u16 Ks[64 * 24];
  __shared__ __align__(16) u16 Vs[16 * 72];
  __shared__ __align__(16) u16 Ps[4][16 * 72];
  int tid = threadIdx.x;
  int wave = tid >> 6, lane = tid & 63;
  int quad = lane >> 4, l15 = lane & 15;
  int h = blockIdx.x & 7;
  int q0 = (blockIdx.x >> 3) * 64 + wave * 16;

  const bf16x8 Zb = {0, 0, 0, 0, 0, 0, 0, 0};
  bf16x8 qf = Zb;
  if (quad < 2) qf = *(const bf16x8*)(Q + (long)(q0 + l15) * 128 + h * 16 + quad * 8);

  const u16* Kbase = Kh + (long)h * NK * 16;
  const u16* Vbase = Vt + (long)h * 16 * NK;

  float mrow[4], lrow[4];
  f32x4 oacc = {0.f, 0.f, 0.f, 0.f};
#pragma unroll
  for (int r = 0; r < 4; ++r) { mrow[r] = -1e30f; lrow[r] = 0.f; }

  int skey = tid >> 2, sch = (tid & 3) * 4;
  int svd = tid >> 4, svc = (tid & 15) * 4;

  for (int t = 0; t < NTILE; ++t) {
    int k0 = t * 64;
    __syncthreads();
    {
      short4 v = {0, 0, 0, 0};
      int key = k0 + skey;
      if (key < NK) v = *(const short4*)(Kbase + key * 16 + sch);
      *(short4*)&Ks[skey * 24 + sch] = v;
    }
    {
      short4 v = {0, 0, 0, 0};
      int colb = k0 + svc;
      if (colb < NK) v = *(const short4*)(Vbase + svd * NK + colb);
      *(short4*)&Vs[svd * 72 + svc] = v;
    }
    __syncthreads();

    f32x4 s[4];
#pragma unroll
    for (int sub = 0; sub < 4; ++sub) {
      bf16x8 b = Zb;
      if (quad < 2) b = *(const bf16x8*)&Ks[(sub * 16 + l15) * 24 + quad * 8];
      f32x4 zero = {0.f, 0.f, 0.f, 0.f};
      s[sub] = __builtin_amdgcn_mfma_f32_16x16x32_bf16(qf, b, zero, 0, 0, 0);
    }
    float pv[4][4];
    float tmax[4] = {-1e30f, -1e30f, -1e30f, -1e30f};
#pragma unroll
    for (int sub = 0; sub < 4; ++sub) {
      int key = k0 + sub * 16 + l15;
      bool valid = key < NK;
#pragma unroll
      for (int r = 0; r < 4; ++r) {
        float sv = valid ? s[sub][r] * 0.25f : -1e30f;
        pv[sub][r] = sv;
        tmax[r] = fmaxf(tmax[r], sv);
      }
    }
#pragma unroll
    for (int o = 1; o < 16; o <<= 1)
#pragma unroll
      for (int r = 0; r < 4; ++r) tmax[r] = fmaxf(tmax[r], __shfl_xor(tmax[r], o));

    float al[4], tsum[4] = {0.f, 0.f, 0.f, 0.f};
#pragma unroll
    for (int r = 0; r < 4; ++r) {
      float mn = fmaxf(mrow[r], tmax[r]);
      al[r] = __expf(mrow[r] - mn);
      mrow[r] = mn;
    }
#pragma unroll
    for (int sub = 0; sub < 4; ++sub)
#pragma unroll
      for (int r = 0; r < 4; ++r) {
        float pe = __expf(pv[sub][r] - mrow[r]);
        tsum[r] += pe;
        Ps[wave][(quad * 4 + r) * 72 + sub * 16 + l15] = f2bf(pe);
      }
#pragma unroll
    for (int o = 1; o < 16; o <<= 1)
#pragma unroll
      for (int r = 0; r < 4; ++r) tsum[r] += __shfl_xor(tsum[r], o);
#pragma unroll
    for (int r = 0; r < 4; ++r) {
      lrow[r] = lrow[r] * al[r] + tsum[r];
      oacc[r] *= al[r];
    }
    bf16x8 pa0 = *(const bf16x8*)&Ps[wave][l15 * 72 + quad * 8];
    bf16x8 pa1 = *(const bf16x8*)&Ps[wave][l15 * 72 + 32 + quad * 8];
    bf16x8 vb0 = *(const bf16x8*)&Vs[l15 * 72 + quad * 8];
    bf16x8 vb1 = *(const bf16x8*)&Vs[l15 * 72 + 32 + quad * 8];
    oacc = __builtin_amdgcn_mfma_f32_16x16x32_bf16(pa0, vb0, oacc, 0, 0, 0);
    oacc = __builtin_amdgcn_mfma_f32_16x16x32_bf16(pa1, vb1, oacc, 0, 0, 0);
  }

#pragma unroll
  for (int r = 0; r < 4; ++r) {
    float inv = 1.0f / lrow[r];
    Y[(long)(q0 + quad * 4 + r) * 128 + h * 16 + l15] = f2bf(oacc[r] * inv);
  }
}

static inline int ilg(int v) { int r = 0; while ((1 << r) < v) ++r; return r; }

extern "C" void kernel_launch(void* const* d_in, const int* in_sizes, int n_in,
                              void* d_out, int out_size, void* d_ws, size_t ws_size,
                              hipStream_t stream) {
  (void)in_sizes; (void)n_in; (void)out_size; (void)ws_size;
  const float* x    = (const float*)d_in[0];
  const float* n1_w = (const float*)d_in[1];  const float* n1_b = (const float*)d_in[2];
  const float* n2_w = (const float*)d_in[3];  const float* n2_b = (const float*)d_in[4];
  const float* n3_w = (const float*)d_in[5];  const float* n3_b = (const float*)d_in[6];
  const float* sn_w = (const float*)d_in[7];  const float* sn_b = (const float*)d_in[8];
  const float* tq_w = (const float*)d_in[9];  const float* tq_b = (const float*)d_in[10];
  const float* tk_w = (const float*)d_in[11]; const float* tk_b = (const float*)d_in[12];
  const float* tv_w = (const float*)d_in[13]; const float* tv_b = (const float*)d_in[14];
  const float* tp_w = (const float*)d_in[15]; const float* tp_b = (const float*)d_in[16];
  const float* sq_w = (const float*)d_in[17]; const float* sq_b = (const float*)d_in[18];
  const float* sk_w = (const float*)d_in[19]; const float* sk_b = (const float*)d_in[20];
  const float* sv_w = (const float*)d_in[21]; const float* sv_b = (const float*)d_in[22];
  const float* sp_w = (const float*)d_in[23]; const float* sp_b = (const float*)d_in[24];
  const float* sf_w = (const float*)d_in[25]; const float* sf_b = (const float*)d_in[26];
  const float* sc_w = (const float*)d_in[27]; const float* sc_b = (const float*)d_in[28];
  const float* m1_w = (const float*)d_in[29]; const float* m1_b = (const float*)d_in[30];
  const float* m2_w = (const float*)d_in[31]; const float* m2_b = (const float*)d_in[32];

  char* p = (char*)d_ws;
  auto alloc = [&](size_t bytes) { char* r = p; p += (bytes + 255) & ~(size_t)255; return r; };
  const long N = 16384;
  float* X0 = (float*)alloc(N * 128 * 4);
  u16* XN = (u16*)alloc(N * 128 * 2);
  u16* Qb = (u16*)alloc(N * 128 * 2);   // Qb,Kb,Vb adjacent (each 4 MiB, 256-aligned exact)
  u16* Kb = (u16*)alloc(N * 128 * 2);
  u16* Vb = (u16*)alloc(N * 128 * 2);
  u16* Yb = (u16*)alloc(N * 128 * 2);
  u16* H  = (u16*)alloc(N * 512 * 2);
  u16* XC = (u16*)alloc(8 * 128 * 2);
  u16* XF = (u16*)alloc(1024 * 128 * 2);
  float* Kf = (float*)alloc(1032 * 128 * 4);  // Kf,Vf adjacent (528384 B, 256-aligned exact)
  float* Vf = (float*)alloc(1032 * 128 * 4);
  u16* Kh = (u16*)alloc(8 * 1032 * 16 * 2);
  u16* Vt = (u16*)alloc(8 * 16 * 1032 * 2);
  float* SPb = (float*)alloc(2L * N * 512 * 4);  // split-K partials (64 MB)
  u16* ZPb = (u16*)alloc(2048);                   // zero page for masked gather rows
  u16* tq2 = (u16*)alloc(49152 * 2);  u16* tk2 = (u16*)alloc(49152 * 2);  // adjacent,
  u16* tv2 = (u16*)alloc(49152 * 2);  u16* tp2 = (u16*)alloc(49152 * 2);  // stride 49152
  u16* sq2 = (u16*)alloc(442368 * 2); u16* sk2 = (u16*)alloc(442368 * 2); // sk2->sv2
  u16* sv2 = (u16*)alloc(442368 * 2); u16* sp2 = (u16*)alloc(442368 * 2); // stride 442368
  u16* sf2 = (u16*)alloc(442368 * 2); u16* sc2 = (u16*)alloc(442368 * 2);
  u16* m12 = (u16*)alloc(5308416L * 2);
  u16* m22 = (u16*)alloc(5308416L * 2);

  // fused zero-page + all 12 weight repacks
  {
    RAargs ra;
    const float* ws[12] = {tq_w, tk_w, tv_w, tp_w, sq_w, sk_w, sv_w, sp_w, sf_w, sc_w,
                           m1_w, m2_w};
    u16* wbs[12] = {tq2, tk2, tv2, tp2, sq2, sk2, sv2, sp2, sf2, sc2, m12, m22};
    for (int i = 0; i < 12; ++i) { ra.w[i] = ws[i]; ra.wb[i] = wbs[i]; }
    ra.zp = ZPb;
    k_repack_all<<<dim3(512, 1, 12), 256, 0, stream>>>(ra);
  }

  auto conv_gl = [&](const u16* Xp, const u16* Wp, const float* Bp, void* Yp,
                     int M, int IC, int OC, int mode, int NT, int nsplit, int flags) {
    dim3 g(M / 128, OC / 128, nsplit);
    k_conv_gl<<<g, 256, 0, stream>>>(Xp, Wp, Bp, Yp, SPb, ZPb, M, IC, OC, mode, NT, nsplit,
                                     0L, 4, 4, 4, 4, 4, 4, 4, 16, 16, 16, 1, 1, 1, 1, flags);
    if (nsplit > 1 && flags >= 0) {
      long MOC = (long)M * OC;
      k_combine<<<(int)((MOC + 255) / 256), 256, 0, stream>>>(SPb, Bp, Yp, MOC, ilg(OC),
                                                              nsplit, flags);
    }
  };
  auto conv_gl256 = [&](const u16* Xp, const u16* Wp, const float* Bp, void* Yp,
                        int M, int IC, int OC, int mode, int NT, int nsplit, int flags) {
    dim3 g(M / 256, OC / 256, nsplit);
    k_conv_g256<<<g, 512, 0, stream>>>(Xp, Wp, Bp, Yp, SPb, ZPb, M, IC, OC, mode, NT, nsplit,
                                       4, 4, 4, 4, 4, 4, 4, 16, 16, 16, 1, 1, 1, 1, flags);
    if (nsplit > 1) {
      long MOC = (long)M * OC;
      k_combine<<<(int)((MOC + 255) / 256), 256, 0, stream>>>(SPb, Bp, Yp, MOC, ilg(OC),
                                                              nsplit, flags);
    }
  };

  // fused input transpose + LN(n1): x -> X0 + XN
  k_tin_ln<<<dim3(128, 4), 256, 0, stream>>>(x, X0, n1_w, n1_b, XN);

  // ---- TLG branch ----
  // fused tq/tk/tv conv: z = grp*2 + split (3 grps x 2 splits); SP regions 6 x 8MB
  {
    dim3 g(128, 1, 6);
    k_conv_gl<<<g, 256, 0, stream>>>(XN, tq2, tq_b, Qb, SPb, ZPb, 16384, 128, 128, 0, 3, 2,
                                     49152L, 4, 4, 4, 4, 4, 4, 4, 16, 16, 16, 1, 1, 1, 1, 4);
    k_combine3<<<24576, 256, 0, stream>>>(SPb, tq_b, tk_b, tv_b, Qb, 21, 7, 2, 3);
  }
  k_tlg_attn<<<4096, 256, 0, stream>>>(Qb, Kb, Vb, Yb);
  // tp conv (split-K partials only), then fused combine + residual into X0 + LN(n2) -> XN
  {
    dim3 g(128, 1, 3);
    k_conv_gl<<<g, 256, 0, stream>>>(Yb, tp2, tp_b, X0, SPb, ZPb, 16384, 128, 128, 0, 3, 3,
                                     0L, 4, 4, 4, 4, 4, 4, 4, 16, 16, 16, 1, 1, 1, 1, 1);
    k_comb_ln<<<4096, 256, 0, stream>>>(SPb, tp_b, X0, n2_w, n2_b, XN, 3);
  }

  // ---- SLG branch ----
  conv_gl(XN, sq2, sq_b, Qb, 16384, 128, 128, 1, 27, 7, 4);
  // fused sc + sf
  {
    QC q{};
    q.X[0] = XN; q.W[0] = sc2; q.B[0] = sc_b; q.Y[0] = XC; q.M[0] = 8;
    q.lgo[0][0] = 1; q.lgo[0][1] = 1; q.lgo[0][2] = 1;
    q.lgi[0][0] = 4; q.lgi[0][1] = 4; q.lgi[0][2] = 4;
    q.di[0][0] = 16; q.di[0][1] = 16; q.di[0][2] = 16;
    q.st[0][0] = 4; q.st[0][1] = 8; q.st[0][2] = 8; q.st[0][3] = 8;
    q.flags[0] = 4;
    q.X[1] = XN; q.W[1] = sf2; q.B[1] = sf_b; q.Y[1] = XF; q.M[1] = 1024;
    q.lgo[1][0] = 3; q.lgo[1][1] = 3; q.lgo[1][2] = 3;
    q.lgi[1][0] = 4; q.lgi[1][1] = 4; q.lgi[1][2] = 4;
    q.di[1][0] = 16; q.di[1][1] = 16; q.di[1][2] = 16;
    q.st[1][0] = 2; q.st[1][1] = 2; q.st[1][2] = 2; q.st[1][3] = 2;
    q.flags[1] = 4;
    k_conv_quad<<<dim3(16, 2, 2), 256, 0, stream>>>(q);
  }
  // fused k/v convs: coarse-K, coarse-V, fine-K, fine-V
  {
    QC q{};
    for (int i = 0; i < 4; ++i) {
      int fine = i >> 1, isv = i & 1;
      q.X[i] = fine ? XF : XC;
      q.W[i] = isv ? sv2 : sk2;
      q.B[i] = isv ? sv_b : sk_b;
      q.Y[i] = (void*)((isv ? Vf : Kf) + (fine ? 8 * 128 : 0));
      q.M[i] = fine ? 1024 : 8;
      int lo = fine ? 3 : 1;
      q.lgo[i][0] = lo; q.lgo[i][1] = lo; q.lgo[i][2] = lo;
      int li = fine ? 3 : 1;
      q.lgi[i][0] = li; q.lgi[i][1] = li; q.lgi[i][2] = li;
      int dd = fine ? 8 : 2;
      q.di[i][0] = dd; q.di[i][1] = dd; q.di[i][2] = dd;
      q.st[i][0] = 1; q.st[i][1] = 1; q.st[i][2] = 1; q.st[i][3] = 1;
      q.flags[i] = 0;
    }
    k_conv_quad<<<dim3(16, 2, 4), 256, 0, stream>>>(q);
  }
  // fused LN(K/V) + pack -> Kh, Vt
  k_ln_kv<<<516, 256, 0, stream>>>(Kf, sn_w, sn_b, Kh, Vt);
  k_slg_flash<<<2048, 256, 0, stream>>>(Qb, Kh, Vt, Yb);
  // sp conv (split-K partials), then fused combine + residual into X0 + LN(n3) -> XN
  {
    dim3 g(128, 1, 7);
    k_conv_gl<<<g, 256, 0, stream>>>(Yb, sp2, sp_b, X0, SPb, ZPb, 16384, 128, 128, 1, 27, 7,
                                     0L, 4, 4, 4, 4, 4, 4, 4, 16, 16, 16, 1, 1, 1, 1, 1);
    k_comb_ln<<<4096, 256, 0, stream>>>(SPb, sp_b, X0, n3_w, n3_b, XN, 7);
  }

  // ---- MLP branch ----
  conv_gl256(XN, m12, m1_b, H, 16384, 128, 512, 2, 81, 2, 6);
  // m2 conv (split-K partials), then fused combine + residual + transposed output
  {
    dim3 g(128, 1, 8);
    k_conv_gl<<<g, 256, 0, stream>>>(H, m22, m2_b, X0, SPb, ZPb, 16384, 512, 128, 2, 81, 8,
                                     0L, 4, 4, 4, 4, 4, 4, 4, 16, 16, 16, 1, 1, 1, 1, 1);
    k_comb_out<<<dim3(128, 4, 4), 256, 0, stream>>>(SPb, X0, m2_b, (float*)d_out);
  }
}

// Round 7
// 852.920 us; speedup vs baseline: 1.4295x; 1.0291x over previous
//
#include <hip/hip_runtime.h>

typedef unsigned short u16;
typedef __attribute__((ext_vector_type(8))) short bf16x8;
typedef __attribute__((ext_vector_type(4))) float f32x4;

#define PITCH 40   // small-conv kernel LDS pitch (shorts)

__device__ __forceinline__ u16 f2bf(float f) {
  union { float f; unsigned u; } v; v.f = f;
  unsigned r = v.u + 0x7fffu + ((v.u >> 16) & 1u);
  return (u16)(r >> 16);
}
__device__ __forceinline__ float bf2f(u16 h) {
  union { unsigned u; float f; } v; v.u = ((unsigned)h) << 16;
  return v.f;
}
__device__ __forceinline__ float4 load4bf(const u16* p) {
  ushort4 h = *(const ushort4*)p;
  return make_float4(bf2f(h.x), bf2f(h.y), bf2f(h.z), bf2f(h.w));
}
// async global->LDS, 16B per lane; LDS dest = wave-uniform base + lane*16
__device__ __forceinline__ void gll16(const u16* g, u16* l) {
  __builtin_amdgcn_global_load_lds(
      (const __attribute__((address_space(1))) unsigned int*)g,
      (__attribute__((address_space(3))) unsigned int*)l, 16, 0, 0);
}

// wave-per-row layernorm core: lane holds channels 2*lane, 2*lane+1
__device__ __forceinline__ ushort2 ln_row(float2 v, float2 gv, float2 bv) {
  float s = v.x + v.y;
#pragma unroll
  for (int o = 32; o > 0; o >>= 1) s += __shfl_xor(s, o);
  float mu = s * (1.0f / 128.0f);
  float dx = v.x - mu, dy = v.y - mu;
  float q = dx * dx + dy * dy;
#pragma unroll
  for (int o = 32; o > 0; o >>= 1) q += __shfl_xor(q, o);
  float rs = rsqrtf(q * (1.0f / 128.0f) + 1e-5f);
  ushort2 o2;
  o2.x = f2bf(dx * rs * gv.x + bv.x);
  o2.y = f2bf(dy * rs * gv.y + bv.y);
  return o2;
}

// ---------------- fused all-weights repack + zero page + input transpose/LN(n1) --------------
// z: 0..3 = tq,tk,tv,tp (NT=3); 4..9 = sq,sk,sv,sp,sf,sc (NT=27);
// 10 = m1 (OC=512,IC=128,NT=81); 11 = m2 (OC=128,IC=512,NT=81); 12 = tin_ln slice.
struct RAargs {
  const float* w[12]; u16* wb[12]; u16* zp;
  const float* x; float* X0; const float* g; const float* b; u16* XN;
};
__global__ __launch_bounds__(256) void k_repack_all(RAargs a) {
  __shared__ __align__(16) float ws[128 * 81];
  int z = blockIdx.z, x = blockIdx.x, tid = threadIdx.x;
  if (z == 12) {
    // tin_ln: x in 0..511 -> (s-block, l); t[128][33] aliased onto ws
    float (*t)[33] = (float (*)[33])ws;
    int s0 = (x & 127) * 32, l = x >> 7;
#pragma unroll
    for (int r = 0; r < 4; ++r) {
      int lin = r * 256 + tid;
      int c = lin >> 3, sq = (lin & 7) * 4;
      float4 v = *(const float4*)(a.x + ((long)(l * 128 + c) << 12) + s0 + sq);
      t[c][sq] = v.x; t[c][sq + 1] = v.y; t[c][sq + 2] = v.z; t[c][sq + 3] = v.w;
    }
    __syncthreads();
    int wave = tid >> 6, lane = tid & 63;
    int c2 = lane * 2;
    float2 gv = *(const float2*)(a.g + c2);
    float2 bv = *(const float2*)(a.b + c2);
#pragma unroll
    for (int pq = 0; pq < 8; ++pq) {
      int s = pq * 4 + wave;
      float2 v = make_float2(t[c2][s], t[c2 + 1][s]);
      long token = (long)l * 4096 + s0 + s;
      *(float2*)(a.X0 + token * 128 + c2) = v;
      ushort2 o2 = ln_row(v, gv, bv);
      *(ushort2*)(a.XN + token * 128 + c2) = o2;
    }
    return;
  }
  if (z == 0 && x == 0) ((unsigned long long*)a.zp)[tid] = 0ull;  // 2048B zero page
  if (z < 10 && x >= 128) return;
  int NT = (z < 4) ? 3 : ((z < 10) ? 27 : 81);
  int OC = (z == 10) ? 512 : 128;
  int IC = (z == 11) ? 512 : 128;
  int oc, ic0;
  if (z == 11) { oc = x & 127; ic0 = (x >> 7) << 7; }
  else { oc = x; ic0 = 0; }
  const float* src = a.w[z] + ((long)oc * IC + ic0) * NT;
  int n = 128 * NT;
  for (int i = tid; i < n; i += 256) ws[i] = src[i];
  __syncthreads();
  u16* dst = a.wb[z] + (long)oc * IC + ic0;
  long tstep = (long)OC * IC;
  for (int idx = tid; idx < n; idx += 256) {
    int t = idx >> 7, i = idx & 127;
    dst[(long)t * tstep + i] = f2bf(ws[i * NT + t]);
  }
}

// ---------------- quad small conv-as-gather-GEMM body (64x64 tile), mode=1, IC=OC=128 -------
struct QC {
  const u16* X[4]; const u16* W[4]; const float* B[4]; void* Y[4];
  int M[4];
  int lgo[4][3];   // lgWo, lgHo, lgDo
  int lgi[4][3];   // lgWi, lgHi, lgDi
  int di[4][3];    // Di, Hi, Wi
  int st[4][4];    // sL, sD, sH, sW
  int flags[4];
};
__device__ __forceinline__ void conv_quad_body(u16* As, u16* Bs, const QC& a, int grp) {
  int M = a.M[grp];
  int m0 = blockIdx.x * 64;
  if (m0 >= M) return;
  const u16* X = a.X[grp];
  const u16* W3 = a.W[grp];
  const float* bias = a.B[grp];
  void* Yv = a.Y[grp];
  int lgWo = a.lgo[grp][0], lgHo = a.lgo[grp][1], lgDo = a.lgo[grp][2];
  int lgWi = a.lgi[grp][0], lgHi = a.lgi[grp][1], lgDi = a.lgi[grp][2];
  int Di = a.di[grp][0], Hi = a.di[grp][1], Wi = a.di[grp][2];
  int sL = a.st[grp][0], sD = a.st[grp][1], sH = a.st[grp][2], sW = a.st[grp][3];
  int flags = a.flags[grp];

  int tid = threadIdx.x;
  int wave = tid >> 6, lane = tid & 63;
  int quad = lane >> 4, l15 = lane & 15;
  int oc0 = blockIdx.y * 64;

  int srl = tid >> 2;
  int sao = (tid & 3) * 8;
  int sboc = tid >> 2, sbo = (tid & 3) * 8;

  int sm = m0 + srl;
  bool mv = sm < M;
  int w = sm & ((1 << lgWo) - 1);
  int h = (sm >> lgWo) & ((1 << lgHo) - 1);
  int d = (sm >> (lgWo + lgHo)) & ((1 << lgDo) - 1);
  int l = sm >> (lgWo + lgHo + lgDo);

  int c0 = 0, c1 = 0, c2 = 0, c3 = 0;
  auto comp_nb = [&]() -> long {
    if (!mv) return -1;
    int li = l * sL, di = d * sD + c2 - 1, hi = h * sH + c1 - 1, wi = w * sW + c0 - 1;
    bool ok = ((unsigned)di < (unsigned)Di) && ((unsigned)hi < (unsigned)Hi) &&
              ((unsigned)wi < (unsigned)Wi);
    (void)c3;
    if (!ok) return -1;
    return ((((long)((li << lgDi) + di) << lgHi) + hi) << lgWi) + wi;
  };

  long nb = comp_nb();
  const u16* wt = W3 + (long)(oc0 + sboc) * 128 + sbo;
  const long wstep = 128 * 128;
  const int kmask = 3;
  const int total = 27 * 4;

  const bf16x8 Z = {0, 0, 0, 0, 0, 0, 0, 0};
  bf16x8 ra0 = Z, rb;
  if (nb >= 0) ra0 = *(const bf16x8*)(X + nb * 128 + sao);
  rb = *(const bf16x8*)wt;

  f32x4 acc[4];
#pragma unroll
  for (int j = 0; j < 4; ++j) acc[j] = {0.f, 0.f, 0.f, 0.f};

  int wrow = wave * 16;

  for (int ks = 0; ks < total; ++ks) {
    __syncthreads();
    *(bf16x8*)&As[srl * PITCH + sao] = ra0;
    *(bf16x8*)&Bs[sboc * PITCH + sbo] = rb;
    __syncthreads();
    int ksn = ks + 1;
    if (ksn < total) {
      int k0n = (ksn & kmask) << 5;
      if ((ksn & kmask) == 0) {
        wt += wstep;
        if (++c0 == 3) { c0 = 0; if (++c1 == 3) { c1 = 0; if (++c2 == 3) { c2 = 0; ++c3; } } }
        nb = comp_nb();
      }
      ra0 = Z;
      if (nb >= 0) ra0 = *(const bf16x8*)(X + nb * 128 + k0n + sao);
      rb = *(const bf16x8*)(wt + k0n);
    }
    bf16x8 a0 = *(const bf16x8*)&As[(wrow + l15) * PITCH + quad * 8];
#pragma unroll
    for (int j = 0; j < 4; ++j) {
      bf16x8 b = *(const bf16x8*)&Bs[(j * 16 + l15) * PITCH + quad * 8];
      acc[j] = __builtin_amdgcn_mfma_f32_16x16x32_bf16(a0, b, acc[j], 0, 0, 0);
    }
  }

  int col = oc0 + l15;
#pragma unroll
  for (int j = 0; j < 4; ++j) {
    float bj = bias[col + j * 16];
    int rbase = m0 + wrow + quad * 4;
#pragma unroll
    for (int r = 0; r < 4; ++r) {
      int row = rbase + r;
      if (row >= M) continue;
      float v = acc[j][r] + bj;
      if (flags & 2) v = fmaxf(v, 0.f);
      long off = (long)row * 128 + col + j * 16;
      if (flags & 4) ((u16*)Yv)[off] = f2bf(v);
      else if (flags & 1) ((float*)Yv)[off] += v;
      else ((float*)Yv)[off] = v;
    }
  }
}

__global__ __launch_bounds__(256) void k_conv_quad(QC a) {
  __shared__ u16 As[64 * PITCH];
  __shared__ u16 Bs[64 * PITCH];
  conv_quad_body(As, Bs, a, blockIdx.z);
}

// ---------------- big conv-GEMM body: 128x128 tile, BK=64, single-buffer global_load_lds -----
__device__ __forceinline__ void conv_gl_body(
    u16* As, u16* Bs,
    const u16* __restrict__ X, const u16* __restrict__ W3,
    const float* __restrict__ bias, void* __restrict__ Yv,
    float* __restrict__ SP, const u16* __restrict__ ZP,
    int M, int IC, int OC, int mode, int NT, int NSPLIT, int split, int spidx,
    int lgWo, int lgHo, int lgDo,
    int lgWi, int lgHi, int lgDi,
    int Li, int Di, int Hi, int Wi,
    int sL, int sD, int sH, int sW, int flags) {
  int tid = threadIdx.x;
  int wave = tid >> 6, lane = tid & 63;
  int quad = lane >> 4, l15 = lane & 15;
  int m0 = blockIdx.x * 128, oc0 = blockIdx.y * 128;
  int mi = wave & 1, ni = wave >> 1;

  int rp[4], cA[4], sm[4];
#pragma unroll
  for (int q = 0; q < 4; ++q) {
    rp[q] = wave * 32 + q * 8 + (lane >> 3);
    cA[q] = ((lane & 7) - (rp[q] >> 1)) & 7;
    sm[q] = m0 + rp[q];
  }

  int tap_per = (NT + NSPLIT - 1) / NSPLIT;
  int t0 = split * tap_per;
  int t1 = min(NT, t0 + tap_per);
  int kc = IC >> 6;
  int total = (t1 - t0) * kc;

  int c0 = t0 % 3, c1 = (t0 / 3) % 3, c2 = (t0 / 9) % 3, c3 = t0 / 27;
  auto comp_nb = [&](int smv) -> int {
    if (smv >= M) return -1;
    int w = smv & ((1 << lgWo) - 1);
    int h = (smv >> lgWo) & ((1 << lgHo) - 1);
    int d = (smv >> (lgWo + lgHo)) & ((1 << lgDo) - 1);
    int l = smv >> (lgWo + lgHo + lgDo);
    int li, di, hi, wi; bool ok;
    if (mode == 0) {
      int dl = c0 - 1;
      int ll = (l & 1) + dl;
      ok = (ll >= 0 && ll < 2);
      li = l + dl; di = d; hi = h; wi = w;
    } else if (mode == 1) {
      li = l * sL; di = d * sD + c2 - 1; hi = h * sH + c1 - 1; wi = w * sW + c0 - 1;
      ok = ((unsigned)di < (unsigned)Di) && ((unsigned)hi < (unsigned)Hi) &&
           ((unsigned)wi < (unsigned)Wi);
    } else {
      li = l + c3 - 1; di = d + c2 - 1; hi = h + c1 - 1; wi = w + c0 - 1;
      ok = ((unsigned)li < (unsigned)Li) && ((unsigned)di < (unsigned)Di) &&
           ((unsigned)hi < (unsigned)Hi) && ((unsigned)wi < (unsigned)Wi);
    }
    if (!ok) return -1;
    return (((li << lgDi) + di) << lgHi | hi) << lgWi | wi;
  };

  int nb[4];
#pragma unroll
  for (int q = 0; q < 4; ++q) nb[q] = comp_nb(sm[q]);
  long wstep = (long)OC * IC;
  const u16* wbase = W3 + (long)t0 * wstep + (long)oc0 * IC;

  f32x4 acc[4][4];
#pragma unroll
  for (int i = 0; i < 4; ++i)
#pragma unroll
    for (int j = 0; j < 4; ++j) acc[i][j] = {0.f, 0.f, 0.f, 0.f};

  int kk = 0;
  for (int ks = 0; ks < total; ++ks) {
    if (kk == kc) {
      kk = 0;
      if (++c0 == 3) { c0 = 0; if (++c1 == 3) { c1 = 0; if (++c2 == 3) { c2 = 0; ++c3; } } }
#pragma unroll
      for (int q = 0; q < 4; ++q) nb[q] = comp_nb(sm[q]);
      wbase += wstep;
    }
    int k0 = kk << 6;
    ++kk;
    __syncthreads();
#pragma unroll
    for (int q = 0; q < 4; ++q) {
      const u16* a = (nb[q] >= 0) ? X + (long)nb[q] * IC + k0 + cA[q] * 8 : ZP;
      gll16(a, &As[(wave * 4 + q) * 512]);
    }
#pragma unroll
    for (int q = 0; q < 4; ++q) {
      const u16* bsrc = wbase + (long)rp[q] * IC + k0 + cA[q] * 8;
      gll16(bsrc, &Bs[(wave * 4 + q) * 512]);
    }
    __syncthreads();
#pragma unroll
    for (int ksub = 0; ksub < 2; ++ksub) {
      bf16x8 af[4], bf[4];
#pragma unroll
      for (int i = 0; i < 4; ++i) {
        int row = mi * 64 + i * 16 + l15;
        int pa = ((ksub * 4 + quad) + (row >> 1)) & 7;
        af[i] = *(const bf16x8*)&As[row * 64 + pa * 8];
      }
#pragma unroll
      for (int j = 0; j < 4; ++j) {
        int row = ni * 64 + j * 16 + l15;
        int pb = ((ksub * 4 + quad) + (row >> 1)) & 7;
        bf[j] = *(const bf16x8*)&Bs[row * 64 + pb * 8];
      }
#pragma unroll
      for (int i = 0; i < 4; ++i)
#pragma unroll
        for (int j = 0; j < 4; ++j)
          acc[i][j] = __builtin_amdgcn_mfma_f32_16x16x32_bf16(af[i], bf[j], acc[i][j], 0, 0, 0);
    }
  }

  if (NSPLIT > 1) {
    float* out = SP + (long)spidx * M * OC;
#pragma unroll
    for (int j = 0; j < 4; ++j) {
      int c = oc0 + ni * 64 + j * 16 + l15;
#pragma unroll
      for (int i = 0; i < 4; ++i) {
        int rbase = m0 + mi * 64 + i * 16 + quad * 4;
#pragma unroll
        for (int r = 0; r < 4; ++r) {
          int row = rbase + r;
          if (row < M) out[(long)row * OC + c] = acc[i][j][r];
        }
      }
    }
  } else {
#pragma unroll
    for (int j = 0; j < 4; ++j) {
      int c = oc0 + ni * 64 + j * 16 + l15;
      float bj = bias[c];
#pragma unroll
      for (int i = 0; i < 4; ++i) {
        int rbase = m0 + mi * 64 + i * 16 + quad * 4;
#pragma unroll
        for (int r = 0; r < 4; ++r) {
          int row = rbase + r;
          if (row >= M) continue;
          float v = acc[i][j][r] + bj;
          if (flags & 2) v = fmaxf(v, 0.f);
          long off = (long)row * OC + c;
          if (flags & 4) ((u16*)Yv)[off] = f2bf(v);
          else if (flags & 1) ((float*)Yv)[off] += v;
          else ((float*)Yv)[off] = v;
        }
      }
    }
  }
}

// multi-group wrapper: blockIdx.z = grp*NSPLIT + split; grp selects weight (+wgs)
__global__ __launch_bounds__(256, 4) void k_conv_gl(
    const u16* __restrict__ X, const u16* __restrict__ W3,
    const float* __restrict__ bias, void* __restrict__ Yv, float* __restrict__ SP,
    const u16* __restrict__ ZP,
    int M, int IC, int OC, int mode, int NT, int NSPLIT, long wgs,
    int lgWo, int lgHo, int lgDo,
    int lgWi, int lgHi, int lgDi,
    int Li, int Di, int Hi, int Wi,
    int sL, int sD, int sH, int sW, int flags) {
  __shared__ __align__(16) u16 As[128 * 64];
  __shared__ __align__(16) u16 Bs[128 * 64];
  int zz = blockIdx.z;
  int grp = zz / NSPLIT, split = zz % NSPLIT;
  conv_gl_body(As, Bs, X, W3 + (long)grp * wgs, bias, Yv, SP, ZP,
               M, IC, OC, mode, NT, NSPLIT, split, zz,
               lgWo, lgHo, lgDo, lgWi, lgHi, lgDi,
               Li, Di, Hi, Wi, sL, sD, sH, sW, flags);
}

// ---------------- merged heterogeneous dispatch: sq conv (z<7) + sc/sf quad (z>=7) ----------
__global__ __launch_bounds__(256, 4) void k_sq_scsf(
    const u16* __restrict__ XN, const u16* __restrict__ W3,
    float* __restrict__ SP, const u16* __restrict__ ZP, QC qa) {
  __shared__ __align__(16) u16 As[128 * 64];
  __shared__ __align__(16) u16 Bs[128 * 64];
  int z = blockIdx.z;
  if (z < 7) {
    if (blockIdx.y) return;
    conv_gl_body(As, Bs, XN, W3, nullptr, nullptr, SP, ZP,
                 16384, 128, 128, 1, 27, 7, z, z,
                 4, 4, 4, 4, 4, 4, 4, 16, 16, 16, 1, 1, 1, 1, 0);
  } else {
    if (blockIdx.x >= 16) return;
    conv_quad_body(As, Bs, qa, z - 7);
  }
}

// ---------------- 256x256 8-phase conv-GEMM (R3 form: best measured), BK=64, 8 waves -------
__global__ __launch_bounds__(512, 2) void k_conv_g256(
    const u16* __restrict__ X, const u16* __restrict__ W3,
    const float* __restrict__ bias, void* __restrict__ Yv, float* __restrict__ SP,
    const u16* __restrict__ ZP,
    int M, int IC, int OC, int mode, int NT, int NSPLIT,
    int lgWo, int lgHo, int lgDo,
    int lgWi, int lgHi, int lgDi,
    int Li, int Di, int Hi, int Wi,
    int sL, int sD, int sH, int sW, int flags) {
  __shared__ __align__(16) u16 Ab[4][8192];
  __shared__ __align__(16) u16 Bb[4][8192];
  int tid = threadIdx.x;
  int wave = tid >> 6, lane = tid & 63;
  int quad = lane >> 4, l15 = lane & 15;
  int wr = wave >> 2, wc = wave & 3;
  int m0 = blockIdx.x * 256, oc0 = blockIdx.y * 256;

  int srow0 = tid >> 2;
  int spc = tid & 3;
  int lc0 = (spc - (srow0 >> 1)) & 3;
  int lc1 = (spc - ((srow0 + 128) >> 1)) & 3;

  int kc = IC >> 6;
  int hsPerTap = kc << 1;
  int tap_per = (NT + NSPLIT - 1) / NSPLIT;
  int t0 = blockIdx.z * tap_per;
  int t1 = min(NT, t0 + tap_per);
  int TOT = (t1 - t0) * kc;
  int TOTH = TOT * 2;

  int c0 = t0 % 3, c1 = (t0 / 3) % 3, c2 = (t0 / 9) % 3, c3 = t0 / 27;
  auto comp_nb = [&](int smv) -> int {
    if (smv >= M) return -1;
    int w = smv & ((1 << lgWo) - 1);
    int h = (smv >> lgWo) & ((1 << lgHo) - 1);
    int d = (smv >> (lgWo + lgHo)) & ((1 << lgDo) - 1);
    int l = smv >> (lgWo + lgHo + lgDo);
    int li, di, hi, wi; bool ok;
    if (mode == 0) {
      int dl = c0 - 1;
      int ll = (l & 1) + dl;
      ok = (ll >= 0 && ll < 2);
      li = l + dl; di = d; hi = h; wi = w;
    } else if (mode == 1) {
      li = l * sL; di = d * sD + c2 - 1; hi = h * sH + c1 - 1; wi = w * sW + c0 - 1;
      ok = ((unsigned)di < (unsigned)Di) && ((unsigned)hi < (unsigned)Hi) &&
           ((unsigned)wi < (unsigned)Wi);
    } else {
      li = l + c3 - 1; di = d + c2 - 1; hi = h + c1 - 1; wi = w + c0 - 1;
      ok = ((unsigned)li < (unsigned)Li) && ((unsigned)di < (unsigned)Di) &&
           ((unsigned)hi < (unsigned)Hi) && ((unsigned)wi < (unsigned)Wi);
    }
    if (!ok) return -1;
    return (((li << lgDi) + di) << lgHi | hi) << lgWi | wi;
  };

  int nb0 = comp_nb(m0 + srow0);
  int nb1 = comp_nb(m0 + srow0 + 128);
  const u16* ap0;
  const u16* ap1;
  auto setAp = [&]() {
    ap0 = (nb0 >= 0) ? X + (long)nb0 * IC + lc0 * 8 : ZP;
    ap1 = (nb1 >= 0) ? X + (long)nb1 * IC + lc1 * 8 : ZP;
  };
  setAp();
  int ahs = 0, sA = 0;
  u16* adst = &Ab[0][wave << 9];
  auto stageA = [&]() {
    u16* d = adst + ((sA & 3) << 13);
    ++sA;
    if (sA > TOTH) { gll16(ZP, d); gll16(ZP, d + 4096); return; }
    gll16(ap0 + (ahs << 5), d);
    gll16(ap1 + (ahs << 5), d + 4096);
    if (++ahs == hsPerTap) {
      ahs = 0;
      if (++c0 == 3) { c0 = 0; if (++c1 == 3) { c1 = 0; if (++c2 == 3) { c2 = 0; ++c3; } } }
      nb0 = comp_nb(m0 + srow0);
      nb1 = comp_nb(m0 + srow0 + 128);
      setAp();
    }
  };

  long wstep = (long)OC * IC;
  const u16* bp = W3 + ((long)t0 * OC + oc0 + srow0) * IC + lc0 * 8;
  long bdlt = (long)128 * IC + (lc1 - lc0) * 8;
  long btap = wstep - (long)(hsPerTap - 1) * 32;
  int bhs = 0, sB = 0;
  u16* bdst = &Bb[0][wave << 9];
  auto stageB = [&]() {
    u16* d = bdst + ((sB & 3) << 13);
    ++sB;
    if (sB > TOTH) { gll16(ZP, d); gll16(ZP, d + 4096); return; }
    gll16(bp, d);
    gll16(bp + bdlt, d + 4096);
    if (++bhs == hsPerTap) { bhs = 0; bp += btap; }
    else bp += 32;
  };

  int rowA0 = (wr << 7) + l15;
  int rA0 = rowA0 * 32 + (((quad + (rowA0 >> 1)) & 3) << 3);
  int rowB0 = (wc << 6) + l15;
  int rB0 = rowB0 * 32 + (((quad + (rowB0 >> 1)) & 3) << 3);
  const u16* Abase = &Ab[0][0];
  const u16* Bbase = &Bb[0][0];

  f32x4 acc[8][4];
#pragma unroll
  for (int i = 0; i < 8; ++i)
#pragma unroll
    for (int j = 0; j < 4; ++j) acc[i][j] = {0.f, 0.f, 0.f, 0.f};

  bf16x8 af[4], bfr[4];
  auto rdAB = [&](int reg) {
    const u16* pA = Abase + (reg << 13) + rA0;
    const u16* pB = Bbase + (reg << 13) + rB0;
    af[0] = *(const bf16x8*)(pA);
    bfr[0] = *(const bf16x8*)(pB);
    bfr[1] = *(const bf16x8*)(pB + (1 << 9));
    bfr[2] = *(const bf16x8*)(pB + (2 << 9));
    bfr[3] = *(const bf16x8*)(pB + (3 << 9));
    af[1] = *(const bf16x8*)(pA + (1 << 9));
    af[2] = *(const bf16x8*)(pA + (2 << 9));
    af[3] = *(const bf16x8*)(pA + (3 << 9));
  };
  auto rdA = [&](int reg, int ih) {
    const u16* pA = Abase + (reg << 13) + (ih << 11) + rA0;
#pragma unroll
    for (int i = 0; i < 4; ++i) af[i] = *(const bf16x8*)(pA + (i << 9));
  };
  auto mf = [&](int ih) {
    __builtin_amdgcn_s_setprio(1);
#pragma unroll
    for (int i = 0; i < 4; ++i)
#pragma unroll
      for (int j = 0; j < 4; ++j)
        acc[(ih << 2) + i][j] =
            __builtin_amdgcn_mfma_f32_16x16x32_bf16(af[i], bfr[j], acc[(ih << 2) + i][j], 0, 0, 0);
    __builtin_amdgcn_s_setprio(0);
  };

  stageA(); stageB();
  stageA(); stageB();
  stageA(); stageB();
  asm volatile("s_waitcnt vmcnt(8)" ::: "memory");
  __builtin_amdgcn_s_barrier();

  for (int n = 0; n < TOT; ++n) {
    int rg = (n & 1) << 1;
    rdAB(rg);
    stageA();
    __builtin_amdgcn_sched_barrier(0);
    __builtin_amdgcn_s_barrier();
    mf(0);
    __builtin_amdgcn_s_barrier();
    rdA(rg, 1);
    stageB();
    __builtin_amdgcn_sched_barrier(0);
    __builtin_amdgcn_s_barrier();
    mf(1);
    __builtin_amdgcn_sched_barrier(0);
    asm volatile("s_waitcnt vmcnt(8)" ::: "memory");
    __builtin_amdgcn_s_barrier();
    rdAB(rg + 1);
    stageA();
    __builtin_amdgcn_sched_barrier(0);
    __builtin_amdgcn_s_barrier();
    mf(0);
    __builtin_amdgcn_s_barrier();
    rdA(rg + 1, 1);
    stageB();
    __builtin_amdgcn_sched_barrier(0);
    __builtin_amdgcn_s_barrier();
    mf(1);
    __builtin_amdgcn_sched_barrier(0);
    asm volatile("s_waitcnt vmcnt(8)" ::: "memory");
    __builtin_amdgcn_s_barrier();
  }

  if (NSPLIT > 1) {
    float* outp = SP + (long)blockIdx.z * M * OC;
#pragma unroll
    for (int i = 0; i < 8; ++i)
#pragma unroll
      for (int j = 0; j < 4; ++j) {
        int c = oc0 + (wc << 6) + (j << 4) + l15;
        int rb = m0 + (wr << 7) + (i << 4) + (quad << 2);
#pragma unroll
        for (int r = 0; r < 4; ++r) {
          int row = rb + r;
          if (row < M) outp[(long)row * OC + c] = acc[i][j][r];
        }
      }
  } else {
#pragma unroll
    for (int i = 0; i < 8; ++i)
#pragma unroll
      for (int j = 0; j < 4; ++j) {
        int c = oc0 + (wc << 6) + (j << 4) + l15;
        float bj = bias[c];
        int rb = m0 + (wr << 7) + (i << 4) + (quad << 2);
#pragma unroll
        for (int r = 0; r < 4; ++r) {
          int row = rb + r;
          if (row >= M) continue;
          float v = acc[i][j][r] + bj;
          if (flags & 2) v = fmaxf(v, 0.f);
          long off = (long)row * OC + c;
          if (flags & 4) ((u16*)Yv)[off] = f2bf(v);
          else if (flags & 1) ((float*)Yv)[off] += v;
          else ((float*)Yv)[off] = v;
        }
      }
  }
}

// ---------------- combine split-K partials: out = (sum_s SP[s]) + bias ----------------
__global__ __launch_bounds__(256) void k_combine(const float* __restrict__ SP,
                                                 const float* __restrict__ bias,
                                                 void* __restrict__ out,
                                                 long MOC, int lgOC, int nsplit, int flags) {
  long idx = (long)blockIdx.x * 256 + threadIdx.x;
  if (idx >= MOC) return;
  float v = bias[idx & ((1 << lgOC) - 1)];
  for (int s = 0; s < nsplit; ++s) v += SP[s * MOC + idx];
  if (flags & 2) v = fmaxf(v, 0.f);
  if (flags & 4) ((u16*)out)[idx] = f2bf(v);
  else if (flags & 1) ((float*)out)[idx] += v;
  else ((float*)out)[idx] = v;
}

// ---------------- fused split-K combine + residual-accumulate into X0 + LN -> XN ------------
__global__ __launch_bounds__(256) void k_comb_ln(const float* __restrict__ SP,
                                                 const float* __restrict__ bias,
                                                 float* __restrict__ X0,
                                                 const float* __restrict__ g,
                                                 const float* __restrict__ b,
                                                 u16* __restrict__ XN, int nsplit) {
  int n = blockIdx.x * 4 + (threadIdx.x >> 6);
  int lane = threadIdx.x & 63;
  long off = (long)n * 128 + lane * 2;
  float2 v = *(const float2*)(bias + lane * 2);
  for (int s = 0; s < nsplit; ++s) {
    float2 sv = *(const float2*)(SP + (((long)s) << 21) + off);
    v.x += sv.x; v.y += sv.y;
  }
  float2 x0 = *(const float2*)(X0 + off);
  v.x += x0.x; v.y += x0.y;
  *(float2*)(X0 + off) = v;
  float2 gv = *(const float2*)(g + lane * 2);
  float2 bv = *(const float2*)(b + lane * 2);
  ushort2 o2 = ln_row(v, gv, bv);
  *(ushort2*)(XN + off) = o2;
}

// ---------------- fused m2 combine + residual + transposed output write --------------------
__global__ __launch_bounds__(256) void k_comb_out(const float* __restrict__ SP,
                                                  const float* __restrict__ X0,
                                                  const float* __restrict__ bias,
                                                  float* __restrict__ out) {
  __shared__ float t[32][33];
  int s0 = blockIdx.x * 32, c0 = blockIdx.y * 32, l = blockIdx.z;
  int r = threadIdx.x >> 3, q4 = (threadIdx.x & 7) * 4;
  long token = (long)l * 4096 + s0 + r;
  long off = token * 128 + c0 + q4;
  float4 v = *(const float4*)(bias + c0 + q4);
#pragma unroll
  for (int s = 0; s < 8; ++s) {
    float4 sv = *(const float4*)(SP + (((long)s) << 21) + off);
    v.x += sv.x; v.y += sv.y; v.z += sv.z; v.w += sv.w;
  }
  float4 x0 = *(const float4*)(X0 + off);
  v.x += x0.x; v.y += x0.y; v.z += x0.z; v.w += x0.w;
  t[r][q4] = v.x; t[r][q4 + 1] = v.y; t[r][q4 + 2] = v.z; t[r][q4 + 3] = v.w;
  __syncthreads();
  float4 o = {t[q4][r], t[q4 + 1][r], t[q4 + 2][r], t[q4 + 3][r]};
  *(float4*)(out + ((long)(l * 128 + c0 + r) << 12) + s0 + q4) = o;
}

// ---------------- TLG windowed cross attention, fused with tq/tk/tv split-K combine ---------
// reads fp32 partials (regions: q=0,1; k=2,3; v=4,5) + per-proj bias directly.
__global__ __launch_bounds__(256) void k_tlg_attn(const float* __restrict__ SP,
                                                  const float* __restrict__ bq,
                                                  const float* __restrict__ bk,
                                                  const float* __restrict__ bv,
                                                  u16* __restrict__ Y) {
  int gw = blockIdx.x * 4 + (threadIdx.x >> 6);
  int lane = threadIdx.x & 63;
  int head = gw & 7;
  int win = gw >> 3;
  int wB = win & 7, hB = (win >> 3) & 7, dB = (win >> 6) & 7, l = win >> 9;
  int i = lane >> 3, j = lane & 7;
  int nq = (l << 12) | ((dB * 2 + (i >> 2)) << 8) | ((hB * 2 + ((i >> 1) & 1)) << 4) |
           (wB * 2 + (i & 1));
  int lk = l ^ 2;
  int nk = (lk << 12) | ((dB * 2 + (j >> 2)) << 8) | ((hB * 2 + ((j >> 1) & 1)) << 4) |
           (wB * 2 + (j & 1));
  int hoff = head * 16;
  long qoff = (long)nq * 128 + hoff;
  long koff = (long)nk * 128 + hoff;
  const float* S1 = SP + (1L << 21);
  const float* S2 = SP + (2L << 21);
  const float* S3 = SP + (3L << 21);
  const float* S4 = SP + (4L << 21);
  const float* S5 = SP + (5L << 21);
  float s = 0.f;
#pragma unroll
  for (int t = 0; t < 16; t += 4) {
    float4 a0 = *(const float4*)(SP + qoff + t);
    float4 a1 = *(const float4*)(S1 + qoff + t);
    float4 ab = *(const float4*)(bq + hoff + t);
    float4 b0 = *(const float4*)(S2 + koff + t);
    float4 b1 = *(const float4*)(S3 + koff + t);
    float4 bb = *(const float4*)(bk + hoff + t);
    float ax = a0.x + a1.x + ab.x, ay = a0.y + a1.y + ab.y;
    float az = a0.z + a1.z + ab.z, aw = a0.w + a1.w + ab.w;
    float bx = b0.x + b1.x + bb.x, by = b0.y + b1.y + bb.y;
    float bz = b0.z + b1.z + bb.z, bw = b0.w + b1.w + bb.w;
    s += ax * bx + ay * by + az * bz + aw * bw;
  }
  s *= 0.25f;
  float mx = s;
#pragma unroll
  for (int o = 1; o < 8; o <<= 1) mx = fmaxf(mx, __shfl_xor(mx, o));
  float e = __expf(s - mx);
  float sum = e;
#pragma unroll
  for (int o = 1; o < 8; o <<= 1) sum += __shfl_xor(sum, o);
  float p = e / sum;
  float y[16];
#pragma unroll
  for (int t = 0; t < 16; t += 4) {
    float4 v0 = *(const float4*)(S4 + koff + t);
    float4 v1 = *(const float4*)(S5 + koff + t);
    float4 vb = *(const float4*)(bv + hoff + t);
    y[t] = p * (v0.x + v1.x + vb.x);
    y[t + 1] = p * (v0.y + v1.y + vb.y);
    y[t + 2] = p * (v0.z + v1.z + vb.z);
    y[t + 3] = p * (v0.w + v1.w + vb.w);
  }
#pragma unroll
  for (int o = 1; o < 8; o <<= 1) {
#pragma unroll
    for (int t = 0; t < 16; ++t) y[t] += __shfl_xor(y[t], o);
  }
  if (j == 0) {
    u16* yp = Y + (long)nq * 128 + hoff;
    u16 tmp[16];
#pragma unroll
    for (int t = 0; t < 16; ++t) tmp[t] = f2bf(y[t]);
    *(uint4*)(yp) = *(uint4*)tmp;
    *(uint4*)(yp + 8) = *(uint4*)(tmp + 8);
  }
}

// ---------------- fused K/V layernorm + pack: Kf||Vf (fp32) -> Kh, Vt (bf16, attn layouts) ---
__global__ __launch_bounds__(256) void k_ln_kv(const float* __restrict__ X,
                                               const float* __restrict__ g,
                                               const float* __restrict__ b,
                                               u16* __restrict__ Kh,
                                               u16* __restrict__ Vt) {
  int n = blockIdx.x * 4 + (threadIdx.x >> 6);
  if (n >= 2064) return;
  int lane = threadIdx.x & 63;
  float2 v = *(const float2*)(X + (long)n * 128 + lane * 2);
  float2 gv = *(const float2*)(g + lane * 2);
  float2 bv = *(const float2*)(b + lane * 2);
  ushort2 o2 = ln_row(v, gv, bv);
  int isK = n < 1032;
  int k = isK ? n : n - 1032;
  int h = lane >> 3, d = (lane & 7) * 2;
  if (isK) {
    *(ushort2*)(Kh + (((long)h * 1032 + k) << 4) + d) = o2;
  } else {
    Vt[((long)(h * 16 + d)) * 1032 + k] = o2.x;
    Vt[((long)(h * 16 + d) + 1) * 1032 + k] = o2.y;
  }
}

// ---------------- SLG MFMA flash attention, fused with sq split-K combine -------------------
// Q = f2bf(sq_bias + sum of 7 fp32 partials) -- bit-identical to the old combine+read path.
__global__ __launch_bounds__(256) void k_slg_flash(const float* __restrict__ QSP,
                                                   const float* __restrict__ bq,
                                                   const u16* __restrict__ Kh,
                                                   const u16* __restrict__ Vt,
                                                   u16* __restrict__ Y) {
  constexpr int NK = 1032;
  constexpr int NTILE = 17;
  __shared__ __align__(16) u16 Ks[64 * 24];
  __shared__ __align__(16) u16 Vs[16 * 72];
  __shared__ __align__(16) u16 Ps[4][16 * 72];
  int tid = threadIdx.x;
  int wave = tid >> 6, lane = tid & 63;
  int quad = lane >> 4, l15 = lane & 15;
  int h = blockIdx.x & 7;
  int q0 = (blockIdx.x >> 3) * 64 + wave * 16;

  const bf16x8 Zb = {0, 0, 0, 0, 0, 0, 0, 0};
  bf16x8 qf = Zb;
  if (quad < 2) {
    long off = (long)(q0 + l15) * 128 + h * 16 + quad * 8;
    float v[8];
#pragma unroll
    for (int jj = 0; jj < 8; ++jj) v[jj] = bq[h * 16 + quad * 8 + jj];
#pragma unroll
    for (int sx = 0; sx < 7; ++sx) {
      float4 p0 = *(const float4*)(QSP + ((long)sx << 21) + off);
      float4 p1 = *(const float4*)(QSP + ((long)sx << 21) + off + 4);
      v[0] += p0.x; v[1] += p0.y; v[2] += p0.z; v[3] += p0.w;
      v[4] += p1.x; v[5] += p1.y; v[6] += p1.z; v[7] += p1.w;
    }
    union { u16 u[8]; bf16x8 v8; } cv;
#pragma unroll
    for (int jj = 0; jj < 8; ++jj) cv.u[jj] = f2bf(v[jj]);
    qf = cv.v8;
  }

  const u16* Kbase = Kh + (long)h * NK * 16;
  const u16* Vbase = Vt + (long)h * 16 * NK;

  float mrow[4], lrow[4];
  f32x4 oacc = {0.f, 0.f, 0.f, 0.f};
#pragma unroll
  for (int r = 0; r < 4; ++r) { mrow[r] = -1e30f; lrow[r] = 0.f; }

  int skey = tid >> 2, sch = (tid & 3) * 4;
  int svd = tid >> 4, svc = (tid & 15) * 4;

  for (int t = 0; t < NTILE; ++t) {
    int k0 = t * 64;
    __syncthreads();
    {
      short4 v = {0, 0, 0, 0};
      int key = k0 + skey;
      if (key < NK) v = *(const short4*)(Kbase + key * 16 + sch);
      *(short4*)&Ks[skey * 24 + sch] = v;
    }
    {
      short4 v = {0, 0, 0, 0};
      int colb = k0 + svc;
      if (colb < NK) v = *(const short4*)(Vbase + svd * NK + colb);
      *(short4*)&Vs[svd * 72 + svc] = v;
    }
    __syncthreads();

    f32x4 s[4];
#pragma unroll
    for (int sub = 0; sub < 4; ++sub) {
      bf16x8 b = Zb;
      if (quad < 2) b = *(const bf16x8*)&Ks[(sub * 16 + l15) * 24 + quad * 8];
      f32x4 zero = {0.f, 0.f, 0.f, 0.f};
      s[sub] = __builtin_amdgcn_mfma_f32_16x16x32_bf16(qf, b, zero, 0, 0, 0);
    }
    float pv[4][4];
    float tmax[4] = {-1e30f, -1e30f, -1e30f, -1e30f};
#pragma unroll
    for (int sub = 0; sub < 4; ++sub) {
      int key = k0 + sub * 16 + l15;
      bool valid = key < NK;
#pragma unroll
      for (int r = 0; r < 4; ++r) {
        float sv = valid ? s[sub][r] * 0.25f : -1e30f;
        pv[sub][r] = sv;
        tmax[r] = fmaxf(tmax[r], sv);
      }
    }
#pragma unroll
    for (int o = 1; o < 16; o <<= 1)
#pragma unroll
      for (int r = 0; r < 4; ++r) tmax[r] = fmaxf(tmax[r], __shfl_xor(tmax[r], o));

    float al[4], tsum[4] = {0.f, 0.f, 0.f, 0.f};
#pragma unroll
    for (int r = 0; r < 4; ++r) {
      float mn = fmaxf(mrow[r], tmax[r]);
      al[r] = __expf(mrow[r] - mn);
      mrow[r] = mn;
    }
#pragma unroll
    for (int sub = 0; sub < 4; ++sub)
#pragma unroll
      for (int r = 0; r < 4; ++r) {
        float pe = __expf(pv[sub][r] - mrow[r]);
        tsum[r] += pe;
        Ps[wave][(quad * 4 + r) * 72 + sub * 16 + l15] = f2bf(pe);
      }
#pragma unroll
    for (int o = 1; o < 16; o <<= 1)
#pragma unroll
      for (int r = 0; r < 4; ++r) tsum[r] += __shfl_xor(tsum[r], o);
#pragma unroll
    for (int r = 0; r < 4; ++r) {
      lrow[r] = lrow[r] * al[r] + tsum[r];
      oacc[r] *= al[r];
    }
    bf16x8 pa0 = *(const bf16x8*)&Ps[wave][l15 * 72 + quad * 8];
    bf16x8 pa1 = *(const bf16x8*)&Ps[wave][l15 * 72 + 32 + quad * 8];
    bf16x8 vb0 = *(const bf16x8*)&Vs[l15 * 72 + quad * 8];
    bf16x8 vb1 = *(const bf16x8*)&Vs[l15 * 72 + 32 + quad * 8];
    oacc = __builtin_amdgcn_mfma_f32_16x16x32_bf16(pa0, vb0, oacc, 0, 0, 0);
    oacc = __builtin_amdgcn_mfma_f32_16x16x32_bf16(pa1, vb1, oacc, 0, 0, 0);
  }

#pragma unroll
  for (int r = 0; r < 4; ++r) {
    float inv = 1.0f / lrow[r];
    Y[(long)(q0 + quad * 4 + r) * 128 + h * 16 + l15] = f2bf(oacc[r] * inv);
  }
}

static inline int ilg(int v) { int r = 0; while ((1 << r) < v) ++r; return r; }

extern "C" void kernel_launch(void* const* d_in, const int* in_sizes, int n_in,
                              void* d_out, int out_size, void* d_ws, size_t ws_size,
                              hipStream_t stream) {
  (void)in_sizes; (void)n_in; (void)out_size; (void)ws_size;
  const float* x    = (const float*)d_in[0];
  const float* n1_w = (const float*)d_in[1];  const float* n1_b = (const float*)d_in[2];
  const float* n2_w = (const float*)d_in[3];  const float* n2_b = (const float*)d_in[4];
  const float* n3_w = (const float*)d_in[5];  const float* n3_b = (const float*)d_in[6];
  const float* sn_w = (const float*)d_in[7];  const float* sn_b = (const float*)d_in[8];
  const float* tq_w = (const float*)d_in[9];  const float* tq_b = (const float*)d_in[10];
  const float* tk_w = (const float*)d_in[11]; const float* tk_b = (const float*)d_in[12];
  const float* tv_w = (const float*)d_in[13]; const float* tv_b = (const float*)d_in[14];
  const float* tp_w = (const float*)d_in[15]; const float* tp_b = (const float*)d_in[16];
  const float* sq_w = (const float*)d_in[17]; const float* sq_b = (const float*)d_in[18];
  const float* sk_w = (const float*)d_in[19]; const float* sk_b = (const float*)d_in[20];
  const float* sv_w = (const float*)d_in[21]; const float* sv_b = (const float*)d_in[22];
  const float* sp_w = (const float*)d_in[23]; const float* sp_b = (const float*)d_in[24];
  const float* sf_w = (const float*)d_in[25]; const float* sf_b = (const float*)d_in[26];
  const float* sc_w = (const float*)d_in[27]; const float* sc_b = (const float*)d_in[28];
  const float* m1_w = (const float*)d_in[29]; const float* m1_b = (const float*)d_in[30];
  const float* m2_w = (const float*)d_in[31]; const float* m2_b = (const float*)d_in[32];

  char* p = (char*)d_ws;
  auto alloc = [&](size_t bytes) { char* r = p; p += (bytes + 255) & ~(size_t)255; return r; };
  const long N = 16384;
  float* X0 = (float*)alloc(N * 128 * 4);
  u16* XN = (u16*)alloc(N * 128 * 2);
  u16* Qb = (u16*)alloc(N * 128 * 2);
  u16* Kb = (u16*)alloc(N * 128 * 2);
  u16* Vb = (u16*)alloc(N * 128 * 2);
  u16* Yb = (u16*)alloc(N * 128 * 2);
  u16* H  = (u16*)alloc(N * 512 * 2);
  u16* XC = (u16*)alloc(8 * 128 * 2);
  u16* XF = (u16*)alloc(1024 * 128 * 2);
  float* Kf = (float*)alloc(1032 * 128 * 4);  // Kf,Vf adjacent
  float* Vf = (float*)alloc(1032 * 128 * 4);
  u16* Kh = (u16*)alloc(8 * 1032 * 16 * 2);
  u16* Vt = (u16*)alloc(8 * 16 * 1032 * 2);
  float* SPb = (float*)alloc(2L * N * 512 * 4);  // split-K partials (64 MB)
  u16* ZPb = (u16*)alloc(2048);                   // zero page for masked gather rows
  u16* tq2 = (u16*)alloc(49152 * 2);  u16* tk2 = (u16*)alloc(49152 * 2);  // adjacent,
  u16* tv2 = (u16*)alloc(49152 * 2);  u16* tp2 = (u16*)alloc(49152 * 2);  // stride 49152
  u16* sq2 = (u16*)alloc(442368 * 2); u16* sk2 = (u16*)alloc(442368 * 2);
  u16* sv2 = (u16*)alloc(442368 * 2); u16* sp2 = (u16*)alloc(442368 * 2);
  u16* sf2 = (u16*)alloc(442368 * 2); u16* sc2 = (u16*)alloc(442368 * 2);
  u16* m12 = (u16*)alloc(5308416L * 2);
  u16* m22 = (u16*)alloc(5308416L * 2);
  (void)Kb; (void)Vb;

  // fused zero-page + all 12 weight repacks + input transpose/LN(n1) (z=12)
  {
    RAargs ra;
    const float* ws[12] = {tq_w, tk_w, tv_w, tp_w, sq_w, sk_w, sv_w, sp_w, sf_w, sc_w,
                           m1_w, m2_w};
    u16* wbs[12] = {tq2, tk2, tv2, tp2, sq2, sk2, sv2, sp2, sf2, sc2, m12, m22};
    for (int i = 0; i < 12; ++i) { ra.w[i] = ws[i]; ra.wb[i] = wbs[i]; }
    ra.zp = ZPb; ra.x = x; ra.X0 = X0; ra.g = n1_w; ra.b = n1_b; ra.XN = XN;
    k_repack_all<<<dim3(512, 1, 13), 256, 0, stream>>>(ra);
  }

  auto conv_gl = [&](const u16* Xp, const u16* Wp, const float* Bp, void* Yp,
                     int M, int IC, int OC, int mode, int NT, int nsplit, int flags) {
    dim3 g(M / 128, OC / 128, nsplit);
    k_conv_gl<<<g, 256, 0, stream>>>(Xp, Wp, Bp, Yp, SPb, ZPb, M, IC, OC, mode, NT, nsplit,
                                     0L, 4, 4, 4, 4, 4, 4, 4, 16, 16, 16, 1, 1, 1, 1, flags);
  };

  // ---- TLG branch ----
  // fused tq/tk/tv conv: z = grp*2 + split (regions 0..5); attn combines inline
  {
    dim3 g(128, 1, 6);
    k_conv_gl<<<g, 256, 0, stream>>>(XN, tq2, tq_b, Qb, SPb, ZPb, 16384, 128, 128, 0, 3, 2,
                                     49152L, 4, 4, 4, 4, 4, 4, 4, 16, 16, 16, 1, 1, 1, 1, 4);
  }
  k_tlg_attn<<<4096, 256, 0, stream>>>(SPb, tq_b, tk_b, tv_b, Yb);
  // tp conv (split-K partials), then fused combine + residual into X0 + LN(n2) -> XN
  conv_gl(Yb, tp2, tp_b, X0, 16384, 128, 128, 0, 3, 3, 1);
  k_comb_ln<<<4096, 256, 0, stream>>>(SPb, tp_b, X0, n2_w, n2_b, XN, 3);

  // ---- SLG branch ----
  // merged: sq conv partials (z<7, regions 0..6) + sc/sf quad (z=7,8)
  {
    QC q{};
    q.X[0] = XN; q.W[0] = sc2; q.B[0] = sc_b; q.Y[0] = XC; q.M[0] = 8;
    q.lgo[0][0] = 1; q.lgo[0][1] = 1; q.lgo[0][2] = 1;
    q.lgi[0][0] = 4; q.lgi[0][1] = 4; q.lgi[0][2] = 4;
    q.di[0][0] = 16; q.di[0][1] = 16; q.di[0][2] = 16;
    q.st[0][0] = 4; q.st[0][1] = 8; q.st[0][2] = 8; q.st[0][3] = 8;
    q.flags[0] = 4;
    q.X[1] = XN; q.W[1] = sf2; q.B[1] = sf_b; q.Y[1] = XF; q.M[1] = 1024;
    q.lgo[1][0] = 3; q.lgo[1][1] = 3; q.lgo[1][2] = 3;
    q.lgi[1][0] = 4; q.lgi[1][1] = 4; q.lgi[1][2] = 4;
    q.di[1][0] = 16; q.di[1][1] = 16; q.di[1][2] = 16;
    q.st[1][0] = 2; q.st[1][1] = 2; q.st[1][2] = 2; q.st[1][3] = 2;
    q.flags[1] = 4;
    k_sq_scsf<<<dim3(128, 2, 9), 256, 0, stream>>>(XN, sq2, SPb, ZPb, q);
  }
  // fused k/v convs: coarse-K, coarse-V, fine-K, fine-V
  {
    QC q{};
    for (int i = 0; i < 4; ++i) {
      int fine = i >> 1, isv = i & 1;
      q.X[i] = fine ? XF : XC;
      q.W[i] = isv ? sv2 : sk2;
      q.B[i] = isv ? sv_b : sk_b;
      q.Y[i] = (void*)((isv ? Vf : Kf) + (fine ? 8 * 128 : 0));
      q.M[i] = fine ? 1024 : 8;
      int lo = fine ? 3 : 1;
      q.lgo[i][0] = lo; q.lgo[i][1] = lo; q.lgo[i][2] = lo;
      int li = fine ? 3 : 1;
      q.lgi[i][0] = li; q.lgi[i][1] = li; q.lgi[i][2] = li;
      int dd = fine ? 8 : 2;
      q.di[i][0] = dd; q.di[i][1] = dd; q.di[i][2] = dd;
      q.st[i][0] = 1; q.st[i][1] = 1; q.st[i][2] = 1; q.st[i][3] = 1;
      q.flags[i] = 0;
    }
    k_conv_quad<<<dim3(16, 2, 4), 256, 0, stream>>>(q);
  }
  // fused LN(K/V) + pack -> Kh, Vt
  k_ln_kv<<<516, 256, 0, stream>>>(Kf, sn_w, sn_b, Kh, Vt);
  // flash combines sq partials inline (regions 0..6, still live)
  k_slg_flash<<<2048, 256, 0, stream>>>(SPb, sq_b, Kh, Vt, Yb);
  // sp conv (split-K partials), then fused combine + residual into X0 + LN(n3) -> XN
  conv_gl(Yb, sp2, sp_b, X0, 16384, 128, 128, 1, 27, 7, 1);
  k_comb_ln<<<4096, 256, 0, stream>>>(SPb, sp_b, X0, n3_w, n3_b, XN, 7);

  // ---- MLP branch ----
  {
    dim3 g(64, 2, 2);
    k_conv_g256<<<g, 512, 0, stream>>>(XN, m12, m1_b, H, SPb, ZPb, 16384, 128, 512, 2, 81, 2,
                                       4, 4, 4, 4, 4, 4, 4, 16, 16, 16, 1, 1, 1, 1, 6);
    long MOC = (long)16384 * 512;
    k_combine<<<(int)((MOC + 255) / 256), 256, 0, stream>>>(SPb, m1_b, H, MOC, ilg(512), 2, 6);
  }
  // m2 conv (split-K partials), then fused combine + residual + transposed output
  conv_gl(H, m22, m2_b, X0, 16384, 512, 128, 2, 81, 8, 1);
  k_comb_out<<<dim3(128, 4, 4), 256, 0, stream>>>(SPb, X0, m2_b, (float*)d_out);
}